// Round 2
// baseline (681.163 us; speedup 1.0000x reference)
//
#include <hip/hip_runtime.h>
#include <hip/hip_bf16.h>
#include <cmath>

typedef __bf16 bf16;
typedef __bf16 bf16x8 __attribute__((ext_vector_type(8)));
typedef float f32x4 __attribute__((ext_vector_type(4)));

#define BB 4
#define CC 512
#define NN 4096      // 64*64 spatial
#define NRR 1024     // 32*32 spatial (stride-2)
#define NHH 8
#define DKK 64

static __device__ __forceinline__ bf16x8 ld8(const bf16* p) {
    return *reinterpret_cast<const bf16x8*>(p);
}

// ---------------------------------------------------------------------------
// weight convert / permute (fp32 -> bf16)
// ---------------------------------------------------------------------------
__global__ __launch_bounds__(256) void wcvt_kernel(const float* __restrict__ Wq,
                                                   const float* __restrict__ Wp,
                                                   bf16* __restrict__ Wqb,
                                                   bf16* __restrict__ Wpb) {
    int e = blockIdx.x * 256 + threadIdx.x;   // 262144
    Wqb[e] = (bf16)Wq[e];
    Wpb[e] = (bf16)Wp[e];
}

__global__ __launch_bounds__(256) void wperm_kernel(const float* __restrict__ Wk,
                                                    const float* __restrict__ Wv,
                                                    bf16* __restrict__ Wkf,
                                                    bf16* __restrict__ Wvf) {
    int e = blockIdx.x * 256 + threadIdx.x;   // 512*2048
    int o = e >> 11, q = (e >> 9) & 3, ci = e & 511;
    int src = o * 2048 + ci * 4 + q;
    Wkf[e] = (bf16)Wk[src];
    Wvf[e] = (bf16)Wv[src];
}

// ---------------------------------------------------------------------------
// x (b,C,N) fp32 -> xt (b,N,C) bf16; blockIdx.z = batch
// ---------------------------------------------------------------------------
__global__ __launch_bounds__(256) void transpose_kernel(const float* __restrict__ x,
                                                        bf16* __restrict__ xt) {
    __shared__ bf16 tile[64][65];
    int b = blockIdx.z;
    const float* xb = x + (size_t)b * CC * NN;
    bf16* xtb = xt + (size_t)b * NN * CC;
    int n0 = blockIdx.x * 64, c0 = blockIdx.y * 64;
    int tr = threadIdx.x >> 6, tc = threadIdx.x & 63;
#pragma unroll
    for (int i = 0; i < 64; i += 4)
        tile[tc][i + tr] = (bf16)xb[(long)(c0 + i + tr) * NN + n0 + tc];
    __syncthreads();
#pragma unroll
    for (int i = 0; i < 64; i += 4)
        xtb[(long)(n0 + i + tr) * CC + c0 + tc] = tile[i + tr][tc];
}

// ---------------------------------------------------------------------------
// K/V GEMM, im2col fused; blockIdx.z = b*2 + (0=K,1=V)
// K written key-major [m][C] (as before); V written TRANSPOSED [c][m] so the
// attention PV step can read B-fragments straight from global (L2-resident)
// with no LDS staging / no barriers.
// ---------------------------------------------------------------------------
__global__ __launch_bounds__(256) void gemm_kv(const bf16* __restrict__ xt,
                                               const bf16* __restrict__ Wkf,
                                               const bf16* __restrict__ Wvf,
                                               bf16* __restrict__ kt,
                                               bf16* __restrict__ vt) {
    __shared__ __align__(16) bf16 ttile[64][72];   // V-transpose staging
    const f32x4 fzero = {0.f, 0.f, 0.f, 0.f};
    int z = blockIdx.z;
    int b = z >> 1, kv = z & 1;
    const bf16* xtb = xt + (size_t)b * NN * CC;
    const bf16* Wf = kv ? Wvf : Wkf;
    int w = threadIdx.x >> 6, lane = threadIdx.x & 63;
    int quad = lane >> 4, l15 = lane & 15;
    int m0 = blockIdx.x * 64 + w * 16;
    long n0 = (long)blockIdx.y * 64;
    int m2 = m0 + l15;
    int i2 = m2 >> 5, j2 = m2 & 31;
    const bf16* ap[4];
#pragma unroll
    for (int q = 0; q < 4; ++q) {
        int n = (2 * i2 + (q >> 1)) * 64 + 2 * j2 + (q & 1);
        ap[q] = xtb + (long)n * CC + quad * 8;
    }
    const bf16* Bp = Wf + (n0 + l15) * 2048 + quad * 8;
    f32x4 acc[4];
#pragma unroll
    for (int ct = 0; ct < 4; ++ct) acc[ct] = fzero;
#pragma unroll
    for (int q = 0; q < 4; ++q) {
        const bf16* aq = ap[q];
        const bf16* bq = Bp + q * 512;
#pragma unroll 2
        for (int kk = 0; kk < 512; kk += 32) {
            bf16x8 a = ld8(aq + kk);
#pragma unroll
            for (int ct = 0; ct < 4; ++ct) {
                bf16x8 bv = ld8(bq + kk + ct * 16 * 2048);
                acc[ct] = __builtin_amdgcn_mfma_f32_16x16x32_bf16(a, bv, acc[ct], 0, 0, 0);
            }
        }
    }
    if (!kv) {
        // K: key-major [m][C]
        bf16* Ct = kt + (size_t)b * NRR * CC;
#pragma unroll
        for (int ct = 0; ct < 4; ++ct)
#pragma unroll
            for (int r = 0; r < 4; ++r)
                Ct[(long)(m0 + quad * 4 + r) * CC + n0 + ct * 16 + l15] = (bf16)acc[ct][r];
    } else {
        // V^T: channel-major [c][m]; transpose the 64x64 tile through LDS
        bf16* Ct = vt + (size_t)b * CC * NRR;
#pragma unroll
        for (int ct = 0; ct < 4; ++ct)
#pragma unroll
            for (int r = 0; r < 4; ++r)
                ttile[ct * 16 + l15][w * 16 + quad * 4 + r] = (bf16)acc[ct][r];
        __syncthreads();
        int row = threadIdx.x >> 2, seg = threadIdx.x & 3;   // 64 rows x 4 segs
        bf16x8 v0 = ld8(&ttile[row][seg * 16]);
        bf16x8 v1 = ld8(&ttile[row][seg * 16 + 8]);
        bf16* dst = Ct + (n0 + row) * NRR + (long)blockIdx.x * 64 + seg * 16;
        *reinterpret_cast<bf16x8*>(dst) = v0;
        *reinterpret_cast<bf16x8*>(dst + 8) = v1;
    }
}

// ---------------------------------------------------------------------------
// flash attention with fused Q-GEMM; blockIdx.z = batch
// V read directly from global in [c][m] layout (L2-resident) -> NO barriers
// in the main loop; P LDS round-trip is per-wave, pinned by lgkmcnt(0).
// ---------------------------------------------------------------------------
__global__ __launch_bounds__(256) void attn_kernel(const bf16* __restrict__ xt,
                                                   const bf16* __restrict__ Wqb,
                                                   const bf16* __restrict__ Kt,
                                                   const bf16* __restrict__ Vt,
                                                   const float* __restrict__ bias,
                                                   bf16* __restrict__ Ot) {
    __shared__ __align__(16) bf16 ptile[4][16 * 72];    // per-wave Q/P stripe
    const f32x4 fzero = {0.f, 0.f, 0.f, 0.f};
    int b = blockIdx.z, h = blockIdx.y;
    const bf16* xtb = xt + (size_t)b * NN * CC;
    const bf16* Ktb = Kt + (size_t)b * NRR * CC;
    const bf16* Vtb = Vt + (size_t)b * CC * NRR;        // [c][m] layout
    bf16* Otb = Ot + (size_t)b * NN * CC;
    int w = threadIdx.x >> 6, lane = threadIdx.x & 63;
    int quad = lane >> 4, l15 = lane & 15;
    int m0 = blockIdx.x * 64 + w * 16;
    float bh = bias[h];

    // fused Q-GEMM: Q(16x64) = xt(16x512) . Wq_head^T
    f32x4 qacc[4];
#pragma unroll
    for (int ct = 0; ct < 4; ++ct) qacc[ct] = fzero;
    {
        const bf16* axp = xtb + (long)(m0 + l15) * CC + quad * 8;
        const bf16* bwp = Wqb + (long)(h * DKK + l15) * CC + quad * 8;
#pragma unroll 2
        for (int k0 = 0; k0 < 512; k0 += 32) {
            bf16x8 a = ld8(axp + k0);
#pragma unroll
            for (int ct = 0; ct < 4; ++ct) {
                bf16x8 bv = ld8(bwp + k0 + ct * 16 * CC);
                qacc[ct] = __builtin_amdgcn_mfma_f32_16x16x32_bf16(a, bv, qacc[ct], 0, 0, 0);
            }
        }
    }
    // D-layout -> LDS -> A-layout; per-wave stripe, wave-internal fence only
    bf16* ql = &ptile[w][0];
#pragma unroll
    for (int ct = 0; ct < 4; ++ct)
#pragma unroll
        for (int r = 0; r < 4; ++r)
            ql[(quad * 4 + r) * 72 + ct * 16 + l15] = (bf16)qacc[ct][r];
    asm volatile("s_waitcnt lgkmcnt(0)" ::: "memory");
    __builtin_amdgcn_sched_barrier(0);
    bf16x8 aq0 = ld8(ql + l15 * 72 + quad * 8);
    bf16x8 aq1 = ld8(ql + l15 * 72 + 32 + quad * 8);

    f32x4 oacc[4];
    float mrow[4], lrow[4];
#pragma unroll
    for (int r = 0; r < 4; ++r) { mrow[r] = -1e30f; lrow[r] = 0.f; }
#pragma unroll
    for (int ct = 0; ct < 4; ++ct) oacc[ct] = fzero;

    const bf16* vbase0 = Vtb + (long)(h * DKK + l15) * NRR + quad * 8;

    for (int kt = 0; kt < 16; ++kt) {
        // S = Q K^T  (K direct from global, L2-resident)
        f32x4 s[4];
#pragma unroll
        for (int ct = 0; ct < 4; ++ct) s[ct] = fzero;
        const bf16* kp = Ktb + (long)(kt * 64 + l15) * CC + h * DKK + quad * 8;
        __builtin_amdgcn_s_setprio(1);
#pragma unroll
        for (int ct = 0; ct < 4; ++ct) {
            bf16x8 bk0 = ld8(kp + ct * 16 * CC);
            bf16x8 bk1 = ld8(kp + ct * 16 * CC + 32);
            s[ct] = __builtin_amdgcn_mfma_f32_16x16x32_bf16(aq0, bk0, s[ct], 0, 0, 0);
            s[ct] = __builtin_amdgcn_mfma_f32_16x16x32_bf16(aq1, bk1, s[ct], 0, 0, 0);
        }
        __builtin_amdgcn_s_setprio(0);

        // online softmax
        float pv[4][4], tmax[4], rsum[4], alpha[4];
#pragma unroll
        for (int ct = 0; ct < 4; ++ct)
#pragma unroll
            for (int r = 0; r < 4; ++r) pv[ct][r] = s[ct][r] * 0.125f + bh;
#pragma unroll
        for (int r = 0; r < 4; ++r)
            tmax[r] = fmaxf(fmaxf(pv[0][r], pv[1][r]), fmaxf(pv[2][r], pv[3][r]));
#pragma unroll
        for (int off = 1; off < 16; off <<= 1)
#pragma unroll
            for (int r = 0; r < 4; ++r)
                tmax[r] = fmaxf(tmax[r], __shfl_xor(tmax[r], off, 16));
#pragma unroll
        for (int r = 0; r < 4; ++r) {
            float mn = fmaxf(mrow[r], tmax[r]);
            alpha[r] = __expf(mrow[r] - mn);
            mrow[r] = mn;
            rsum[r] = 0.f;
        }
#pragma unroll
        for (int ct = 0; ct < 4; ++ct)
#pragma unroll
            for (int r = 0; r < 4; ++r) {
                pv[ct][r] = __expf(pv[ct][r] - mrow[r]);
                rsum[r] += pv[ct][r];
            }
#pragma unroll
        for (int off = 1; off < 16; off <<= 1)
#pragma unroll
            for (int r = 0; r < 4; ++r)
                rsum[r] += __shfl_xor(rsum[r], off, 16);
#pragma unroll
        for (int r = 0; r < 4; ++r) {
            lrow[r] = lrow[r] * alpha[r] + rsum[r];
#pragma unroll
            for (int ct = 0; ct < 4; ++ct) oacc[ct][r] *= alpha[r];
        }

        // P: D-layout -> LDS -> A-layout (per-wave; DS ops in-order per wave)
        bf16* pl = &ptile[w][0];
#pragma unroll
        for (int ct = 0; ct < 4; ++ct)
#pragma unroll
            for (int r = 0; r < 4; ++r)
                pl[(quad * 4 + r) * 72 + ct * 16 + l15] = (bf16)pv[ct][r];
        asm volatile("s_waitcnt lgkmcnt(0)" ::: "memory");
        __builtin_amdgcn_sched_barrier(0);

        // O += P V  (V^T direct from global, [c][m] layout)
        const bf16* vp = vbase0 + kt * 64;
        __builtin_amdgcn_s_setprio(1);
#pragma unroll
        for (int ks = 0; ks < 2; ++ks) {
            bf16x8 ap = ld8(&ptile[w][l15 * 72 + ks * 32 + quad * 8]);
#pragma unroll
            for (int ct = 0; ct < 4; ++ct) {
                bf16x8 bv = ld8(vp + (long)ct * 16 * NRR + ks * 32);
                oacc[ct] = __builtin_amdgcn_mfma_f32_16x16x32_bf16(ap, bv, oacc[ct], 0, 0, 0);
            }
        }
        __builtin_amdgcn_s_setprio(0);
    }

    float inv[4];
#pragma unroll
    for (int r = 0; r < 4; ++r) inv[r] = 1.f / lrow[r];
#pragma unroll
    for (int ct = 0; ct < 4; ++ct)
#pragma unroll
        for (int r = 0; r < 4; ++r)
            Otb[(long)(m0 + quad * 4 + r) * CC + h * DKK + ct * 16 + l15] =
                (bf16)(oacc[ct][r] * inv[r]);
}

// ---------------------------------------------------------------------------
// proj: p[b,o,n] = Wproj . ot[b,n,:]^T, fp32 out; blockIdx.z = batch
// ---------------------------------------------------------------------------
__global__ __launch_bounds__(256) void gemm_ntf(const bf16* __restrict__ A,
                                                const bf16* __restrict__ Bt,
                                                float* __restrict__ C) {
    const f32x4 fzero = {0.f, 0.f, 0.f, 0.f};
    int b = blockIdx.z;
    const bf16* Btb = Bt + (size_t)b * NN * CC;
    float* Cb = C + (size_t)b * CC * NN;
    int w = threadIdx.x >> 6, lane = threadIdx.x & 63;
    int quad = lane >> 4, l15 = lane & 15;
    long m0 = (long)blockIdx.x * 64 + w * 16;
    long n0 = (long)blockIdx.y * 64;
    f32x4 acc[4];
#pragma unroll
    for (int ct = 0; ct < 4; ++ct) acc[ct] = fzero;
    const bf16* Ap = A + (m0 + l15) * CC + quad * 8;
    const bf16* Bp = Btb + (n0 + l15) * CC + quad * 8;
#pragma unroll 2
    for (int k0 = 0; k0 < 512; k0 += 32) {
        bf16x8 a = ld8(Ap + k0);
#pragma unroll
        for (int ct = 0; ct < 4; ++ct) {
            bf16x8 bv = ld8(Bp + k0 + (long)ct * 16 * CC);
            acc[ct] = __builtin_amdgcn_mfma_f32_16x16x32_bf16(a, bv, acc[ct], 0, 0, 0);
        }
    }
#pragma unroll
    for (int ct = 0; ct < 4; ++ct)
#pragma unroll
        for (int r = 0; r < 4; ++r)
            Cb[(m0 + quad * 4 + r) * NN + n0 + ct * 16 + l15] = acc[ct][r];
}

// ---------------------------------------------------------------------------
// BN batch stats folded into scale/shift (fp32 p = d_out)
// ---------------------------------------------------------------------------
__global__ __launch_bounds__(256) void bnstats_kernel(const float* __restrict__ p,
                                                      const float* __restrict__ gamma,
                                                      const float* __restrict__ beta,
                                                      float* __restrict__ stats) {
    int c = blockIdx.x, t = threadIdx.x;
    float s = 0.f, ss = 0.f;
    for (int b = 0; b < BB; ++b) {
        const float* base = p + ((long)(b * CC + c)) * NN;
        for (int n = t; n < NN; n += 256) {
            float v = base[n];
            s += v; ss += v * v;
        }
    }
    __shared__ float rs[256], rss[256];
    rs[t] = s; rss[t] = ss;
    __syncthreads();
    for (int st = 128; st > 0; st >>= 1) {
        if (t < st) { rs[t] += rs[t + st]; rss[t] += rss[t + st]; }
        __syncthreads();
    }
    if (t == 0) {
        float mean = rs[0] * (1.f / 16384.f);
        float var = rss[0] * (1.f / 16384.f) - mean * mean;
        float rstd = rsqrtf(var + 1e-5f);
        float sc = gamma[c] * rstd;
        stats[c * 2] = sc;
        stats[c * 2 + 1] = beta[c] - mean * sc;
    }
}

// ---------------------------------------------------------------------------
// y = x + bn(p); LayerNorm over C per pixel; fp32 in-place on d_out
// ---------------------------------------------------------------------------
__global__ __launch_bounds__(256) void final_kernel(const float* __restrict__ x,
                                                    const float* __restrict__ p,
                                                    const float* __restrict__ stats,
                                                    const float* __restrict__ lg,
                                                    const float* __restrict__ lb,
                                                    float* __restrict__ out) {
    int blk = blockIdx.x;
    int b = blk >> 6;
    int pix0 = (blk & 63) * 64;
    int sub = threadIdx.x >> 6, px = threadIdx.x & 63;
    float s = 0.f, ss = 0.f;
    for (int i = 0; i < 128; ++i) {
        int c = i * 4 + sub;
        long idx = ((long)(b * CC + c)) * NN + pix0 + px;
        float y = x[idx] + p[idx] * stats[c * 2] + stats[c * 2 + 1];
        s += y; ss += y * y;
    }
    __shared__ float rs[4][64], rss[4][64];
    rs[sub][px] = s; rss[sub][px] = ss;
    __syncthreads();
    float sum = rs[0][px] + rs[1][px] + rs[2][px] + rs[3][px];
    float sq  = rss[0][px] + rss[1][px] + rss[2][px] + rss[3][px];
    float mu = sum * (1.f / 512.f);
    float var = sq * (1.f / 512.f) - mu * mu;
    float rstd = rsqrtf(var + 1e-5f);
    for (int i = 0; i < 128; ++i) {
        int c = i * 4 + sub;
        long idx = ((long)(b * CC + c)) * NN + pix0 + px;
        float y = x[idx] + p[idx] * stats[c * 2] + stats[c * 2 + 1];
        out[idx] = (y - mu) * rstd * lg[c] + lb[c];
    }
}

// ---------------------------------------------------------------------------
extern "C" void kernel_launch(void* const* d_in, const int* in_sizes, int n_in,
                              void* d_out, int out_size, void* d_ws, size_t ws_size,
                              hipStream_t stream) {
    (void)in_sizes; (void)n_in; (void)out_size;
    const float* x     = (const float*)d_in[0];
    const float* Wq    = (const float*)d_in[1];
    const float* Wk    = (const float*)d_in[2];
    const float* Wv    = (const float*)d_in[3];
    const float* bias  = (const float*)d_in[4];
    const float* Wproj = (const float*)d_in[5];
    const float* bng   = (const float*)d_in[6];
    const float* bnb   = (const float*)d_in[7];
    const float* lng   = (const float*)d_in[8];
    const float* lnb   = (const float*)d_in[9];
    float* out = (float*)d_out;   // fp32 output (verified R9)

    char* ws = (char*)d_ws;
    size_t off = 0;
    auto alloc = [&](size_t bytes) {
        char* pp = ws + off;
        off += (bytes + 255) & ~(size_t)255;
        return pp;
    };
    bf16* Wqb = (bf16*)alloc((size_t)CC * CC * 2);          // 0.52 MB
    bf16* Wpb = (bf16*)alloc((size_t)CC * CC * 2);          // 0.52 MB
    float* stats = (float*)alloc(512 * 2 * sizeof(float));

    // Layout A (fully batched) needs ~47 MB; layout B (per-batch) ~11.6 MB.
    size_t needA = off + ((size_t)CC * 2048 * 2 * 2)        // Wkf+Wvf 4.2 MB
                 + ((size_t)BB * NN * CC * 2)               // xt_all 16.8
                 + ((size_t)BB * NRR * CC * 2 * 2)          // kt+vt   8.4
                 + ((size_t)BB * NN * CC * 2) + 4096;       // ot_all 16.8

    if (ws_size >= needA) {
        // ---- layout A: one launch per stage, full batch in grid.z ----
        bf16* Wkf = (bf16*)alloc((size_t)CC * 2048 * 2);
        bf16* Wvf = (bf16*)alloc((size_t)CC * 2048 * 2);
        bf16* xt  = (bf16*)alloc((size_t)BB * NN * CC * 2);
        bf16* kt  = (bf16*)alloc((size_t)BB * NRR * CC * 2);
        bf16* vt  = (bf16*)alloc((size_t)BB * NRR * CC * 2);   // holds V^T [c][m]
        bf16* ot  = (bf16*)alloc((size_t)BB * NN * CC * 2);

        wcvt_kernel<<<1024, 256, 0, stream>>>(Wq, Wproj, Wqb, Wpb);
        wperm_kernel<<<4096, 256, 0, stream>>>(Wk, Wv, Wkf, Wvf);
        transpose_kernel<<<dim3(64, 8, BB), 256, 0, stream>>>(x, xt);
        gemm_kv<<<dim3(16, 8, BB * 2), 256, 0, stream>>>(xt, Wkf, Wvf, kt, vt);
        attn_kernel<<<dim3(64, NHH, BB), 256, 0, stream>>>(xt, Wqb, kt, vt, bias, ot);
        gemm_ntf<<<dim3(8, 64, BB), 256, 0, stream>>>(Wpb, ot, out);
    } else {
        // ---- layout B: per-batch loop, Wkf/Wvf overlay out slice 3 ----
        bf16* Wkf = (bf16*)(out + (size_t)3 * CC * NN);
        bf16* Wvf = Wkf + (size_t)CC * 2048;
        bf16* xt = (bf16*)alloc((size_t)NN * CC * 2);
        bf16* kt = (bf16*)alloc((size_t)NRR * CC * 2);
        bf16* vt = (bf16*)alloc((size_t)NRR * CC * 2);         // V^T [c][m]
        bf16* ot = (bf16*)alloc((size_t)NN * CC * 2);

        wcvt_kernel<<<1024, 256, 0, stream>>>(Wq, Wproj, Wqb, Wpb);
        wperm_kernel<<<4096, 256, 0, stream>>>(Wk, Wv, Wkf, Wvf);
        for (int b = 0; b < BB; ++b) {
            const float* xb = x + (size_t)b * CC * NN;
            float* pb = out + (size_t)b * CC * NN;
            transpose_kernel<<<dim3(64, 8, 1), 256, 0, stream>>>(xb, xt);
            gemm_kv<<<dim3(16, 8, 2), 256, 0, stream>>>(xt, Wkf, Wvf, kt, vt);
            attn_kernel<<<dim3(64, NHH, 1), 256, 0, stream>>>(xt, Wqb, kt, vt, bias, ot);
            gemm_ntf<<<dim3(8, 64, 1), 256, 0, stream>>>(Wpb, ot, pb);
        }
    }

    bnstats_kernel<<<512, 256, 0, stream>>>(out, bng, bnb, stats);
    final_kernel<<<256, 256, 0, stream>>>(x, out, stats, lng, lnb, out);
}

// Round 3
// 678.239 us; speedup vs baseline: 1.0043x; 1.0043x over previous
//
#include <hip/hip_runtime.h>
#include <hip/hip_bf16.h>
#include <cmath>

typedef __bf16 bf16;
typedef __bf16 bf16x8 __attribute__((ext_vector_type(8)));
typedef float f32x4 __attribute__((ext_vector_type(4)));

#define BB 4
#define CC 512
#define NN 4096      // 64*64 spatial
#define NRR 1024     // 32*32 spatial (stride-2)
#define NHH 8
#define DKK 64

static __device__ __forceinline__ bf16x8 ld8(const bf16* p) {
    return *reinterpret_cast<const bf16x8*>(p);
}

// ---------------------------------------------------------------------------
// weight convert / permute (fp32 -> bf16)
// ---------------------------------------------------------------------------
__global__ __launch_bounds__(256) void wcvt_kernel(const float* __restrict__ Wq,
                                                   const float* __restrict__ Wp,
                                                   bf16* __restrict__ Wqb,
                                                   bf16* __restrict__ Wpb) {
    int e = blockIdx.x * 256 + threadIdx.x;   // 262144
    Wqb[e] = (bf16)Wq[e];
    Wpb[e] = (bf16)Wp[e];
}

__global__ __launch_bounds__(256) void wperm_kernel(const float* __restrict__ Wk,
                                                    const float* __restrict__ Wv,
                                                    bf16* __restrict__ Wkf,
                                                    bf16* __restrict__ Wvf) {
    int e = blockIdx.x * 256 + threadIdx.x;   // 512*2048
    int o = e >> 11, q = (e >> 9) & 3, ci = e & 511;
    int src = o * 2048 + ci * 4 + q;
    Wkf[e] = (bf16)Wk[src];
    Wvf[e] = (bf16)Wv[src];
}

// ---------------------------------------------------------------------------
// x (b,C,N) fp32 -> xt (b,N,C) bf16; blockIdx.z = batch
// ---------------------------------------------------------------------------
__global__ __launch_bounds__(256) void transpose_kernel(const float* __restrict__ x,
                                                        bf16* __restrict__ xt) {
    __shared__ bf16 tile[64][65];
    int b = blockIdx.z;
    const float* xb = x + (size_t)b * CC * NN;
    bf16* xtb = xt + (size_t)b * NN * CC;
    int n0 = blockIdx.x * 64, c0 = blockIdx.y * 64;
    int tr = threadIdx.x >> 6, tc = threadIdx.x & 63;
#pragma unroll
    for (int i = 0; i < 64; i += 4)
        tile[tc][i + tr] = (bf16)xb[(long)(c0 + i + tr) * NN + n0 + tc];
    __syncthreads();
#pragma unroll
    for (int i = 0; i < 64; i += 4)
        xtb[(long)(n0 + i + tr) * CC + c0 + tc] = tile[i + tr][tc];
}

// ---------------------------------------------------------------------------
// K/V GEMM, im2col fused; blockIdx.z = b*2 + (0=K,1=V)
// K written key-major [m][C]; V written TRANSPOSED [c][m] so the attention
// PV step can read B-fragments straight from global (L2-resident).
// ---------------------------------------------------------------------------
__global__ __launch_bounds__(256) void gemm_kv(const bf16* __restrict__ xt,
                                               const bf16* __restrict__ Wkf,
                                               const bf16* __restrict__ Wvf,
                                               bf16* __restrict__ kt,
                                               bf16* __restrict__ vt) {
    __shared__ __align__(16) bf16 ttile[64][72];   // V-transpose staging
    const f32x4 fzero = {0.f, 0.f, 0.f, 0.f};
    int z = blockIdx.z;
    int b = z >> 1, kv = z & 1;
    const bf16* xtb = xt + (size_t)b * NN * CC;
    const bf16* Wf = kv ? Wvf : Wkf;
    int w = threadIdx.x >> 6, lane = threadIdx.x & 63;
    int quad = lane >> 4, l15 = lane & 15;
    int m0 = blockIdx.x * 64 + w * 16;
    long n0 = (long)blockIdx.y * 64;
    int m2 = m0 + l15;
    int i2 = m2 >> 5, j2 = m2 & 31;
    const bf16* ap[4];
#pragma unroll
    for (int q = 0; q < 4; ++q) {
        int n = (2 * i2 + (q >> 1)) * 64 + 2 * j2 + (q & 1);
        ap[q] = xtb + (long)n * CC + quad * 8;
    }
    const bf16* Bp = Wf + (n0 + l15) * 2048 + quad * 8;
    f32x4 acc[4];
#pragma unroll
    for (int ct = 0; ct < 4; ++ct) acc[ct] = fzero;
#pragma unroll
    for (int q = 0; q < 4; ++q) {
        const bf16* aq = ap[q];
        const bf16* bq = Bp + q * 512;
#pragma unroll 2
        for (int kk = 0; kk < 512; kk += 32) {
            bf16x8 a = ld8(aq + kk);
#pragma unroll
            for (int ct = 0; ct < 4; ++ct) {
                bf16x8 bv = ld8(bq + kk + ct * 16 * 2048);
                acc[ct] = __builtin_amdgcn_mfma_f32_16x16x32_bf16(a, bv, acc[ct], 0, 0, 0);
            }
        }
    }
    if (!kv) {
        // K: key-major [m][C]
        bf16* Ct = kt + (size_t)b * NRR * CC;
#pragma unroll
        for (int ct = 0; ct < 4; ++ct)
#pragma unroll
            for (int r = 0; r < 4; ++r)
                Ct[(long)(m0 + quad * 4 + r) * CC + n0 + ct * 16 + l15] = (bf16)acc[ct][r];
    } else {
        // V^T: channel-major [c][m]; transpose the 64x64 tile through LDS
        bf16* Ct = vt + (size_t)b * CC * NRR;
#pragma unroll
        for (int ct = 0; ct < 4; ++ct)
#pragma unroll
            for (int r = 0; r < 4; ++r)
                ttile[ct * 16 + l15][w * 16 + quad * 4 + r] = (bf16)acc[ct][r];
        __syncthreads();
        int row = threadIdx.x >> 2, seg = threadIdx.x & 3;   // 64 rows x 4 segs
        bf16x8 v0 = ld8(&ttile[row][seg * 16]);
        bf16x8 v1 = ld8(&ttile[row][seg * 16 + 8]);
        bf16* dst = Ct + (n0 + row) * NRR + (long)blockIdx.x * 64 + seg * 16;
        *reinterpret_cast<bf16x8*>(dst) = v0;
        *reinterpret_cast<bf16x8*>(dst + 8) = v1;
    }
}

// ---------------------------------------------------------------------------
// flash attention with fused Q-GEMM; blockIdx.z = batch
// V prefetched into VGPRs at iteration top (T14): its L2 latency hides under
// QK^T + softmax. No block barriers in the main loop.
// ---------------------------------------------------------------------------
__global__ __launch_bounds__(256) void attn_kernel(const bf16* __restrict__ xt,
                                                   const bf16* __restrict__ Wqb,
                                                   const bf16* __restrict__ Kt,
                                                   const bf16* __restrict__ Vt,
                                                   const float* __restrict__ bias,
                                                   bf16* __restrict__ Ot) {
    __shared__ __align__(16) bf16 ptile[4][16 * 72];    // per-wave Q/P stripe
    const f32x4 fzero = {0.f, 0.f, 0.f, 0.f};
    int b = blockIdx.z, h = blockIdx.y;
    const bf16* xtb = xt + (size_t)b * NN * CC;
    const bf16* Ktb = Kt + (size_t)b * NRR * CC;
    const bf16* Vtb = Vt + (size_t)b * CC * NRR;        // [c][m] layout
    bf16* Otb = Ot + (size_t)b * NN * CC;
    int w = threadIdx.x >> 6, lane = threadIdx.x & 63;
    int quad = lane >> 4, l15 = lane & 15;
    int m0 = blockIdx.x * 64 + w * 16;
    float bh = bias[h];

    // fused Q-GEMM: Q(16x64) = xt(16x512) . Wq_head^T
    f32x4 qacc[4];
#pragma unroll
    for (int ct = 0; ct < 4; ++ct) qacc[ct] = fzero;
    {
        const bf16* axp = xtb + (long)(m0 + l15) * CC + quad * 8;
        const bf16* bwp = Wqb + (long)(h * DKK + l15) * CC + quad * 8;
#pragma unroll 2
        for (int k0 = 0; k0 < 512; k0 += 32) {
            bf16x8 a = ld8(axp + k0);
#pragma unroll
            for (int ct = 0; ct < 4; ++ct) {
                bf16x8 bv = ld8(bwp + k0 + ct * 16 * CC);
                qacc[ct] = __builtin_amdgcn_mfma_f32_16x16x32_bf16(a, bv, qacc[ct], 0, 0, 0);
            }
        }
    }
    // D-layout -> LDS -> A-layout; per-wave stripe, wave-internal fence only
    bf16* ql = &ptile[w][0];
#pragma unroll
    for (int ct = 0; ct < 4; ++ct)
#pragma unroll
        for (int r = 0; r < 4; ++r)
            ql[(quad * 4 + r) * 72 + ct * 16 + l15] = (bf16)qacc[ct][r];
    asm volatile("s_waitcnt lgkmcnt(0)" ::: "memory");
    __builtin_amdgcn_sched_barrier(0);
    bf16x8 aq0 = ld8(ql + l15 * 72 + quad * 8);
    bf16x8 aq1 = ld8(ql + l15 * 72 + 32 + quad * 8);

    f32x4 oacc[4];
    float mrow[4], lrow[4];
#pragma unroll
    for (int r = 0; r < 4; ++r) { mrow[r] = -1e30f; lrow[r] = 0.f; }
#pragma unroll
    for (int ct = 0; ct < 4; ++ct) oacc[ct] = fzero;

    const bf16* vbase0 = Vtb + (long)(h * DKK + l15) * NRR + quad * 8;

    for (int kt = 0; kt < 16; ++kt) {
        // ---- V prefetch into registers (issued BEFORE QK^T; latency hides
        //      under QK^T + softmax; program order pins it ahead of fences)
        bf16x8 vreg[8];
        const bf16* vp = vbase0 + kt * 64;
#pragma unroll
        for (int ks = 0; ks < 2; ++ks)
#pragma unroll
            for (int ct = 0; ct < 4; ++ct)
                vreg[ks * 4 + ct] = ld8(vp + (long)ct * 16 * NRR + ks * 32);

        // S = Q K^T  (K direct from global, L2-resident)
        f32x4 s[4];
#pragma unroll
        for (int ct = 0; ct < 4; ++ct) s[ct] = fzero;
        const bf16* kp = Ktb + (long)(kt * 64 + l15) * CC + h * DKK + quad * 8;
        __builtin_amdgcn_s_setprio(1);
#pragma unroll
        for (int ct = 0; ct < 4; ++ct) {
            bf16x8 bk0 = ld8(kp + ct * 16 * CC);
            bf16x8 bk1 = ld8(kp + ct * 16 * CC + 32);
            s[ct] = __builtin_amdgcn_mfma_f32_16x16x32_bf16(aq0, bk0, s[ct], 0, 0, 0);
            s[ct] = __builtin_amdgcn_mfma_f32_16x16x32_bf16(aq1, bk1, s[ct], 0, 0, 0);
        }
        __builtin_amdgcn_s_setprio(0);

        // online softmax
        float pv[4][4], tmax[4], rsum[4], alpha[4];
#pragma unroll
        for (int ct = 0; ct < 4; ++ct)
#pragma unroll
            for (int r = 0; r < 4; ++r) pv[ct][r] = s[ct][r] * 0.125f + bh;
#pragma unroll
        for (int r = 0; r < 4; ++r)
            tmax[r] = fmaxf(fmaxf(pv[0][r], pv[1][r]), fmaxf(pv[2][r], pv[3][r]));
#pragma unroll
        for (int off = 1; off < 16; off <<= 1)
#pragma unroll
            for (int r = 0; r < 4; ++r)
                tmax[r] = fmaxf(tmax[r], __shfl_xor(tmax[r], off, 16));
#pragma unroll
        for (int r = 0; r < 4; ++r) {
            float mn = fmaxf(mrow[r], tmax[r]);
            alpha[r] = __expf(mrow[r] - mn);
            mrow[r] = mn;
            rsum[r] = 0.f;
        }
#pragma unroll
        for (int ct = 0; ct < 4; ++ct)
#pragma unroll
            for (int r = 0; r < 4; ++r) {
                pv[ct][r] = __expf(pv[ct][r] - mrow[r]);
                rsum[r] += pv[ct][r];
            }
#pragma unroll
        for (int off = 1; off < 16; off <<= 1)
#pragma unroll
            for (int r = 0; r < 4; ++r)
                rsum[r] += __shfl_xor(rsum[r], off, 16);
#pragma unroll
        for (int r = 0; r < 4; ++r) {
            lrow[r] = lrow[r] * alpha[r] + rsum[r];
#pragma unroll
            for (int ct = 0; ct < 4; ++ct) oacc[ct][r] *= alpha[r];
        }

        // P: D-layout -> LDS -> A-layout (per-wave; DS ops in-order per wave)
        bf16* pl = &ptile[w][0];
#pragma unroll
        for (int ct = 0; ct < 4; ++ct)
#pragma unroll
            for (int r = 0; r < 4; ++r)
                pl[(quad * 4 + r) * 72 + ct * 16 + l15] = (bf16)pv[ct][r];
        asm volatile("s_waitcnt lgkmcnt(0)" ::: "memory");
        __builtin_amdgcn_sched_barrier(0);

        // O += P V  (V already in registers)
        __builtin_amdgcn_s_setprio(1);
#pragma unroll
        for (int ks = 0; ks < 2; ++ks) {
            bf16x8 ap = ld8(&ptile[w][l15 * 72 + ks * 32 + quad * 8]);
#pragma unroll
            for (int ct = 0; ct < 4; ++ct)
                oacc[ct] = __builtin_amdgcn_mfma_f32_16x16x32_bf16(ap, vreg[ks * 4 + ct], oacc[ct], 0, 0, 0);
        }
        __builtin_amdgcn_s_setprio(0);
    }

    float inv[4];
#pragma unroll
    for (int r = 0; r < 4; ++r) inv[r] = 1.f / lrow[r];
#pragma unroll
    for (int ct = 0; ct < 4; ++ct)
#pragma unroll
        for (int r = 0; r < 4; ++r)
            Otb[(long)(m0 + quad * 4 + r) * CC + h * DKK + ct * 16 + l15] =
                (bf16)(oacc[ct][r] * inv[r]);
}

// ---------------------------------------------------------------------------
// proj: p[b,o,n] = Wproj . ot[b,n,:]^T, fp32 out; blockIdx.z = batch
// ---------------------------------------------------------------------------
__global__ __launch_bounds__(256) void gemm_ntf(const bf16* __restrict__ A,
                                                const bf16* __restrict__ Bt,
                                                float* __restrict__ C) {
    const f32x4 fzero = {0.f, 0.f, 0.f, 0.f};
    int b = blockIdx.z;
    const bf16* Btb = Bt + (size_t)b * NN * CC;
    float* Cb = C + (size_t)b * CC * NN;
    int w = threadIdx.x >> 6, lane = threadIdx.x & 63;
    int quad = lane >> 4, l15 = lane & 15;
    long m0 = (long)blockIdx.x * 64 + w * 16;
    long n0 = (long)blockIdx.y * 64;
    f32x4 acc[4];
#pragma unroll
    for (int ct = 0; ct < 4; ++ct) acc[ct] = fzero;
    const bf16* Ap = A + (m0 + l15) * CC + quad * 8;
    const bf16* Bp = Btb + (n0 + l15) * CC + quad * 8;
#pragma unroll 2
    for (int k0 = 0; k0 < 512; k0 += 32) {
        bf16x8 a = ld8(Ap + k0);
#pragma unroll
        for (int ct = 0; ct < 4; ++ct) {
            bf16x8 bv = ld8(Bp + k0 + (long)ct * 16 * CC);
            acc[ct] = __builtin_amdgcn_mfma_f32_16x16x32_bf16(a, bv, acc[ct], 0, 0, 0);
        }
    }
#pragma unroll
    for (int ct = 0; ct < 4; ++ct)
#pragma unroll
        for (int r = 0; r < 4; ++r)
            Cb[(m0 + quad * 4 + r) * NN + n0 + ct * 16 + l15] = acc[ct][r];
}

// ---------------------------------------------------------------------------
// BN batch stats folded into scale/shift (fp32 p = d_out)
// ---------------------------------------------------------------------------
__global__ __launch_bounds__(256) void bnstats_kernel(const float* __restrict__ p,
                                                      const float* __restrict__ gamma,
                                                      const float* __restrict__ beta,
                                                      float* __restrict__ stats) {
    int c = blockIdx.x, t = threadIdx.x;
    float s = 0.f, ss = 0.f;
    for (int b = 0; b < BB; ++b) {
        const float* base = p + ((long)(b * CC + c)) * NN;
        for (int n = t; n < NN; n += 256) {
            float v = base[n];
            s += v; ss += v * v;
        }
    }
    __shared__ float rs[256], rss[256];
    rs[t] = s; rss[t] = ss;
    __syncthreads();
    for (int st = 128; st > 0; st >>= 1) {
        if (t < st) { rs[t] += rs[t + st]; rss[t] += rss[t + st]; }
        __syncthreads();
    }
    if (t == 0) {
        float mean = rs[0] * (1.f / 16384.f);
        float var = rss[0] * (1.f / 16384.f) - mean * mean;
        float rstd = rsqrtf(var + 1e-5f);
        float sc = gamma[c] * rstd;
        stats[c * 2] = sc;
        stats[c * 2 + 1] = beta[c] - mean * sc;
    }
}

// ---------------------------------------------------------------------------
// y = x + bn(p); LayerNorm over C per pixel; fp32 in-place on d_out
// ---------------------------------------------------------------------------
__global__ __launch_bounds__(256) void final_kernel(const float* __restrict__ x,
                                                    const float* __restrict__ p,
                                                    const float* __restrict__ stats,
                                                    const float* __restrict__ lg,
                                                    const float* __restrict__ lb,
                                                    float* __restrict__ out) {
    int blk = blockIdx.x;
    int b = blk >> 6;
    int pix0 = (blk & 63) * 64;
    int sub = threadIdx.x >> 6, px = threadIdx.x & 63;
    float s = 0.f, ss = 0.f;
    for (int i = 0; i < 128; ++i) {
        int c = i * 4 + sub;
        long idx = ((long)(b * CC + c)) * NN + pix0 + px;
        float y = x[idx] + p[idx] * stats[c * 2] + stats[c * 2 + 1];
        s += y; ss += y * y;
    }
    __shared__ float rs[4][64], rss[4][64];
    rs[sub][px] = s; rss[sub][px] = ss;
    __syncthreads();
    float sum = rs[0][px] + rs[1][px] + rs[2][px] + rs[3][px];
    float sq  = rss[0][px] + rss[1][px] + rss[2][px] + rss[3][px];
    float mu = sum * (1.f / 512.f);
    float var = sq * (1.f / 512.f) - mu * mu;
    float rstd = rsqrtf(var + 1e-5f);
    for (int i = 0; i < 128; ++i) {
        int c = i * 4 + sub;
        long idx = ((long)(b * CC + c)) * NN + pix0 + px;
        float y = x[idx] + p[idx] * stats[c * 2] + stats[c * 2 + 1];
        out[idx] = (y - mu) * rstd * lg[c] + lb[c];
    }
}

// ---------------------------------------------------------------------------
extern "C" void kernel_launch(void* const* d_in, const int* in_sizes, int n_in,
                              void* d_out, int out_size, void* d_ws, size_t ws_size,
                              hipStream_t stream) {
    (void)in_sizes; (void)n_in; (void)out_size;
    const float* x     = (const float*)d_in[0];
    const float* Wq    = (const float*)d_in[1];
    const float* Wk    = (const float*)d_in[2];
    const float* Wv    = (const float*)d_in[3];
    const float* bias  = (const float*)d_in[4];
    const float* Wproj = (const float*)d_in[5];
    const float* bng   = (const float*)d_in[6];
    const float* bnb   = (const float*)d_in[7];
    const float* lng   = (const float*)d_in[8];
    const float* lnb   = (const float*)d_in[9];
    float* out = (float*)d_out;   // fp32 output (verified R9)

    char* ws = (char*)d_ws;
    size_t off = 0;
    auto alloc = [&](size_t bytes) {
        char* pp = ws + off;
        off += (bytes + 255) & ~(size_t)255;
        return pp;
    };
    bf16* Wqb = (bf16*)alloc((size_t)CC * CC * 2);          // 0.52 MB
    bf16* Wpb = (bf16*)alloc((size_t)CC * CC * 2);          // 0.52 MB
    float* stats = (float*)alloc(512 * 2 * sizeof(float));

    // Layout A (fully batched) needs ~47 MB; layout B (per-batch) ~11.6 MB.
    size_t needA = off + ((size_t)CC * 2048 * 2 * 2)        // Wkf+Wvf 4.2 MB
                 + ((size_t)BB * NN * CC * 2)               // xt_all 16.8
                 + ((size_t)BB * NRR * CC * 2 * 2)          // kt+vt   8.4
                 + ((size_t)BB * NN * CC * 2) + 4096;       // ot_all 16.8

    if (ws_size >= needA) {
        // ---- layout A: one launch per stage, full batch in grid.z ----
        bf16* Wkf = (bf16*)alloc((size_t)CC * 2048 * 2);
        bf16* Wvf = (bf16*)alloc((size_t)CC * 2048 * 2);
        bf16* xt  = (bf16*)alloc((size_t)BB * NN * CC * 2);
        bf16* kt  = (bf16*)alloc((size_t)BB * NRR * CC * 2);
        bf16* vt  = (bf16*)alloc((size_t)BB * NRR * CC * 2);   // holds V^T [c][m]
        bf16* ot  = (bf16*)alloc((size_t)BB * NN * CC * 2);

        wcvt_kernel<<<1024, 256, 0, stream>>>(Wq, Wproj, Wqb, Wpb);
        wperm_kernel<<<4096, 256, 0, stream>>>(Wk, Wv, Wkf, Wvf);
        transpose_kernel<<<dim3(64, 8, BB), 256, 0, stream>>>(x, xt);
        gemm_kv<<<dim3(16, 8, BB * 2), 256, 0, stream>>>(xt, Wkf, Wvf, kt, vt);
        attn_kernel<<<dim3(64, NHH, BB), 256, 0, stream>>>(xt, Wqb, kt, vt, bias, ot);
        gemm_ntf<<<dim3(8, 64, BB), 256, 0, stream>>>(Wpb, ot, out);
    } else {
        // ---- layout B: per-batch loop, Wkf/Wvf overlay out slice 3 ----
        bf16* Wkf = (bf16*)(out + (size_t)3 * CC * NN);
        bf16* Wvf = Wkf + (size_t)CC * 2048;
        bf16* xt = (bf16*)alloc((size_t)NN * CC * 2);
        bf16* kt = (bf16*)alloc((size_t)NRR * CC * 2);
        bf16* vt = (bf16*)alloc((size_t)NRR * CC * 2);         // V^T [c][m]
        bf16* ot = (bf16*)alloc((size_t)NN * CC * 2);

        wcvt_kernel<<<1024, 256, 0, stream>>>(Wq, Wproj, Wqb, Wpb);
        wperm_kernel<<<4096, 256, 0, stream>>>(Wk, Wv, Wkf, Wvf);
        for (int b = 0; b < BB; ++b) {
            const float* xb = x + (size_t)b * CC * NN;
            float* pb = out + (size_t)b * CC * NN;
            transpose_kernel<<<dim3(64, 8, 1), 256, 0, stream>>>(xb, xt);
            gemm_kv<<<dim3(16, 8, 2), 256, 0, stream>>>(xt, Wkf, Wvf, kt, vt);
            attn_kernel<<<dim3(64, NHH, 1), 256, 0, stream>>>(xt, Wqb, kt, vt, bias, ot);
            gemm_ntf<<<dim3(8, 64, 1), 256, 0, stream>>>(Wpb, ot, pb);
        }
    }

    bnstats_kernel<<<512, 256, 0, stream>>>(out, bng, bnb, stats);
    final_kernel<<<256, 256, 0, stream>>>(x, out, stats, lng, lnb, out);
}

// Round 4
// 592.112 us; speedup vs baseline: 1.1504x; 1.1455x over previous
//
#include <hip/hip_runtime.h>
#include <hip/hip_bf16.h>
#include <cmath>

typedef __bf16 bf16;
typedef __bf16 bf16x8 __attribute__((ext_vector_type(8)));
typedef float f32x4 __attribute__((ext_vector_type(4)));

#define BB 4
#define CC 512
#define NN 4096      // 64*64 spatial
#define NRR 1024     // 32*32 spatial (stride-2)
#define NHH 8
#define DKK 64

static __device__ __forceinline__ bf16x8 ld8(const bf16* p) {
    return *reinterpret_cast<const bf16x8*>(p);
}

// ---------------------------------------------------------------------------
// weight convert / permute (fp32 -> bf16)
// ---------------------------------------------------------------------------
__global__ __launch_bounds__(256) void wcvt_kernel(const float* __restrict__ Wq,
                                                   const float* __restrict__ Wp,
                                                   bf16* __restrict__ Wqb,
                                                   bf16* __restrict__ Wpb) {
    int e = blockIdx.x * 256 + threadIdx.x;   // 262144
    Wqb[e] = (bf16)Wq[e];
    Wpb[e] = (bf16)Wp[e];
}

__global__ __launch_bounds__(256) void wperm_kernel(const float* __restrict__ Wk,
                                                    const float* __restrict__ Wv,
                                                    bf16* __restrict__ Wkf,
                                                    bf16* __restrict__ Wvf) {
    int e = blockIdx.x * 256 + threadIdx.x;   // 512*2048
    int o = e >> 11, q = (e >> 9) & 3, ci = e & 511;
    int src = o * 2048 + ci * 4 + q;
    Wkf[e] = (bf16)Wk[src];
    Wvf[e] = (bf16)Wv[src];
}

// ---------------------------------------------------------------------------
// x (b,C,N) fp32 -> xt (b,N,C) bf16; blockIdx.z = batch
// ---------------------------------------------------------------------------
__global__ __launch_bounds__(256) void transpose_kernel(const float* __restrict__ x,
                                                        bf16* __restrict__ xt) {
    __shared__ bf16 tile[64][65];
    int b = blockIdx.z;
    const float* xb = x + (size_t)b * CC * NN;
    bf16* xtb = xt + (size_t)b * NN * CC;
    int n0 = blockIdx.x * 64, c0 = blockIdx.y * 64;
    int tr = threadIdx.x >> 6, tc = threadIdx.x & 63;
#pragma unroll
    for (int i = 0; i < 64; i += 4)
        tile[tc][i + tr] = (bf16)xb[(long)(c0 + i + tr) * NN + n0 + tc];
    __syncthreads();
#pragma unroll
    for (int i = 0; i < 64; i += 4)
        xtb[(long)(n0 + i + tr) * CC + c0 + tc] = tile[i + tr][tc];
}

// ---------------------------------------------------------------------------
// K/V GEMM, im2col fused; blockIdx.z = b*2 + (0=K,1=V)
// K written key-major [m][C]; V written TRANSPOSED [c][m] so attention can
// stage V tiles into LDS with vectorized copies (no transpose, no scatter).
// ---------------------------------------------------------------------------
__global__ __launch_bounds__(256) void gemm_kv(const bf16* __restrict__ xt,
                                               const bf16* __restrict__ Wkf,
                                               const bf16* __restrict__ Wvf,
                                               bf16* __restrict__ kt,
                                               bf16* __restrict__ vt) {
    __shared__ __align__(16) bf16 ttile[64][72];   // V-transpose staging
    const f32x4 fzero = {0.f, 0.f, 0.f, 0.f};
    int z = blockIdx.z;
    int b = z >> 1, kv = z & 1;
    const bf16* xtb = xt + (size_t)b * NN * CC;
    const bf16* Wf = kv ? Wvf : Wkf;
    int w = threadIdx.x >> 6, lane = threadIdx.x & 63;
    int quad = lane >> 4, l15 = lane & 15;
    int m0 = blockIdx.x * 64 + w * 16;
    long n0 = (long)blockIdx.y * 64;
    int m2 = m0 + l15;
    int i2 = m2 >> 5, j2 = m2 & 31;
    const bf16* ap[4];
#pragma unroll
    for (int q = 0; q < 4; ++q) {
        int n = (2 * i2 + (q >> 1)) * 64 + 2 * j2 + (q & 1);
        ap[q] = xtb + (long)n * CC + quad * 8;
    }
    const bf16* Bp = Wf + (n0 + l15) * 2048 + quad * 8;
    f32x4 acc[4];
#pragma unroll
    for (int ct = 0; ct < 4; ++ct) acc[ct] = fzero;
#pragma unroll
    for (int q = 0; q < 4; ++q) {
        const bf16* aq = ap[q];
        const bf16* bq = Bp + q * 512;
#pragma unroll 2
        for (int kk = 0; kk < 512; kk += 32) {
            bf16x8 a = ld8(aq + kk);
#pragma unroll
            for (int ct = 0; ct < 4; ++ct) {
                bf16x8 bv = ld8(bq + kk + ct * 16 * 2048);
                acc[ct] = __builtin_amdgcn_mfma_f32_16x16x32_bf16(a, bv, acc[ct], 0, 0, 0);
            }
        }
    }
    if (!kv) {
        // K: key-major [m][C]
        bf16* Ct = kt + (size_t)b * NRR * CC;
#pragma unroll
        for (int ct = 0; ct < 4; ++ct)
#pragma unroll
            for (int r = 0; r < 4; ++r)
                Ct[(long)(m0 + quad * 4 + r) * CC + n0 + ct * 16 + l15] = (bf16)acc[ct][r];
    } else {
        // V^T: channel-major [c][m]; transpose the 64x64 tile through LDS
        bf16* Ct = vt + (size_t)b * CC * NRR;
#pragma unroll
        for (int ct = 0; ct < 4; ++ct)
#pragma unroll
            for (int r = 0; r < 4; ++r)
                ttile[ct * 16 + l15][w * 16 + quad * 4 + r] = (bf16)acc[ct][r];
        __syncthreads();
        int row = threadIdx.x >> 2, seg = threadIdx.x & 3;   // 64 rows x 4 segs
        bf16x8 v0 = ld8(&ttile[row][seg * 16]);
        bf16x8 v1 = ld8(&ttile[row][seg * 16 + 8]);
        bf16* dst = Ct + (n0 + row) * NRR + (long)blockIdx.x * 64 + seg * 16;
        *reinterpret_cast<bf16x8*>(dst) = v0;
        *reinterpret_cast<bf16x8*>(dst + 8) = v1;
    }
}

// ---------------------------------------------------------------------------
// flash attention with fused Q-GEMM; blockIdx.z = batch
// R0 skeleton (barriered, LDS-staged V) with: double-buffered vtile (ONE
// __syncthreads per iter), vectorized V^T staging (issue-early/write-late),
// chunk-XOR swizzle on vtile, per-wave fence for the P round-trip.
// ---------------------------------------------------------------------------
__global__ __launch_bounds__(256) void attn_kernel(const bf16* __restrict__ xt,
                                                   const bf16* __restrict__ Wqb,
                                                   const bf16* __restrict__ Kt,
                                                   const bf16* __restrict__ Vt,
                                                   const float* __restrict__ bias,
                                                   bf16* __restrict__ Ot) {
    __shared__ __align__(16) bf16 vbuf[2][64 * 64];     // [d][m], chunk-swizzled
    __shared__ __align__(16) bf16 ptile[4][16 * 72];    // per-wave Q/P stripe
    const f32x4 fzero = {0.f, 0.f, 0.f, 0.f};
    int b = blockIdx.z, h = blockIdx.y;
    const bf16* xtb = xt + (size_t)b * NN * CC;
    const bf16* Ktb = Kt + (size_t)b * NRR * CC;
    const bf16* Vtb = Vt + (size_t)b * CC * NRR;        // [c][m] layout
    bf16* Otb = Ot + (size_t)b * NN * CC;
    int w = threadIdx.x >> 6, lane = threadIdx.x & 63;
    int quad = lane >> 4, l15 = lane & 15;
    int m0 = blockIdx.x * 64 + w * 16;
    float bh = bias[h];

    // staging geometry: thread covers (d0, chunk) and (d0+32, chunk)
    int sd0 = threadIdx.x >> 3, schunk = threadIdx.x & 7;
    const bf16* vsrc0 = Vtb + (long)(h * DKK + sd0) * NRR + schunk * 8;
    const bf16* vsrc1 = vsrc0 + (long)32 * NRR;
    int soff0 = sd0 * 64 + ((schunk ^ (sd0 & 7)) * 8);
    int soff1 = (sd0 + 32) * 64 + ((schunk ^ (sd0 & 7)) * 8);

    // fused Q-GEMM: Q(16x64) = xt(16x512) . Wq_head^T
    f32x4 qacc[4];
#pragma unroll
    for (int ct = 0; ct < 4; ++ct) qacc[ct] = fzero;
    {
        const bf16* axp = xtb + (long)(m0 + l15) * CC + quad * 8;
        const bf16* bwp = Wqb + (long)(h * DKK + l15) * CC + quad * 8;
#pragma unroll 2
        for (int k0 = 0; k0 < 512; k0 += 32) {
            bf16x8 a = ld8(axp + k0);
#pragma unroll
            for (int ct = 0; ct < 4; ++ct) {
                bf16x8 bv = ld8(bwp + k0 + ct * 16 * CC);
                qacc[ct] = __builtin_amdgcn_mfma_f32_16x16x32_bf16(a, bv, qacc[ct], 0, 0, 0);
            }
        }
    }
    // D-layout -> LDS -> A-layout; per-wave stripe, wave-internal fence only
    bf16* ql = &ptile[w][0];
#pragma unroll
    for (int ct = 0; ct < 4; ++ct)
#pragma unroll
        for (int r = 0; r < 4; ++r)
            ql[(quad * 4 + r) * 72 + ct * 16 + l15] = (bf16)qacc[ct][r];
    asm volatile("s_waitcnt lgkmcnt(0)" ::: "memory");
    __builtin_amdgcn_sched_barrier(0);
    bf16x8 aq0 = ld8(ql + l15 * 72 + quad * 8);
    bf16x8 aq1 = ld8(ql + l15 * 72 + 32 + quad * 8);

    // prologue: stage V tile 0 into vbuf[0]
    {
        bf16x8 s0 = ld8(vsrc0);
        bf16x8 s1 = ld8(vsrc1);
        *reinterpret_cast<bf16x8*>(&vbuf[0][0] + soff0) = s0;
        *reinterpret_cast<bf16x8*>(&vbuf[0][0] + soff1) = s1;
    }
    __syncthreads();

    f32x4 oacc[4];
    float mrow[4], lrow[4];
#pragma unroll
    for (int r = 0; r < 4; ++r) { mrow[r] = -1e30f; lrow[r] = 0.f; }
#pragma unroll
    for (int ct = 0; ct < 4; ++ct) oacc[ct] = fzero;

    for (int kt = 0; kt < 16; ++kt) {
        int cur = kt & 1;
        // ---- issue next-tile V loads early (latency hides under QK^T+softmax)
        bf16x8 sv0, sv1;
        if (kt < 15) {
            sv0 = ld8(vsrc0 + (kt + 1) * 64);
            sv1 = ld8(vsrc1 + (kt + 1) * 64);
        }

        // S = Q K^T  (K direct from global, L2-resident)
        f32x4 s[4];
#pragma unroll
        for (int ct = 0; ct < 4; ++ct) s[ct] = fzero;
        const bf16* kp = Ktb + (long)(kt * 64 + l15) * CC + h * DKK + quad * 8;
#pragma unroll
        for (int ct = 0; ct < 4; ++ct) {
            bf16x8 bk0 = ld8(kp + ct * 16 * CC);
            bf16x8 bk1 = ld8(kp + ct * 16 * CC + 32);
            s[ct] = __builtin_amdgcn_mfma_f32_16x16x32_bf16(aq0, bk0, s[ct], 0, 0, 0);
            s[ct] = __builtin_amdgcn_mfma_f32_16x16x32_bf16(aq1, bk1, s[ct], 0, 0, 0);
        }

        // online softmax
        float pv[4][4], tmax[4], rsum[4], alpha[4];
#pragma unroll
        for (int ct = 0; ct < 4; ++ct)
#pragma unroll
            for (int r = 0; r < 4; ++r) pv[ct][r] = s[ct][r] * 0.125f + bh;
#pragma unroll
        for (int r = 0; r < 4; ++r)
            tmax[r] = fmaxf(fmaxf(pv[0][r], pv[1][r]), fmaxf(pv[2][r], pv[3][r]));
#pragma unroll
        for (int off = 1; off < 16; off <<= 1)
#pragma unroll
            for (int r = 0; r < 4; ++r)
                tmax[r] = fmaxf(tmax[r], __shfl_xor(tmax[r], off, 16));
#pragma unroll
        for (int r = 0; r < 4; ++r) {
            float mn = fmaxf(mrow[r], tmax[r]);
            alpha[r] = __expf(mrow[r] - mn);
            mrow[r] = mn;
            rsum[r] = 0.f;
        }
#pragma unroll
        for (int ct = 0; ct < 4; ++ct)
#pragma unroll
            for (int r = 0; r < 4; ++r) {
                pv[ct][r] = __expf(pv[ct][r] - mrow[r]);
                rsum[r] += pv[ct][r];
            }
#pragma unroll
        for (int off = 1; off < 16; off <<= 1)
#pragma unroll
            for (int r = 0; r < 4; ++r)
                rsum[r] += __shfl_xor(rsum[r], off, 16);
#pragma unroll
        for (int r = 0; r < 4; ++r) {
            lrow[r] = lrow[r] * alpha[r] + rsum[r];
#pragma unroll
            for (int ct = 0; ct < 4; ++ct) oacc[ct][r] *= alpha[r];
        }

        // P: D-layout -> LDS -> A-layout (per-wave; fence pins cross-lane RAW)
        bf16* pl = &ptile[w][0];
#pragma unroll
        for (int ct = 0; ct < 4; ++ct)
#pragma unroll
            for (int r = 0; r < 4; ++r)
                pl[(quad * 4 + r) * 72 + ct * 16 + l15] = (bf16)pv[ct][r];
        asm volatile("s_waitcnt lgkmcnt(0)" ::: "memory");
        __builtin_amdgcn_sched_barrier(0);

        // O += P V  (V from current LDS buffer, swizzled)
        const bf16* vb = &vbuf[cur][0];
#pragma unroll
        for (int ks = 0; ks < 2; ++ks) {
            bf16x8 ap = ld8(&ptile[w][l15 * 72 + ks * 32 + quad * 8]);
#pragma unroll
            for (int ct = 0; ct < 4; ++ct) {
                int d = ct * 16 + l15;
                bf16x8 bv = ld8(vb + d * 64 + (((ks * 4 + quad) ^ (d & 7)) * 8));
                oacc[ct] = __builtin_amdgcn_mfma_f32_16x16x32_bf16(ap, bv, oacc[ct], 0, 0, 0);
            }
        }

        // ---- write staged V for tile kt+1 into the other buffer
        if (kt < 15) {
            bf16* wb = &vbuf[cur ^ 1][0];
            *reinterpret_cast<bf16x8*>(wb + soff0) = sv0;
            *reinterpret_cast<bf16x8*>(wb + soff1) = sv1;
        }
        __syncthreads();
    }

    float inv[4];
#pragma unroll
    for (int r = 0; r < 4; ++r) inv[r] = 1.f / lrow[r];
#pragma unroll
    for (int ct = 0; ct < 4; ++ct)
#pragma unroll
        for (int r = 0; r < 4; ++r)
            Otb[(long)(m0 + quad * 4 + r) * CC + h * DKK + ct * 16 + l15] =
                (bf16)(oacc[ct][r] * inv[r]);
}

// ---------------------------------------------------------------------------
// proj: p[b,o,n] = Wproj . ot[b,n,:]^T, fp32 out; blockIdx.z = batch
// ---------------------------------------------------------------------------
__global__ __launch_bounds__(256) void gemm_ntf(const bf16* __restrict__ A,
                                                const bf16* __restrict__ Bt,
                                                float* __restrict__ C) {
    const f32x4 fzero = {0.f, 0.f, 0.f, 0.f};
    int b = blockIdx.z;
    const bf16* Btb = Bt + (size_t)b * NN * CC;
    float* Cb = C + (size_t)b * CC * NN;
    int w = threadIdx.x >> 6, lane = threadIdx.x & 63;
    int quad = lane >> 4, l15 = lane & 15;
    long m0 = (long)blockIdx.x * 64 + w * 16;
    long n0 = (long)blockIdx.y * 64;
    f32x4 acc[4];
#pragma unroll
    for (int ct = 0; ct < 4; ++ct) acc[ct] = fzero;
    const bf16* Ap = A + (m0 + l15) * CC + quad * 8;
    const bf16* Bp = Btb + (n0 + l15) * CC + quad * 8;
#pragma unroll 2
    for (int k0 = 0; k0 < 512; k0 += 32) {
        bf16x8 a = ld8(Ap + k0);
#pragma unroll
        for (int ct = 0; ct < 4; ++ct) {
            bf16x8 bv = ld8(Bp + k0 + (long)ct * 16 * CC);
            acc[ct] = __builtin_amdgcn_mfma_f32_16x16x32_bf16(a, bv, acc[ct], 0, 0, 0);
        }
    }
#pragma unroll
    for (int ct = 0; ct < 4; ++ct)
#pragma unroll
        for (int r = 0; r < 4; ++r)
            Cb[(m0 + quad * 4 + r) * NN + n0 + ct * 16 + l15] = acc[ct][r];
}

// ---------------------------------------------------------------------------
// BN batch stats folded into scale/shift (fp32 p = d_out)
// ---------------------------------------------------------------------------
__global__ __launch_bounds__(256) void bnstats_kernel(const float* __restrict__ p,
                                                      const float* __restrict__ gamma,
                                                      const float* __restrict__ beta,
                                                      float* __restrict__ stats) {
    int c = blockIdx.x, t = threadIdx.x;
    float s = 0.f, ss = 0.f;
    for (int b = 0; b < BB; ++b) {
        const float* base = p + ((long)(b * CC + c)) * NN;
        for (int n = t; n < NN; n += 256) {
            float v = base[n];
            s += v; ss += v * v;
        }
    }
    __shared__ float rs[256], rss[256];
    rs[t] = s; rss[t] = ss;
    __syncthreads();
    for (int st = 128; st > 0; st >>= 1) {
        if (t < st) { rs[t] += rs[t + st]; rss[t] += rss[t + st]; }
        __syncthreads();
    }
    if (t == 0) {
        float mean = rs[0] * (1.f / 16384.f);
        float var = rss[0] * (1.f / 16384.f) - mean * mean;
        float rstd = rsqrtf(var + 1e-5f);
        float sc = gamma[c] * rstd;
        stats[c * 2] = sc;
        stats[c * 2 + 1] = beta[c] - mean * sc;
    }
}

// ---------------------------------------------------------------------------
// y = x + bn(p); LayerNorm over C per pixel; fp32 in-place on d_out
// ---------------------------------------------------------------------------
__global__ __launch_bounds__(256) void final_kernel(const float* __restrict__ x,
                                                    const float* __restrict__ p,
                                                    const float* __restrict__ stats,
                                                    const float* __restrict__ lg,
                                                    const float* __restrict__ lb,
                                                    float* __restrict__ out) {
    int blk = blockIdx.x;
    int b = blk >> 6;
    int pix0 = (blk & 63) * 64;
    int sub = threadIdx.x >> 6, px = threadIdx.x & 63;
    float s = 0.f, ss = 0.f;
    for (int i = 0; i < 128; ++i) {
        int c = i * 4 + sub;
        long idx = ((long)(b * CC + c)) * NN + pix0 + px;
        float y = x[idx] + p[idx] * stats[c * 2] + stats[c * 2 + 1];
        s += y; ss += y * y;
    }
    __shared__ float rs[4][64], rss[4][64];
    rs[sub][px] = s; rss[sub][px] = ss;
    __syncthreads();
    float sum = rs[0][px] + rs[1][px] + rs[2][px] + rs[3][px];
    float sq  = rss[0][px] + rss[1][px] + rss[2][px] + rss[3][px];
    float mu = sum * (1.f / 512.f);
    float var = sq * (1.f / 512.f) - mu * mu;
    float rstd = rsqrtf(var + 1e-5f);
    for (int i = 0; i < 128; ++i) {
        int c = i * 4 + sub;
        long idx = ((long)(b * CC + c)) * NN + pix0 + px;
        float y = x[idx] + p[idx] * stats[c * 2] + stats[c * 2 + 1];
        out[idx] = (y - mu) * rstd * lg[c] + lb[c];
    }
}

// ---------------------------------------------------------------------------
extern "C" void kernel_launch(void* const* d_in, const int* in_sizes, int n_in,
                              void* d_out, int out_size, void* d_ws, size_t ws_size,
                              hipStream_t stream) {
    (void)in_sizes; (void)n_in; (void)out_size;
    const float* x     = (const float*)d_in[0];
    const float* Wq    = (const float*)d_in[1];
    const float* Wk    = (const float*)d_in[2];
    const float* Wv    = (const float*)d_in[3];
    const float* bias  = (const float*)d_in[4];
    const float* Wproj = (const float*)d_in[5];
    const float* bng   = (const float*)d_in[6];
    const float* bnb   = (const float*)d_in[7];
    const float* lng   = (const float*)d_in[8];
    const float* lnb   = (const float*)d_in[9];
    float* out = (float*)d_out;   // fp32 output (verified R9)

    char* ws = (char*)d_ws;
    size_t off = 0;
    auto alloc = [&](size_t bytes) {
        char* pp = ws + off;
        off += (bytes + 255) & ~(size_t)255;
        return pp;
    };
    bf16* Wqb = (bf16*)alloc((size_t)CC * CC * 2);          // 0.52 MB
    bf16* Wpb = (bf16*)alloc((size_t)CC * CC * 2);          // 0.52 MB
    float* stats = (float*)alloc(512 * 2 * sizeof(float));

    // Layout A (fully batched) needs ~47 MB; layout B (per-batch) ~11.6 MB.
    size_t needA = off + ((size_t)CC * 2048 * 2 * 2)        // Wkf+Wvf 4.2 MB
                 + ((size_t)BB * NN * CC * 2)               // xt_all 16.8
                 + ((size_t)BB * NRR * CC * 2 * 2)          // kt+vt   8.4
                 + ((size_t)BB * NN * CC * 2) + 4096;       // ot_all 16.8

    if (ws_size >= needA) {
        // ---- layout A: one launch per stage, full batch in grid.z ----
        bf16* Wkf = (bf16*)alloc((size_t)CC * 2048 * 2);
        bf16* Wvf = (bf16*)alloc((size_t)CC * 2048 * 2);
        bf16* xt  = (bf16*)alloc((size_t)BB * NN * CC * 2);
        bf16* kt  = (bf16*)alloc((size_t)BB * NRR * CC * 2);
        bf16* vt  = (bf16*)alloc((size_t)BB * NRR * CC * 2);   // holds V^T [c][m]
        bf16* ot  = (bf16*)alloc((size_t)BB * NN * CC * 2);

        wcvt_kernel<<<1024, 256, 0, stream>>>(Wq, Wproj, Wqb, Wpb);
        wperm_kernel<<<4096, 256, 0, stream>>>(Wk, Wv, Wkf, Wvf);
        transpose_kernel<<<dim3(64, 8, BB), 256, 0, stream>>>(x, xt);
        gemm_kv<<<dim3(16, 8, BB * 2), 256, 0, stream>>>(xt, Wkf, Wvf, kt, vt);
        attn_kernel<<<dim3(64, NHH, BB), 256, 0, stream>>>(xt, Wqb, kt, vt, bias, ot);
        gemm_ntf<<<dim3(8, 64, BB), 256, 0, stream>>>(Wpb, ot, out);
    } else {
        // ---- layout B: per-batch loop, Wkf/Wvf overlay out slice 3 ----
        bf16* Wkf = (bf16*)(out + (size_t)3 * CC * NN);
        bf16* Wvf = Wkf + (size_t)CC * 2048;
        bf16* xt = (bf16*)alloc((size_t)NN * CC * 2);
        bf16* kt = (bf16*)alloc((size_t)NRR * CC * 2);
        bf16* vt = (bf16*)alloc((size_t)NRR * CC * 2);         // V^T [c][m]
        bf16* ot = (bf16*)alloc((size_t)NN * CC * 2);

        wcvt_kernel<<<1024, 256, 0, stream>>>(Wq, Wproj, Wqb, Wpb);
        wperm_kernel<<<4096, 256, 0, stream>>>(Wk, Wv, Wkf, Wvf);
        for (int b = 0; b < BB; ++b) {
            const float* xb = x + (size_t)b * CC * NN;
            float* pb = out + (size_t)b * CC * NN;
            transpose_kernel<<<dim3(64, 8, 1), 256, 0, stream>>>(xb, xt);
            gemm_kv<<<dim3(16, 8, 2), 256, 0, stream>>>(xt, Wkf, Wvf, kt, vt);
            attn_kernel<<<dim3(64, NHH, 1), 256, 0, stream>>>(xt, Wqb, kt, vt, bias, ot);
            gemm_ntf<<<dim3(8, 64, 1), 256, 0, stream>>>(Wpb, ot, pb);
        }
    }

    bnstats_kernel<<<512, 256, 0, stream>>>(out, bng, bnb, stats);
    final_kernel<<<256, 256, 0, stream>>>(x, out, stats, lng, lnb, out);
}

// Round 5
// 574.281 us; speedup vs baseline: 1.1861x; 1.0310x over previous
//
#include <hip/hip_runtime.h>
#include <hip/hip_bf16.h>
#include <cmath>

typedef __bf16 bf16;
typedef __bf16 bf16x8 __attribute__((ext_vector_type(8)));
typedef float f32x4 __attribute__((ext_vector_type(4)));

#define BB 4
#define CC 512
#define NN 4096      // 64*64 spatial
#define NRR 1024     // 32*32 spatial (stride-2)
#define NHH 8
#define DKK 64

static __device__ __forceinline__ bf16x8 ld8(const bf16* p) {
    return *reinterpret_cast<const bf16x8*>(p);
}

// ---------------------------------------------------------------------------
// weight convert / permute (fp32 -> bf16)
// ---------------------------------------------------------------------------
__global__ __launch_bounds__(256) void wcvt_kernel(const float* __restrict__ Wq,
                                                   const float* __restrict__ Wp,
                                                   bf16* __restrict__ Wqb,
                                                   bf16* __restrict__ Wpb) {
    int e = blockIdx.x * 256 + threadIdx.x;   // 262144
    Wqb[e] = (bf16)Wq[e];
    Wpb[e] = (bf16)Wp[e];
}

__global__ __launch_bounds__(256) void wperm_kernel(const float* __restrict__ Wk,
                                                    const float* __restrict__ Wv,
                                                    bf16* __restrict__ Wkf,
                                                    bf16* __restrict__ Wvf) {
    int e = blockIdx.x * 256 + threadIdx.x;   // 512*2048
    int o = e >> 11, q = (e >> 9) & 3, ci = e & 511;
    int src = o * 2048 + ci * 4 + q;
    Wkf[e] = (bf16)Wk[src];
    Wvf[e] = (bf16)Wv[src];
}

// ---------------------------------------------------------------------------
// x (b,C,N) fp32 -> xt (b,N,C) bf16; blockIdx.z = batch
// ---------------------------------------------------------------------------
__global__ __launch_bounds__(256) void transpose_kernel(const float* __restrict__ x,
                                                        bf16* __restrict__ xt) {
    __shared__ bf16 tile[64][65];
    int b = blockIdx.z;
    const float* xb = x + (size_t)b * CC * NN;
    bf16* xtb = xt + (size_t)b * NN * CC;
    int n0 = blockIdx.x * 64, c0 = blockIdx.y * 64;
    int tr = threadIdx.x >> 6, tc = threadIdx.x & 63;
#pragma unroll
    for (int i = 0; i < 64; i += 4)
        tile[tc][i + tr] = (bf16)xb[(long)(c0 + i + tr) * NN + n0 + tc];
    __syncthreads();
#pragma unroll
    for (int i = 0; i < 64; i += 4)
        xtb[(long)(n0 + i + tr) * CC + c0 + tc] = tile[i + tr][tc];
}

// ---------------------------------------------------------------------------
// K/V GEMM, im2col fused; blockIdx.z = b*2 + (0=K,1=V)
// K written key-major [m][C]; V written TRANSPOSED [c][m] so attention can
// stage V tiles into LDS with vectorized copies (no transpose, no scatter).
// ---------------------------------------------------------------------------
__global__ __launch_bounds__(256) void gemm_kv(const bf16* __restrict__ xt,
                                               const bf16* __restrict__ Wkf,
                                               const bf16* __restrict__ Wvf,
                                               bf16* __restrict__ kt,
                                               bf16* __restrict__ vt) {
    __shared__ __align__(16) bf16 ttile[64][72];   // V-transpose staging
    const f32x4 fzero = {0.f, 0.f, 0.f, 0.f};
    int z = blockIdx.z;
    int b = z >> 1, kv = z & 1;
    const bf16* xtb = xt + (size_t)b * NN * CC;
    const bf16* Wf = kv ? Wvf : Wkf;
    int w = threadIdx.x >> 6, lane = threadIdx.x & 63;
    int quad = lane >> 4, l15 = lane & 15;
    int m0 = blockIdx.x * 64 + w * 16;
    long n0 = (long)blockIdx.y * 64;
    int m2 = m0 + l15;
    int i2 = m2 >> 5, j2 = m2 & 31;
    const bf16* ap[4];
#pragma unroll
    for (int q = 0; q < 4; ++q) {
        int n = (2 * i2 + (q >> 1)) * 64 + 2 * j2 + (q & 1);
        ap[q] = xtb + (long)n * CC + quad * 8;
    }
    const bf16* Bp = Wf + (n0 + l15) * 2048 + quad * 8;
    f32x4 acc[4];
#pragma unroll
    for (int ct = 0; ct < 4; ++ct) acc[ct] = fzero;
#pragma unroll
    for (int q = 0; q < 4; ++q) {
        const bf16* aq = ap[q];
        const bf16* bq = Bp + q * 512;
#pragma unroll 2
        for (int kk = 0; kk < 512; kk += 32) {
            bf16x8 a = ld8(aq + kk);
#pragma unroll
            for (int ct = 0; ct < 4; ++ct) {
                bf16x8 bv = ld8(bq + kk + ct * 16 * 2048);
                acc[ct] = __builtin_amdgcn_mfma_f32_16x16x32_bf16(a, bv, acc[ct], 0, 0, 0);
            }
        }
    }
    if (!kv) {
        // K: key-major [m][C]
        bf16* Ct = kt + (size_t)b * NRR * CC;
#pragma unroll
        for (int ct = 0; ct < 4; ++ct)
#pragma unroll
            for (int r = 0; r < 4; ++r)
                Ct[(long)(m0 + quad * 4 + r) * CC + n0 + ct * 16 + l15] = (bf16)acc[ct][r];
    } else {
        // V^T: channel-major [c][m]; transpose the 64x64 tile through LDS
        bf16* Ct = vt + (size_t)b * CC * NRR;
#pragma unroll
        for (int ct = 0; ct < 4; ++ct)
#pragma unroll
            for (int r = 0; r < 4; ++r)
                ttile[ct * 16 + l15][w * 16 + quad * 4 + r] = (bf16)acc[ct][r];
        __syncthreads();
        int row = threadIdx.x >> 2, seg = threadIdx.x & 3;   // 64 rows x 4 segs
        bf16x8 v0 = ld8(&ttile[row][seg * 16]);
        bf16x8 v1 = ld8(&ttile[row][seg * 16 + 8]);
        bf16* dst = Ct + (n0 + row) * NRR + (long)blockIdx.x * 64 + seg * 16;
        *reinterpret_cast<bf16x8*>(dst) = v0;
        *reinterpret_cast<bf16x8*>(dst + 8) = v1;
    }
}

// ---------------------------------------------------------------------------
// flash attention with fused Q-GEMM; blockIdx.z = batch
// SWAPPED-OPERAND QK^T: S^T = mfma(K, Q) puts a full P-row per lane
// (col = lane&15 = query). Softmax reduces become: in-register max tree +
// 2 shfl_xor; the sum reduce is deferred to after the loop. PV computes
// O^T = mfma(V^T, P^T) with the same vtile/ptile access patterns.
// Bias dropped: constant along softmax axis => softmax-invariant (exact).
// ---------------------------------------------------------------------------
__global__ __launch_bounds__(256) void attn_kernel(const bf16* __restrict__ xt,
                                                   const bf16* __restrict__ Wqb,
                                                   const bf16* __restrict__ Kt,
                                                   const bf16* __restrict__ Vt,
                                                   const float* __restrict__ bias,
                                                   bf16* __restrict__ Ot) {
    __shared__ __align__(16) bf16 vbuf[2][64 * 64];     // [d][m], chunk-swizzled
    __shared__ __align__(16) bf16 ptile[4][16 * 72];    // per-wave Q/P stripe
    const f32x4 fzero = {0.f, 0.f, 0.f, 0.f};
    (void)bias;                                         // softmax-invariant
    int b = blockIdx.z, h = blockIdx.y;
    const bf16* xtb = xt + (size_t)b * NN * CC;
    const bf16* Ktb = Kt + (size_t)b * NRR * CC;
    const bf16* Vtb = Vt + (size_t)b * CC * NRR;        // [c][m] layout
    bf16* Otb = Ot + (size_t)b * NN * CC;
    int w = threadIdx.x >> 6, lane = threadIdx.x & 63;
    int quad = lane >> 4, l15 = lane & 15;
    int m0 = blockIdx.x * 64 + w * 16;

    // staging geometry: thread covers (d0, chunk) and (d0+32, chunk)
    int sd0 = threadIdx.x >> 3, schunk = threadIdx.x & 7;
    const bf16* vsrc0 = Vtb + (long)(h * DKK + sd0) * NRR + schunk * 8;
    const bf16* vsrc1 = vsrc0 + (long)32 * NRR;
    int soff0 = sd0 * 64 + ((schunk ^ (sd0 & 7)) * 8);
    int soff1 = (sd0 + 32) * 64 + ((schunk ^ (sd0 & 7)) * 8);

    // fused Q-GEMM: Q(16x64) = xt(16x512) . Wq_head^T
    f32x4 qacc[4];
#pragma unroll
    for (int ct = 0; ct < 4; ++ct) qacc[ct] = fzero;
    {
        const bf16* axp = xtb + (long)(m0 + l15) * CC + quad * 8;
        const bf16* bwp = Wqb + (long)(h * DKK + l15) * CC + quad * 8;
#pragma unroll 2
        for (int k0 = 0; k0 < 512; k0 += 32) {
            bf16x8 a = ld8(axp + k0);
#pragma unroll
            for (int ct = 0; ct < 4; ++ct) {
                bf16x8 bv = ld8(bwp + k0 + ct * 16 * CC);
                qacc[ct] = __builtin_amdgcn_mfma_f32_16x16x32_bf16(a, bv, qacc[ct], 0, 0, 0);
            }
        }
    }
    // D-layout -> LDS -> A/B-layout; per-wave stripe, wave-internal fence only
    bf16* ql = &ptile[w][0];
#pragma unroll
    for (int ct = 0; ct < 4; ++ct)
#pragma unroll
        for (int r = 0; r < 4; ++r)
            ql[(quad * 4 + r) * 72 + ct * 16 + l15] = (bf16)qacc[ct][r];
    asm volatile("s_waitcnt lgkmcnt(0)" ::: "memory");
    __builtin_amdgcn_sched_barrier(0);
    // B-fragment of Q for swapped QK^T: lane col = l15 (query), k = quad*8
    bf16x8 aq0 = ld8(ql + l15 * 72 + quad * 8);
    bf16x8 aq1 = ld8(ql + l15 * 72 + 32 + quad * 8);

    // prologue: stage V tile 0 into vbuf[0]
    {
        bf16x8 s0 = ld8(vsrc0);
        bf16x8 s1 = ld8(vsrc1);
        *reinterpret_cast<bf16x8*>(&vbuf[0][0] + soff0) = s0;
        *reinterpret_cast<bf16x8*>(&vbuf[0][0] + soff1) = s1;
    }
    __syncthreads();

    f32x4 oacc[4];
    float mrow = -1e30f, lrow = 0.f;     // scalars: this lane's query = l15
#pragma unroll
    for (int ct = 0; ct < 4; ++ct) oacc[ct] = fzero;

    for (int kt = 0; kt < 16; ++kt) {
        int cur = kt & 1;
        // ---- issue next-tile V loads early (latency hides under QK^T+softmax)
        bf16x8 sv0, sv1;
        if (kt < 15) {
            sv0 = ld8(vsrc0 + (kt + 1) * 64);
            sv1 = ld8(vsrc1 + (kt + 1) * 64);
        }

        // S^T = K Q^T : A = K-frag (rows = keys), B = Q-frag (cols = queries)
        f32x4 s[4];
#pragma unroll
        for (int ct = 0; ct < 4; ++ct) s[ct] = fzero;
        const bf16* kp = Ktb + (long)(kt * 64 + l15) * CC + h * DKK + quad * 8;
#pragma unroll
        for (int ct = 0; ct < 4; ++ct) {
            bf16x8 ka0 = ld8(kp + ct * 16 * CC);
            bf16x8 ka1 = ld8(kp + ct * 16 * CC + 32);
            s[ct] = __builtin_amdgcn_mfma_f32_16x16x32_bf16(ka0, aq0, s[ct], 0, 0, 0);
            s[ct] = __builtin_amdgcn_mfma_f32_16x16x32_bf16(ka1, aq1, s[ct], 0, 0, 0);
        }

        // online softmax: lane owns 16 key-logits for query l15
        float pv[4][4];
#pragma unroll
        for (int ct = 0; ct < 4; ++ct)
#pragma unroll
            for (int r = 0; r < 4; ++r) pv[ct][r] = s[ct][r] * 0.125f;
        float t0 = fmaxf(fmaxf(pv[0][0], pv[0][1]), fmaxf(pv[0][2], pv[0][3]));
        float t1 = fmaxf(fmaxf(pv[1][0], pv[1][1]), fmaxf(pv[1][2], pv[1][3]));
        float t2 = fmaxf(fmaxf(pv[2][0], pv[2][1]), fmaxf(pv[2][2], pv[2][3]));
        float t3 = fmaxf(fmaxf(pv[3][0], pv[3][1]), fmaxf(pv[3][2], pv[3][3]));
        float tmax = fmaxf(fmaxf(t0, t1), fmaxf(t2, t3));
        tmax = fmaxf(tmax, __shfl_xor(tmax, 16));
        tmax = fmaxf(tmax, __shfl_xor(tmax, 32));
        float mn = fmaxf(mrow, tmax);
        float alpha = __expf(mrow - mn);
        mrow = mn;
        float ls = 0.f;
#pragma unroll
        for (int ct = 0; ct < 4; ++ct)
#pragma unroll
            for (int r = 0; r < 4; ++r) {
                pv[ct][r] = __expf(pv[ct][r] - mn);
                ls += pv[ct][r];
            }
        lrow = lrow * alpha + ls;        // per-lane partial; reduced after loop
#pragma unroll
        for (int ct = 0; ct < 4; ++ct)
#pragma unroll
            for (int r = 0; r < 4; ++r) oacc[ct][r] *= alpha;

        // P^T: D-layout -> LDS (row = query l15, col = key)
        bf16* pl = &ptile[w][0];
#pragma unroll
        for (int ct = 0; ct < 4; ++ct)
#pragma unroll
            for (int r = 0; r < 4; ++r)
                pl[l15 * 72 + ct * 16 + quad * 4 + r] = (bf16)pv[ct][r];
        asm volatile("s_waitcnt lgkmcnt(0)" ::: "memory");
        __builtin_amdgcn_sched_barrier(0);

        // O^T += V^T P^T  (A = V^T-frag rows=d, B = P^T-frag cols=queries)
        const bf16* vb = &vbuf[cur][0];
#pragma unroll
        for (int ks = 0; ks < 2; ++ks) {
            bf16x8 bp = ld8(pl + l15 * 72 + ks * 32 + quad * 8);
#pragma unroll
            for (int ct = 0; ct < 4; ++ct) {
                int d = ct * 16 + l15;
                bf16x8 av = ld8(vb + d * 64 + (((ks * 4 + quad) ^ (d & 7)) * 8));
                oacc[ct] = __builtin_amdgcn_mfma_f32_16x16x32_bf16(av, bp, oacc[ct], 0, 0, 0);
            }
        }

        // ---- write staged V for tile kt+1 into the other buffer
        if (kt < 15) {
            bf16* wb = &vbuf[cur ^ 1][0];
            *reinterpret_cast<bf16x8*>(wb + soff0) = sv0;
            *reinterpret_cast<bf16x8*>(wb + soff1) = sv1;
        }
        __syncthreads();
    }

    // final denominator: reduce per-lane partials across the 4 quads
    lrow += __shfl_xor(lrow, 16);
    lrow += __shfl_xor(lrow, 32);
    float inv = 1.f / lrow;

    // O^T (d = ct*16+quad*4+r, q = l15) -> transpose via ptile -> coalesced
    bf16* pl = &ptile[w][0];
#pragma unroll
    for (int ct = 0; ct < 4; ++ct)
#pragma unroll
        for (int r = 0; r < 4; ++r)
            pl[l15 * 72 + ct * 16 + quad * 4 + r] = (bf16)(oacc[ct][r] * inv);
    asm volatile("s_waitcnt lgkmcnt(0)" ::: "memory");
    __builtin_amdgcn_sched_barrier(0);
    {
        bf16x8 o0 = ld8(pl + l15 * 72 + quad * 16);
        bf16x8 o1 = ld8(pl + l15 * 72 + quad * 16 + 8);
        bf16* dst = Otb + (long)(m0 + l15) * CC + h * DKK + quad * 16;
        *reinterpret_cast<bf16x8*>(dst) = o0;
        *reinterpret_cast<bf16x8*>(dst + 8) = o1;
    }
}

// ---------------------------------------------------------------------------
// proj: p[b,o,n] = Wproj . ot[b,n,:]^T, fp32 out; blockIdx.z = batch
// ---------------------------------------------------------------------------
__global__ __launch_bounds__(256) void gemm_ntf(const bf16* __restrict__ A,
                                                const bf16* __restrict__ Bt,
                                                float* __restrict__ C) {
    const f32x4 fzero = {0.f, 0.f, 0.f, 0.f};
    int b = blockIdx.z;
    const bf16* Btb = Bt + (size_t)b * NN * CC;
    float* Cb = C + (size_t)b * CC * NN;
    int w = threadIdx.x >> 6, lane = threadIdx.x & 63;
    int quad = lane >> 4, l15 = lane & 15;
    long m0 = (long)blockIdx.x * 64 + w * 16;
    long n0 = (long)blockIdx.y * 64;
    f32x4 acc[4];
#pragma unroll
    for (int ct = 0; ct < 4; ++ct) acc[ct] = fzero;
    const bf16* Ap = A + (m0 + l15) * CC + quad * 8;
    const bf16* Bp = Btb + (n0 + l15) * CC + quad * 8;
#pragma unroll 2
    for (int k0 = 0; k0 < 512; k0 += 32) {
        bf16x8 a = ld8(Ap + k0);
#pragma unroll
        for (int ct = 0; ct < 4; ++ct) {
            bf16x8 bv = ld8(Bp + k0 + (long)ct * 16 * CC);
            acc[ct] = __builtin_amdgcn_mfma_f32_16x16x32_bf16(a, bv, acc[ct], 0, 0, 0);
        }
    }
#pragma unroll
    for (int ct = 0; ct < 4; ++ct)
#pragma unroll
        for (int r = 0; r < 4; ++r)
            Cb[(m0 + quad * 4 + r) * NN + n0 + ct * 16 + l15] = acc[ct][r];
}

// ---------------------------------------------------------------------------
// BN batch stats folded into scale/shift (fp32 p = d_out)
// ---------------------------------------------------------------------------
__global__ __launch_bounds__(256) void bnstats_kernel(const float* __restrict__ p,
                                                      const float* __restrict__ gamma,
                                                      const float* __restrict__ beta,
                                                      float* __restrict__ stats) {
    int c = blockIdx.x, t = threadIdx.x;
    float s = 0.f, ss = 0.f;
    for (int b = 0; b < BB; ++b) {
        const float* base = p + ((long)(b * CC + c)) * NN;
        for (int n = t; n < NN; n += 256) {
            float v = base[n];
            s += v; ss += v * v;
        }
    }
    __shared__ float rs[256], rss[256];
    rs[t] = s; rss[t] = ss;
    __syncthreads();
    for (int st = 128; st > 0; st >>= 1) {
        if (t < st) { rs[t] += rs[t + st]; rss[t] += rss[t + st]; }
        __syncthreads();
    }
    if (t == 0) {
        float mean = rs[0] * (1.f / 16384.f);
        float var = rss[0] * (1.f / 16384.f) - mean * mean;
        float rstd = rsqrtf(var + 1e-5f);
        float sc = gamma[c] * rstd;
        stats[c * 2] = sc;
        stats[c * 2 + 1] = beta[c] - mean * sc;
    }
}

// ---------------------------------------------------------------------------
// y = x + bn(p); LayerNorm over C per pixel; fp32 in-place on d_out
// ---------------------------------------------------------------------------
__global__ __launch_bounds__(256) void final_kernel(const float* __restrict__ x,
                                                    const float* __restrict__ p,
                                                    const float* __restrict__ stats,
                                                    const float* __restrict__ lg,
                                                    const float* __restrict__ lb,
                                                    float* __restrict__ out) {
    int blk = blockIdx.x;
    int b = blk >> 6;
    int pix0 = (blk & 63) * 64;
    int sub = threadIdx.x >> 6, px = threadIdx.x & 63;
    float s = 0.f, ss = 0.f;
    for (int i = 0; i < 128; ++i) {
        int c = i * 4 + sub;
        long idx = ((long)(b * CC + c)) * NN + pix0 + px;
        float y = x[idx] + p[idx] * stats[c * 2] + stats[c * 2 + 1];
        s += y; ss += y * y;
    }
    __shared__ float rs[4][64], rss[4][64];
    rs[sub][px] = s; rss[sub][px] = ss;
    __syncthreads();
    float sum = rs[0][px] + rs[1][px] + rs[2][px] + rs[3][px];
    float sq  = rss[0][px] + rss[1][px] + rss[2][px] + rss[3][px];
    float mu = sum * (1.f / 512.f);
    float var = sq * (1.f / 512.f) - mu * mu;
    float rstd = rsqrtf(var + 1e-5f);
    for (int i = 0; i < 128; ++i) {
        int c = i * 4 + sub;
        long idx = ((long)(b * CC + c)) * NN + pix0 + px;
        float y = x[idx] + p[idx] * stats[c * 2] + stats[c * 2 + 1];
        out[idx] = (y - mu) * rstd * lg[c] + lb[c];
    }
}

// ---------------------------------------------------------------------------
extern "C" void kernel_launch(void* const* d_in, const int* in_sizes, int n_in,
                              void* d_out, int out_size, void* d_ws, size_t ws_size,
                              hipStream_t stream) {
    (void)in_sizes; (void)n_in; (void)out_size;
    const float* x     = (const float*)d_in[0];
    const float* Wq    = (const float*)d_in[1];
    const float* Wk    = (const float*)d_in[2];
    const float* Wv    = (const float*)d_in[3];
    const float* bias  = (const float*)d_in[4];
    const float* Wproj = (const float*)d_in[5];
    const float* bng   = (const float*)d_in[6];
    const float* bnb   = (const float*)d_in[7];
    const float* lng   = (const float*)d_in[8];
    const float* lnb   = (const float*)d_in[9];
    float* out = (float*)d_out;   // fp32 output (verified R9)

    char* ws = (char*)d_ws;
    size_t off = 0;
    auto alloc = [&](size_t bytes) {
        char* pp = ws + off;
        off += (bytes + 255) & ~(size_t)255;
        return pp;
    };
    bf16* Wqb = (bf16*)alloc((size_t)CC * CC * 2);          // 0.52 MB
    bf16* Wpb = (bf16*)alloc((size_t)CC * CC * 2);          // 0.52 MB
    float* stats = (float*)alloc(512 * 2 * sizeof(float));

    // Layout A (fully batched) needs ~47 MB; layout B (per-batch) ~11.6 MB.
    size_t needA = off + ((size_t)CC * 2048 * 2 * 2)        // Wkf+Wvf 4.2 MB
                 + ((size_t)BB * NN * CC * 2)               // xt_all 16.8
                 + ((size_t)BB * NRR * CC * 2 * 2)          // kt+vt   8.4
                 + ((size_t)BB * NN * CC * 2) + 4096;       // ot_all 16.8

    if (ws_size >= needA) {
        // ---- layout A: one launch per stage, full batch in grid.z ----
        bf16* Wkf = (bf16*)alloc((size_t)CC * 2048 * 2);
        bf16* Wvf = (bf16*)alloc((size_t)CC * 2048 * 2);
        bf16* xt  = (bf16*)alloc((size_t)BB * NN * CC * 2);
        bf16* kt  = (bf16*)alloc((size_t)BB * NRR * CC * 2);
        bf16* vt  = (bf16*)alloc((size_t)BB * NRR * CC * 2);   // holds V^T [c][m]
        bf16* ot  = (bf16*)alloc((size_t)BB * NN * CC * 2);

        wcvt_kernel<<<1024, 256, 0, stream>>>(Wq, Wproj, Wqb, Wpb);
        wperm_kernel<<<4096, 256, 0, stream>>>(Wk, Wv, Wkf, Wvf);
        transpose_kernel<<<dim3(64, 8, BB), 256, 0, stream>>>(x, xt);
        gemm_kv<<<dim3(16, 8, BB * 2), 256, 0, stream>>>(xt, Wkf, Wvf, kt, vt);
        attn_kernel<<<dim3(64, NHH, BB), 256, 0, stream>>>(xt, Wqb, kt, vt, bias, ot);
        gemm_ntf<<<dim3(8, 64, BB), 256, 0, stream>>>(Wpb, ot, out);
    } else {
        // ---- layout B: per-batch loop, Wkf/Wvf overlay out slice 3 ----
        bf16* Wkf = (bf16*)(out + (size_t)3 * CC * NN);
        bf16* Wvf = Wkf + (size_t)CC * 2048;
        bf16* xt = (bf16*)alloc((size_t)NN * CC * 2);
        bf16* kt = (bf16*)alloc((size_t)NRR * CC * 2);
        bf16* vt = (bf16*)alloc((size_t)NRR * CC * 2);         // V^T [c][m]
        bf16* ot = (bf16*)alloc((size_t)NN * CC * 2);

        wcvt_kernel<<<1024, 256, 0, stream>>>(Wq, Wproj, Wqb, Wpb);
        wperm_kernel<<<4096, 256, 0, stream>>>(Wk, Wv, Wkf, Wvf);
        for (int b = 0; b < BB; ++b) {
            const float* xb = x + (size_t)b * CC * NN;
            float* pb = out + (size_t)b * CC * NN;
            transpose_kernel<<<dim3(64, 8, 1), 256, 0, stream>>>(xb, xt);
            gemm_kv<<<dim3(16, 8, 2), 256, 0, stream>>>(xt, Wkf, Wvf, kt, vt);
            attn_kernel<<<dim3(64, NHH, 1), 256, 0, stream>>>(xt, Wqb, kt, vt, bias, ot);
            gemm_ntf<<<dim3(8, 64, 1), 256, 0, stream>>>(Wpb, ot, pb);
        }
    }

    bnstats_kernel<<<512, 256, 0, stream>>>(out, bng, bnb, stats);
    final_kernel<<<256, 256, 0, stream>>>(x, out, stats, lng, lnb, out);
}

// Round 6
// 501.539 us; speedup vs baseline: 1.3581x; 1.1450x over previous
//
#include <hip/hip_runtime.h>
#include <hip/hip_bf16.h>
#include <cmath>

typedef __bf16 bf16;
typedef __bf16 bf16x8 __attribute__((ext_vector_type(8)));
typedef float f32x4 __attribute__((ext_vector_type(4)));

#define BB 4
#define CC 512
#define NN 4096      // 64*64 spatial
#define NRR 1024     // 32*32 spatial (stride-2)
#define NHH 8
#define DKK 64

static __device__ __forceinline__ bf16x8 ld8(const bf16* p) {
    return *reinterpret_cast<const bf16x8*>(p);
}

// ---------------------------------------------------------------------------
// weight convert / permute (fp32 -> bf16); also zeroes the BN stats buffer
// ---------------------------------------------------------------------------
__global__ __launch_bounds__(256) void wcvt_kernel(const float* __restrict__ Wq,
                                                   const float* __restrict__ Wp,
                                                   bf16* __restrict__ Wqb,
                                                   bf16* __restrict__ Wpb,
                                                   float* __restrict__ stats) {
    int e = blockIdx.x * 256 + threadIdx.x;   // 262144
    if (e < 1024) stats[e] = 0.f;
    Wqb[e] = (bf16)Wq[e];
    Wpb[e] = (bf16)Wp[e];
}

__global__ __launch_bounds__(256) void wperm_kernel(const float* __restrict__ Wk,
                                                    const float* __restrict__ Wv,
                                                    bf16* __restrict__ Wkf,
                                                    bf16* __restrict__ Wvf) {
    int e = blockIdx.x * 256 + threadIdx.x;   // 512*2048
    int o = e >> 11, q = (e >> 9) & 3, ci = e & 511;
    int src = o * 2048 + ci * 4 + q;
    Wkf[e] = (bf16)Wk[src];
    Wvf[e] = (bf16)Wv[src];
}

// ---------------------------------------------------------------------------
// x (b,C,N) fp32 -> xt (b,N,C) bf16; blockIdx.z = batch
// ---------------------------------------------------------------------------
__global__ __launch_bounds__(256) void transpose_kernel(const float* __restrict__ x,
                                                        bf16* __restrict__ xt) {
    __shared__ bf16 tile[64][65];
    int b = blockIdx.z;
    const float* xb = x + (size_t)b * CC * NN;
    bf16* xtb = xt + (size_t)b * NN * CC;
    int n0 = blockIdx.x * 64, c0 = blockIdx.y * 64;
    int tr = threadIdx.x >> 6, tc = threadIdx.x & 63;
#pragma unroll
    for (int i = 0; i < 64; i += 4)
        tile[tc][i + tr] = (bf16)xb[(long)(c0 + i + tr) * NN + n0 + tc];
    __syncthreads();
#pragma unroll
    for (int i = 0; i < 64; i += 4)
        xtb[(long)(n0 + i + tr) * CC + c0 + tc] = tile[i + tr][tc];
}

// ---------------------------------------------------------------------------
// K/V GEMM, im2col fused; blockIdx.z = b*2 + (0=K,1=V)
// K written key-major [m][C]; V written TRANSPOSED [c][m].
// ---------------------------------------------------------------------------
__global__ __launch_bounds__(256) void gemm_kv(const bf16* __restrict__ xt,
                                               const bf16* __restrict__ Wkf,
                                               const bf16* __restrict__ Wvf,
                                               bf16* __restrict__ kt,
                                               bf16* __restrict__ vt) {
    __shared__ __align__(16) bf16 ttile[64][72];   // V-transpose staging
    const f32x4 fzero = {0.f, 0.f, 0.f, 0.f};
    int z = blockIdx.z;
    int b = z >> 1, kv = z & 1;
    const bf16* xtb = xt + (size_t)b * NN * CC;
    const bf16* Wf = kv ? Wvf : Wkf;
    int w = threadIdx.x >> 6, lane = threadIdx.x & 63;
    int quad = lane >> 4, l15 = lane & 15;
    int m0 = blockIdx.x * 64 + w * 16;
    long n0 = (long)blockIdx.y * 64;
    int m2 = m0 + l15;
    int i2 = m2 >> 5, j2 = m2 & 31;
    const bf16* ap[4];
#pragma unroll
    for (int q = 0; q < 4; ++q) {
        int n = (2 * i2 + (q >> 1)) * 64 + 2 * j2 + (q & 1);
        ap[q] = xtb + (long)n * CC + quad * 8;
    }
    const bf16* Bp = Wf + (n0 + l15) * 2048 + quad * 8;
    f32x4 acc[4];
#pragma unroll
    for (int ct = 0; ct < 4; ++ct) acc[ct] = fzero;
#pragma unroll
    for (int q = 0; q < 4; ++q) {
        const bf16* aq = ap[q];
        const bf16* bq = Bp + q * 512;
#pragma unroll 2
        for (int kk = 0; kk < 512; kk += 32) {
            bf16x8 a = ld8(aq + kk);
#pragma unroll
            for (int ct = 0; ct < 4; ++ct) {
                bf16x8 bv = ld8(bq + kk + ct * 16 * 2048);
                acc[ct] = __builtin_amdgcn_mfma_f32_16x16x32_bf16(a, bv, acc[ct], 0, 0, 0);
            }
        }
    }
    if (!kv) {
        // K: key-major [m][C]
        bf16* Ct = kt + (size_t)b * NRR * CC;
#pragma unroll
        for (int ct = 0; ct < 4; ++ct)
#pragma unroll
            for (int r = 0; r < 4; ++r)
                Ct[(long)(m0 + quad * 4 + r) * CC + n0 + ct * 16 + l15] = (bf16)acc[ct][r];
    } else {
        // V^T: channel-major [c][m]; transpose the 64x64 tile through LDS
        bf16* Ct = vt + (size_t)b * CC * NRR;
#pragma unroll
        for (int ct = 0; ct < 4; ++ct)
#pragma unroll
            for (int r = 0; r < 4; ++r)
                ttile[ct * 16 + l15][w * 16 + quad * 4 + r] = (bf16)acc[ct][r];
        __syncthreads();
        int row = threadIdx.x >> 2, seg = threadIdx.x & 3;   // 64 rows x 4 segs
        bf16x8 v0 = ld8(&ttile[row][seg * 16]);
        bf16x8 v1 = ld8(&ttile[row][seg * 16 + 8]);
        bf16* dst = Ct + (n0 + row) * NRR + (long)blockIdx.x * 64 + seg * 16;
        *reinterpret_cast<bf16x8*>(dst) = v0;
        *reinterpret_cast<bf16x8*>(dst + 8) = v1;
    }
}

// ---------------------------------------------------------------------------
// flash attention, swapped-operand QK^T, TWO query tiles per wave (32 q).
// K/V/Wq fragment loads and the P-fence are shared between tiles; the two
// softmax chains are independent (ILP). Grid: (32, NH, B) = 1024 blocks ->
// 4 blocks/CU, all resident. Bias dropped (softmax-invariant, exact).
// ---------------------------------------------------------------------------
__global__ __launch_bounds__(256) void attn_kernel(const bf16* __restrict__ xt,
                                                   const bf16* __restrict__ Wqb,
                                                   const bf16* __restrict__ Kt,
                                                   const bf16* __restrict__ Vt,
                                                   const float* __restrict__ bias,
                                                   bf16* __restrict__ Ot) {
    __shared__ __align__(16) bf16 vbuf[2][64 * 64];     // [d][m], chunk-swizzled
    __shared__ __align__(16) bf16 ptile[4][32 * 72];    // per-wave 2 stripes
    const f32x4 fzero = {0.f, 0.f, 0.f, 0.f};
    (void)bias;                                         // softmax-invariant
    int b = blockIdx.z, h = blockIdx.y;
    const bf16* xtb = xt + (size_t)b * NN * CC;
    const bf16* Ktb = Kt + (size_t)b * NRR * CC;
    const bf16* Vtb = Vt + (size_t)b * CC * NRR;        // [c][m] layout
    bf16* Otb = Ot + (size_t)b * NN * CC;
    int w = threadIdx.x >> 6, lane = threadIdx.x & 63;
    int quad = lane >> 4, l15 = lane & 15;
    int m0 = blockIdx.x * 128 + w * 32;                 // tile A: m0, tile B: m0+16

    // staging geometry: thread covers (d0, chunk) and (d0+32, chunk)
    int sd0 = threadIdx.x >> 3, schunk = threadIdx.x & 7;
    const bf16* vsrc0 = Vtb + (long)(h * DKK + sd0) * NRR + schunk * 8;
    const bf16* vsrc1 = vsrc0 + (long)32 * NRR;
    int soff0 = sd0 * 64 + ((schunk ^ (sd0 & 7)) * 8);
    int soff1 = (sd0 + 32) * 64 + ((schunk ^ (sd0 & 7)) * 8);

    // fused Q-GEMM for both tiles: Wq fragments shared
    f32x4 qaccA[4], qaccB[4];
#pragma unroll
    for (int ct = 0; ct < 4; ++ct) { qaccA[ct] = fzero; qaccB[ct] = fzero; }
    {
        const bf16* axpA = xtb + (long)(m0 + l15) * CC + quad * 8;
        const bf16* axpB = axpA + 16 * CC;
        const bf16* bwp = Wqb + (long)(h * DKK + l15) * CC + quad * 8;
#pragma unroll 2
        for (int k0 = 0; k0 < 512; k0 += 32) {
            bf16x8 aA = ld8(axpA + k0);
            bf16x8 aB = ld8(axpB + k0);
#pragma unroll
            for (int ct = 0; ct < 4; ++ct) {
                bf16x8 bv = ld8(bwp + k0 + ct * 16 * CC);
                qaccA[ct] = __builtin_amdgcn_mfma_f32_16x16x32_bf16(aA, bv, qaccA[ct], 0, 0, 0);
                qaccB[ct] = __builtin_amdgcn_mfma_f32_16x16x32_bf16(aB, bv, qaccB[ct], 0, 0, 0);
            }
        }
    }
    // D-layout -> LDS stripes -> B-fragment layout; per-wave fence only
    bf16* ql = &ptile[w][0];
#pragma unroll
    for (int ct = 0; ct < 4; ++ct)
#pragma unroll
        for (int r = 0; r < 4; ++r) {
            ql[(quad * 4 + r) * 72 + ct * 16 + l15] = (bf16)qaccA[ct][r];
            ql[(16 + quad * 4 + r) * 72 + ct * 16 + l15] = (bf16)qaccB[ct][r];
        }
    asm volatile("s_waitcnt lgkmcnt(0)" ::: "memory");
    __builtin_amdgcn_sched_barrier(0);
    bf16x8 aq0A = ld8(ql + l15 * 72 + quad * 8);
    bf16x8 aq1A = ld8(ql + l15 * 72 + 32 + quad * 8);
    bf16x8 aq0B = ld8(ql + (16 + l15) * 72 + quad * 8);
    bf16x8 aq1B = ld8(ql + (16 + l15) * 72 + 32 + quad * 8);

    // prologue: stage V tile 0 into vbuf[0]
    {
        bf16x8 s0 = ld8(vsrc0);
        bf16x8 s1 = ld8(vsrc1);
        *reinterpret_cast<bf16x8*>(&vbuf[0][0] + soff0) = s0;
        *reinterpret_cast<bf16x8*>(&vbuf[0][0] + soff1) = s1;
    }
    __syncthreads();

    f32x4 oaccA[4], oaccB[4];
    float mrowA = -1e30f, lrowA = 0.f, mrowB = -1e30f, lrowB = 0.f;
#pragma unroll
    for (int ct = 0; ct < 4; ++ct) { oaccA[ct] = fzero; oaccB[ct] = fzero; }

    for (int kt = 0; kt < 16; ++kt) {
        int cur = kt & 1;
        // ---- issue next-tile V loads early
        bf16x8 sv0, sv1;
        if (kt < 15) {
            sv0 = ld8(vsrc0 + (kt + 1) * 64);
            sv1 = ld8(vsrc1 + (kt + 1) * 64);
        }

        // S^T = K Q^T for both tiles (K fragments shared)
        f32x4 sA[4], sB[4];
#pragma unroll
        for (int ct = 0; ct < 4; ++ct) { sA[ct] = fzero; sB[ct] = fzero; }
        const bf16* kp = Ktb + (long)(kt * 64 + l15) * CC + h * DKK + quad * 8;
#pragma unroll
        for (int ct = 0; ct < 4; ++ct) {
            bf16x8 ka0 = ld8(kp + ct * 16 * CC);
            bf16x8 ka1 = ld8(kp + ct * 16 * CC + 32);
            sA[ct] = __builtin_amdgcn_mfma_f32_16x16x32_bf16(ka0, aq0A, sA[ct], 0, 0, 0);
            sA[ct] = __builtin_amdgcn_mfma_f32_16x16x32_bf16(ka1, aq1A, sA[ct], 0, 0, 0);
            sB[ct] = __builtin_amdgcn_mfma_f32_16x16x32_bf16(ka0, aq0B, sB[ct], 0, 0, 0);
            sB[ct] = __builtin_amdgcn_mfma_f32_16x16x32_bf16(ka1, aq1B, sB[ct], 0, 0, 0);
        }

        // online softmax: two independent scalar chains (ILP)
        float pvA[4][4], pvB[4][4];
#pragma unroll
        for (int ct = 0; ct < 4; ++ct)
#pragma unroll
            for (int r = 0; r < 4; ++r) {
                pvA[ct][r] = sA[ct][r] * 0.125f;
                pvB[ct][r] = sB[ct][r] * 0.125f;
            }
        float tA0 = fmaxf(fmaxf(pvA[0][0], pvA[0][1]), fmaxf(pvA[0][2], pvA[0][3]));
        float tA1 = fmaxf(fmaxf(pvA[1][0], pvA[1][1]), fmaxf(pvA[1][2], pvA[1][3]));
        float tA2 = fmaxf(fmaxf(pvA[2][0], pvA[2][1]), fmaxf(pvA[2][2], pvA[2][3]));
        float tA3 = fmaxf(fmaxf(pvA[3][0], pvA[3][1]), fmaxf(pvA[3][2], pvA[3][3]));
        float tB0 = fmaxf(fmaxf(pvB[0][0], pvB[0][1]), fmaxf(pvB[0][2], pvB[0][3]));
        float tB1 = fmaxf(fmaxf(pvB[1][0], pvB[1][1]), fmaxf(pvB[1][2], pvB[1][3]));
        float tB2 = fmaxf(fmaxf(pvB[2][0], pvB[2][1]), fmaxf(pvB[2][2], pvB[2][3]));
        float tB3 = fmaxf(fmaxf(pvB[3][0], pvB[3][1]), fmaxf(pvB[3][2], pvB[3][3]));
        float tmaxA = fmaxf(fmaxf(tA0, tA1), fmaxf(tA2, tA3));
        float tmaxB = fmaxf(fmaxf(tB0, tB1), fmaxf(tB2, tB3));
        tmaxA = fmaxf(tmaxA, __shfl_xor(tmaxA, 16));
        tmaxB = fmaxf(tmaxB, __shfl_xor(tmaxB, 16));
        tmaxA = fmaxf(tmaxA, __shfl_xor(tmaxA, 32));
        tmaxB = fmaxf(tmaxB, __shfl_xor(tmaxB, 32));
        float mnA = fmaxf(mrowA, tmaxA), mnB = fmaxf(mrowB, tmaxB);
        float alphaA = __expf(mrowA - mnA), alphaB = __expf(mrowB - mnB);
        mrowA = mnA; mrowB = mnB;
        float lsA = 0.f, lsB = 0.f;
#pragma unroll
        for (int ct = 0; ct < 4; ++ct)
#pragma unroll
            for (int r = 0; r < 4; ++r) {
                pvA[ct][r] = __expf(pvA[ct][r] - mnA);
                pvB[ct][r] = __expf(pvB[ct][r] - mnB);
                lsA += pvA[ct][r];
                lsB += pvB[ct][r];
            }
        lrowA = lrowA * alphaA + lsA;
        lrowB = lrowB * alphaB + lsB;
#pragma unroll
        for (int ct = 0; ct < 4; ++ct)
#pragma unroll
            for (int r = 0; r < 4; ++r) {
                oaccA[ct][r] *= alphaA;
                oaccB[ct][r] *= alphaB;
            }

        // P^T stripes: row = query (A: l15, B: 16+l15), col = key; ONE fence
        bf16* pl = &ptile[w][0];
#pragma unroll
        for (int ct = 0; ct < 4; ++ct)
#pragma unroll
            for (int r = 0; r < 4; ++r) {
                pl[l15 * 72 + ct * 16 + quad * 4 + r] = (bf16)pvA[ct][r];
                pl[(16 + l15) * 72 + ct * 16 + quad * 4 + r] = (bf16)pvB[ct][r];
            }
        asm volatile("s_waitcnt lgkmcnt(0)" ::: "memory");
        __builtin_amdgcn_sched_barrier(0);

        // O^T += V^T P^T  (V fragments shared between tiles)
        const bf16* vb = &vbuf[cur][0];
#pragma unroll
        for (int ks = 0; ks < 2; ++ks) {
            bf16x8 bpA = ld8(pl + l15 * 72 + ks * 32 + quad * 8);
            bf16x8 bpB = ld8(pl + (16 + l15) * 72 + ks * 32 + quad * 8);
#pragma unroll
            for (int ct = 0; ct < 4; ++ct) {
                int d = ct * 16 + l15;
                bf16x8 av = ld8(vb + d * 64 + (((ks * 4 + quad) ^ (d & 7)) * 8));
                oaccA[ct] = __builtin_amdgcn_mfma_f32_16x16x32_bf16(av, bpA, oaccA[ct], 0, 0, 0);
                oaccB[ct] = __builtin_amdgcn_mfma_f32_16x16x32_bf16(av, bpB, oaccB[ct], 0, 0, 0);
            }
        }

        // ---- write staged V for tile kt+1 into the other buffer
        if (kt < 15) {
            bf16* wb = &vbuf[cur ^ 1][0];
            *reinterpret_cast<bf16x8*>(wb + soff0) = sv0;
            *reinterpret_cast<bf16x8*>(wb + soff1) = sv1;
        }
        __syncthreads();
    }

    // final denominators
    lrowA += __shfl_xor(lrowA, 16);
    lrowB += __shfl_xor(lrowB, 16);
    lrowA += __shfl_xor(lrowA, 32);
    lrowB += __shfl_xor(lrowB, 32);
    float invA = 1.f / lrowA, invB = 1.f / lrowB;

    // O^T -> transpose via ptile stripes -> coalesced stores
    bf16* pl = &ptile[w][0];
#pragma unroll
    for (int ct = 0; ct < 4; ++ct)
#pragma unroll
        for (int r = 0; r < 4; ++r) {
            pl[l15 * 72 + ct * 16 + quad * 4 + r] = (bf16)(oaccA[ct][r] * invA);
            pl[(16 + l15) * 72 + ct * 16 + quad * 4 + r] = (bf16)(oaccB[ct][r] * invB);
        }
    asm volatile("s_waitcnt lgkmcnt(0)" ::: "memory");
    __builtin_amdgcn_sched_barrier(0);
    {
        bf16x8 o0 = ld8(pl + l15 * 72 + quad * 16);
        bf16x8 o1 = ld8(pl + l15 * 72 + quad * 16 + 8);
        bf16* dst = Otb + (long)(m0 + l15) * CC + h * DKK + quad * 16;
        *reinterpret_cast<bf16x8*>(dst) = o0;
        *reinterpret_cast<bf16x8*>(dst + 8) = o1;
        bf16x8 p0 = ld8(pl + (16 + l15) * 72 + quad * 16);
        bf16x8 p1 = ld8(pl + (16 + l15) * 72 + quad * 16 + 8);
        bf16* dstB = Otb + (long)(m0 + 16 + l15) * CC + h * DKK + quad * 16;
        *reinterpret_cast<bf16x8*>(dstB) = p0;
        *reinterpret_cast<bf16x8*>(dstB + 8) = p1;
    }
}

// ---------------------------------------------------------------------------
// proj: p[b,o,n] = Wproj . ot[b,n,:]^T, fp32 out; blockIdx.z = batch.
// BN raw stats (sum, sumsq per channel) fused via shfl-reduce + atomics.
// ---------------------------------------------------------------------------
__global__ __launch_bounds__(256) void gemm_ntf(const bf16* __restrict__ A,
                                                const bf16* __restrict__ Bt,
                                                float* __restrict__ C,
                                                float* __restrict__ stats) {
    const f32x4 fzero = {0.f, 0.f, 0.f, 0.f};
    int b = blockIdx.z;
    const bf16* Btb = Bt + (size_t)b * NN * CC;
    float* Cb = C + (size_t)b * CC * NN;
    int w = threadIdx.x >> 6, lane = threadIdx.x & 63;
    int quad = lane >> 4, l15 = lane & 15;
    long m0 = (long)blockIdx.x * 64 + w * 16;
    long n0 = (long)blockIdx.y * 64;
    f32x4 acc[4];
#pragma unroll
    for (int ct = 0; ct < 4; ++ct) acc[ct] = fzero;
    const bf16* Ap = A + (m0 + l15) * CC + quad * 8;
    const bf16* Bp = Btb + (n0 + l15) * CC + quad * 8;
#pragma unroll 2
    for (int k0 = 0; k0 < 512; k0 += 32) {
        bf16x8 a = ld8(Ap + k0);
#pragma unroll
        for (int ct = 0; ct < 4; ++ct) {
            bf16x8 bv = ld8(Bp + k0 + (long)ct * 16 * CC);
            acc[ct] = __builtin_amdgcn_mfma_f32_16x16x32_bf16(a, bv, acc[ct], 0, 0, 0);
        }
    }
    float ps[4], pss[4];
#pragma unroll
    for (int r = 0; r < 4; ++r) { ps[r] = 0.f; pss[r] = 0.f; }
#pragma unroll
    for (int ct = 0; ct < 4; ++ct)
#pragma unroll
        for (int r = 0; r < 4; ++r) {
            float v = acc[ct][r];
            Cb[(m0 + quad * 4 + r) * NN + n0 + ct * 16 + l15] = v;
            ps[r] += v; pss[r] += v * v;
        }
    // reduce over l15 (16 lanes share channel m0+quad*4+r)
#pragma unroll
    for (int off = 1; off < 16; off <<= 1)
#pragma unroll
        for (int r = 0; r < 4; ++r) {
            ps[r] += __shfl_xor(ps[r], off);
            pss[r] += __shfl_xor(pss[r], off);
        }
    if (l15 == 0) {
#pragma unroll
        for (int r = 0; r < 4; ++r) {
            int c = (int)(m0 + quad * 4 + r);
            atomicAdd(&stats[c * 2], ps[r]);
            atomicAdd(&stats[c * 2 + 1], pss[r]);
        }
    }
}

// ---------------------------------------------------------------------------
// y = x + bn(p); LayerNorm over C per pixel; BN scale/shift derived from raw
// stats in a small LDS preamble. fp32 in-place on d_out.
// ---------------------------------------------------------------------------
__global__ __launch_bounds__(256) void final_kernel(const float* __restrict__ x,
                                                    const float* __restrict__ p,
                                                    const float* __restrict__ stats,
                                                    const float* __restrict__ bng,
                                                    const float* __restrict__ bnb,
                                                    const float* __restrict__ lg,
                                                    const float* __restrict__ lb,
                                                    float* __restrict__ out) {
    __shared__ float scs[512], shs[512];
    for (int c = threadIdx.x; c < 512; c += 256) {
        float sum = stats[c * 2], ssq = stats[c * 2 + 1];
        float mean = sum * (1.f / 16384.f);
        float var = ssq * (1.f / 16384.f) - mean * mean;
        float rstd = rsqrtf(var + 1e-5f);
        float sc = bng[c] * rstd;
        scs[c] = sc;
        shs[c] = bnb[c] - mean * sc;
    }
    __syncthreads();
    int blk = blockIdx.x;
    int b = blk >> 6;
    int pix0 = (blk & 63) * 64;
    int sub = threadIdx.x >> 6, px = threadIdx.x & 63;
    float s = 0.f, ss = 0.f;
    for (int i = 0; i < 128; ++i) {
        int c = i * 4 + sub;
        long idx = ((long)(b * CC + c)) * NN + pix0 + px;
        float y = x[idx] + p[idx] * scs[c] + shs[c];
        s += y; ss += y * y;
    }
    __shared__ float rs[4][64], rss[4][64];
    rs[sub][px] = s; rss[sub][px] = ss;
    __syncthreads();
    float sum = rs[0][px] + rs[1][px] + rs[2][px] + rs[3][px];
    float sq  = rss[0][px] + rss[1][px] + rss[2][px] + rss[3][px];
    float mu = sum * (1.f / 512.f);
    float var = sq * (1.f / 512.f) - mu * mu;
    float rstd = rsqrtf(var + 1e-5f);
    for (int i = 0; i < 128; ++i) {
        int c = i * 4 + sub;
        long idx = ((long)(b * CC + c)) * NN + pix0 + px;
        float y = x[idx] + p[idx] * scs[c] + shs[c];
        out[idx] = (y - mu) * rstd * lg[c] + lb[c];
    }
}

// ---------------------------------------------------------------------------
extern "C" void kernel_launch(void* const* d_in, const int* in_sizes, int n_in,
                              void* d_out, int out_size, void* d_ws, size_t ws_size,
                              hipStream_t stream) {
    (void)in_sizes; (void)n_in; (void)out_size;
    const float* x     = (const float*)d_in[0];
    const float* Wq    = (const float*)d_in[1];
    const float* Wk    = (const float*)d_in[2];
    const float* Wv    = (const float*)d_in[3];
    const float* bias  = (const float*)d_in[4];
    const float* Wproj = (const float*)d_in[5];
    const float* bng   = (const float*)d_in[6];
    const float* bnb   = (const float*)d_in[7];
    const float* lng   = (const float*)d_in[8];
    const float* lnb   = (const float*)d_in[9];
    float* out = (float*)d_out;   // fp32 output (verified R9)

    char* ws = (char*)d_ws;
    size_t off = 0;
    auto alloc = [&](size_t bytes) {
        char* pp = ws + off;
        off += (bytes + 255) & ~(size_t)255;
        return pp;
    };
    bf16* Wqb = (bf16*)alloc((size_t)CC * CC * 2);          // 0.52 MB
    bf16* Wpb = (bf16*)alloc((size_t)CC * CC * 2);          // 0.52 MB
    float* stats = (float*)alloc(512 * 2 * sizeof(float));

    // Layout A (fully batched) needs ~47 MB; layout B (per-batch) ~11.6 MB.
    size_t needA = off + ((size_t)CC * 2048 * 2 * 2)        // Wkf+Wvf 4.2 MB
                 + ((size_t)BB * NN * CC * 2)               // xt_all 16.8
                 + ((size_t)BB * NRR * CC * 2 * 2)          // kt+vt   8.4
                 + ((size_t)BB * NN * CC * 2) + 4096;       // ot_all 16.8

    if (ws_size >= needA) {
        // ---- layout A: one launch per stage, full batch in grid.z ----
        bf16* Wkf = (bf16*)alloc((size_t)CC * 2048 * 2);
        bf16* Wvf = (bf16*)alloc((size_t)CC * 2048 * 2);
        bf16* xt  = (bf16*)alloc((size_t)BB * NN * CC * 2);
        bf16* kt  = (bf16*)alloc((size_t)BB * NRR * CC * 2);
        bf16* vt  = (bf16*)alloc((size_t)BB * NRR * CC * 2);   // holds V^T [c][m]
        bf16* ot  = (bf16*)alloc((size_t)BB * NN * CC * 2);

        wcvt_kernel<<<1024, 256, 0, stream>>>(Wq, Wproj, Wqb, Wpb, stats);
        wperm_kernel<<<4096, 256, 0, stream>>>(Wk, Wv, Wkf, Wvf);
        transpose_kernel<<<dim3(64, 8, BB), 256, 0, stream>>>(x, xt);
        gemm_kv<<<dim3(16, 8, BB * 2), 256, 0, stream>>>(xt, Wkf, Wvf, kt, vt);
        attn_kernel<<<dim3(32, NHH, BB), 256, 0, stream>>>(xt, Wqb, kt, vt, bias, ot);
        gemm_ntf<<<dim3(8, 64, BB), 256, 0, stream>>>(Wpb, ot, out, stats);
    } else {
        // ---- layout B: per-batch loop, Wkf/Wvf overlay out slice 3 ----
        bf16* Wkf = (bf16*)(out + (size_t)3 * CC * NN);
        bf16* Wvf = Wkf + (size_t)CC * 2048;
        bf16* xt = (bf16*)alloc((size_t)NN * CC * 2);
        bf16* kt = (bf16*)alloc((size_t)NRR * CC * 2);
        bf16* vt = (bf16*)alloc((size_t)NRR * CC * 2);         // V^T [c][m]
        bf16* ot = (bf16*)alloc((size_t)NN * CC * 2);

        wcvt_kernel<<<1024, 256, 0, stream>>>(Wq, Wproj, Wqb, Wpb, stats);
        wperm_kernel<<<4096, 256, 0, stream>>>(Wk, Wv, Wkf, Wvf);
        for (int b = 0; b < BB; ++b) {
            const float* xb = x + (size_t)b * CC * NN;
            float* pb = out + (size_t)b * CC * NN;
            transpose_kernel<<<dim3(64, 8, 1), 256, 0, stream>>>(xb, xt);
            gemm_kv<<<dim3(16, 8, 2), 256, 0, stream>>>(xt, Wkf, Wvf, kt, vt);
            attn_kernel<<<dim3(32, NHH, 1), 256, 0, stream>>>(xt, Wqb, kt, vt, bias, ot);
            gemm_ntf<<<dim3(8, 64, 1), 256, 0, stream>>>(Wpb, ot, pb, stats);
        }
    }

    final_kernel<<<256, 256, 0, stream>>>(x, out, stats, bng, bnb, lng, lnb, out);
}

// Round 7
// 369.377 us; speedup vs baseline: 1.8441x; 1.3578x over previous
//
#include <hip/hip_runtime.h>
#include <hip/hip_bf16.h>
#include <cmath>

typedef __bf16 bf16;
typedef __bf16 bf16x8 __attribute__((ext_vector_type(8)));
typedef float f32x4 __attribute__((ext_vector_type(4)));

#define BB 4
#define CC 512
#define NN 4096      // 64*64 spatial
#define NRR 1024     // 32*32 spatial (stride-2)
#define NHH 8
#define DKK 64

static __device__ __forceinline__ bf16x8 ld8(const bf16* p) {
    return *reinterpret_cast<const bf16x8*>(p);
}

// ---------------------------------------------------------------------------
// weight convert / permute (fp32 -> bf16); also zeroes the BN stats buffer
// ---------------------------------------------------------------------------
__global__ __launch_bounds__(256) void wcvt_kernel(const float* __restrict__ Wq,
                                                   const float* __restrict__ Wp,
                                                   bf16* __restrict__ Wqb,
                                                   bf16* __restrict__ Wpb,
                                                   float* __restrict__ stats) {
    int e = blockIdx.x * 256 + threadIdx.x;   // 262144
    if (e < 1024) stats[e] = 0.f;
    Wqb[e] = (bf16)Wq[e];
    Wpb[e] = (bf16)Wp[e];
}

__global__ __launch_bounds__(256) void wperm_kernel(const float* __restrict__ Wk,
                                                    const float* __restrict__ Wv,
                                                    bf16* __restrict__ Wkf,
                                                    bf16* __restrict__ Wvf) {
    int e = blockIdx.x * 256 + threadIdx.x;   // 512*2048
    int o = e >> 11, q = (e >> 9) & 3, ci = e & 511;
    int src = o * 2048 + ci * 4 + q;
    Wkf[e] = (bf16)Wk[src];
    Wvf[e] = (bf16)Wv[src];
}

// ---------------------------------------------------------------------------
// x (b,C,N) fp32 -> xt (b,N,C) bf16; blockIdx.z = batch
// ---------------------------------------------------------------------------
__global__ __launch_bounds__(256) void transpose_kernel(const float* __restrict__ x,
                                                        bf16* __restrict__ xt) {
    __shared__ bf16 tile[64][65];
    int b = blockIdx.z;
    const float* xb = x + (size_t)b * CC * NN;
    bf16* xtb = xt + (size_t)b * NN * CC;
    int n0 = blockIdx.x * 64, c0 = blockIdx.y * 64;
    int tr = threadIdx.x >> 6, tc = threadIdx.x & 63;
#pragma unroll
    for (int i = 0; i < 64; i += 4)
        tile[tc][i + tr] = (bf16)xb[(long)(c0 + i + tr) * NN + n0 + tc];
    __syncthreads();
#pragma unroll
    for (int i = 0; i < 64; i += 4)
        xtb[(long)(n0 + i + tr) * CC + c0 + tc] = tile[i + tr][tc];
}

// ---------------------------------------------------------------------------
// Merged K+V GEMM with LDS-staged weights; im2col A-gather prefetched.
// blockIdx = (m-tile 64 keys, n-tile 64 ch, batch). Each block computes
// BOTH the K tile (key-major [m][C]) and the V tile (transposed [c][m]).
// Weight tiles double-buffered in LDS (pad-40 rows: conflict-floor).
// ---------------------------------------------------------------------------
__global__ __launch_bounds__(256) void gemm_kv(const bf16* __restrict__ xt,
                                               const bf16* __restrict__ Wkf,
                                               const bf16* __restrict__ Wvf,
                                               bf16* __restrict__ kt,
                                               bf16* __restrict__ vt) {
    __shared__ __align__(16) bf16 smem[2][2][64][40];   // [dbuf][K/V][ch][k]
    const f32x4 fzero = {0.f, 0.f, 0.f, 0.f};
    int b = blockIdx.z;
    const bf16* xtb = xt + (size_t)b * NN * CC;
    int w = threadIdx.x >> 6, lane = threadIdx.x & 63;
    int quad = lane >> 4, l15 = lane & 15;
    int m0 = blockIdx.x * 64 + w * 16;
    int n0 = blockIdx.y * 64;

    // A-gather geometry (im2col): this lane's key row m -> 4 xt rows
    int m = m0 + l15;
    int i2 = m >> 5, j2 = m & 31;
    int nrow[4];
#pragma unroll
    for (int q = 0; q < 4; ++q)
        nrow[q] = (2 * i2 + (q >> 1)) * 64 + 2 * j2 + (q & 1);

    // staging geometry: 256 threads cover 64 rows x 32 k (1 ld8 each/matrix)
    int srow = threadIdx.x >> 2, sseg = threadIdx.x & 3;
    const bf16* wkp = Wkf + (long)(n0 + srow) * 2048 + sseg * 8;
    const bf16* wvp = Wvf + (long)(n0 + srow) * 2048 + sseg * 8;

    // prologue: stage step 0 weights; load step-0 A fragment
    {
        bf16x8 k0v = ld8(wkp);
        bf16x8 v0v = ld8(wvp);
        *reinterpret_cast<bf16x8*>(&smem[0][0][srow][sseg * 8]) = k0v;
        *reinterpret_cast<bf16x8*>(&smem[0][1][srow][sseg * 8]) = v0v;
    }
    bf16x8 areg = ld8(xtb + (long)nrow[0] * CC + quad * 8);
    __syncthreads();

    f32x4 accK[4], accV[4];
#pragma unroll
    for (int ct = 0; ct < 4; ++ct) { accK[ct] = fzero; accV[ct] = fzero; }

    for (int s = 0; s < 64; ++s) {
        int cur = s & 1;
        bf16x8 svK, svV, aNext;
        if (s < 63) {
            int k1 = (s + 1) * 32;
            svK = ld8(wkp + k1);
            svV = ld8(wvp + k1);
            int q1 = k1 >> 9, ci1 = k1 & 511;
            aNext = ld8(xtb + (long)nrow[q1] * CC + ci1 + quad * 8);
        }
#pragma unroll
        for (int ct = 0; ct < 4; ++ct) {
            bf16x8 bk = ld8(&smem[cur][0][ct * 16 + l15][quad * 8]);
            bf16x8 bv = ld8(&smem[cur][1][ct * 16 + l15][quad * 8]);
            accK[ct] = __builtin_amdgcn_mfma_f32_16x16x32_bf16(areg, bk, accK[ct], 0, 0, 0);
            accV[ct] = __builtin_amdgcn_mfma_f32_16x16x32_bf16(areg, bv, accV[ct], 0, 0, 0);
        }
        if (s < 63) {
            areg = aNext;
            *reinterpret_cast<bf16x8*>(&smem[cur ^ 1][0][srow][sseg * 8]) = svK;
            *reinterpret_cast<bf16x8*>(&smem[cur ^ 1][1][srow][sseg * 8]) = svV;
        }
        __syncthreads();
    }

    // K epilogue: key-major [m][C]
    bf16* Ck = kt + (size_t)b * NRR * CC;
#pragma unroll
    for (int ct = 0; ct < 4; ++ct)
#pragma unroll
        for (int r = 0; r < 4; ++r)
            Ck[(long)(m0 + quad * 4 + r) * CC + n0 + ct * 16 + l15] = (bf16)accK[ct][r];

    // V epilogue: transpose to [c][m] via LDS (reuse smem)
    bf16* tt = (bf16*)smem;   // viewed as [64][72]
#pragma unroll
    for (int ct = 0; ct < 4; ++ct)
#pragma unroll
        for (int r = 0; r < 4; ++r)
            tt[(ct * 16 + l15) * 72 + w * 16 + quad * 4 + r] = (bf16)accV[ct][r];
    __syncthreads();
    {
        int row = threadIdx.x >> 2, seg = threadIdx.x & 3;
        bf16x8 v0 = ld8(tt + row * 72 + seg * 16);
        bf16x8 v1 = ld8(tt + row * 72 + seg * 16 + 8);
        bf16* dst = vt + (size_t)b * CC * NRR + (long)(n0 + row) * NRR
                  + (long)blockIdx.x * 64 + seg * 16;
        *reinterpret_cast<bf16x8*>(dst) = v0;
        *reinterpret_cast<bf16x8*>(dst + 8) = v1;
    }
}

// ---------------------------------------------------------------------------
// flash attention, swapped-operand QK^T, TWO query tiles per wave (32 q).
// ---------------------------------------------------------------------------
__global__ __launch_bounds__(256) void attn_kernel(const bf16* __restrict__ xt,
                                                   const bf16* __restrict__ Wqb,
                                                   const bf16* __restrict__ Kt,
                                                   const bf16* __restrict__ Vt,
                                                   const float* __restrict__ bias,
                                                   bf16* __restrict__ Ot) {
    __shared__ __align__(16) bf16 vbuf[2][64 * 64];     // [d][m], chunk-swizzled
    __shared__ __align__(16) bf16 ptile[4][32 * 72];    // per-wave 2 stripes
    const f32x4 fzero = {0.f, 0.f, 0.f, 0.f};
    (void)bias;                                         // softmax-invariant
    int b = blockIdx.z, h = blockIdx.y;
    const bf16* xtb = xt + (size_t)b * NN * CC;
    const bf16* Ktb = Kt + (size_t)b * NRR * CC;
    const bf16* Vtb = Vt + (size_t)b * CC * NRR;        // [c][m] layout
    bf16* Otb = Ot + (size_t)b * NN * CC;
    int w = threadIdx.x >> 6, lane = threadIdx.x & 63;
    int quad = lane >> 4, l15 = lane & 15;
    int m0 = blockIdx.x * 128 + w * 32;                 // tile A: m0, tile B: m0+16

    // staging geometry: thread covers (d0, chunk) and (d0+32, chunk)
    int sd0 = threadIdx.x >> 3, schunk = threadIdx.x & 7;
    const bf16* vsrc0 = Vtb + (long)(h * DKK + sd0) * NRR + schunk * 8;
    const bf16* vsrc1 = vsrc0 + (long)32 * NRR;
    int soff0 = sd0 * 64 + ((schunk ^ (sd0 & 7)) * 8);
    int soff1 = (sd0 + 32) * 64 + ((schunk ^ (sd0 & 7)) * 8);

    // fused Q-GEMM for both tiles: Wq fragments shared
    f32x4 qaccA[4], qaccB[4];
#pragma unroll
    for (int ct = 0; ct < 4; ++ct) { qaccA[ct] = fzero; qaccB[ct] = fzero; }
    {
        const bf16* axpA = xtb + (long)(m0 + l15) * CC + quad * 8;
        const bf16* axpB = axpA + 16 * CC;
        const bf16* bwp = Wqb + (long)(h * DKK + l15) * CC + quad * 8;
#pragma unroll 2
        for (int k0 = 0; k0 < 512; k0 += 32) {
            bf16x8 aA = ld8(axpA + k0);
            bf16x8 aB = ld8(axpB + k0);
#pragma unroll
            for (int ct = 0; ct < 4; ++ct) {
                bf16x8 bv = ld8(bwp + k0 + ct * 16 * CC);
                qaccA[ct] = __builtin_amdgcn_mfma_f32_16x16x32_bf16(aA, bv, qaccA[ct], 0, 0, 0);
                qaccB[ct] = __builtin_amdgcn_mfma_f32_16x16x32_bf16(aB, bv, qaccB[ct], 0, 0, 0);
            }
        }
    }
    // D-layout -> LDS stripes -> B-fragment layout; per-wave fence only
    bf16* ql = &ptile[w][0];
#pragma unroll
    for (int ct = 0; ct < 4; ++ct)
#pragma unroll
        for (int r = 0; r < 4; ++r) {
            ql[(quad * 4 + r) * 72 + ct * 16 + l15] = (bf16)qaccA[ct][r];
            ql[(16 + quad * 4 + r) * 72 + ct * 16 + l15] = (bf16)qaccB[ct][r];
        }
    asm volatile("s_waitcnt lgkmcnt(0)" ::: "memory");
    __builtin_amdgcn_sched_barrier(0);
    bf16x8 aq0A = ld8(ql + l15 * 72 + quad * 8);
    bf16x8 aq1A = ld8(ql + l15 * 72 + 32 + quad * 8);
    bf16x8 aq0B = ld8(ql + (16 + l15) * 72 + quad * 8);
    bf16x8 aq1B = ld8(ql + (16 + l15) * 72 + 32 + quad * 8);

    // prologue: stage V tile 0 into vbuf[0]
    {
        bf16x8 s0 = ld8(vsrc0);
        bf16x8 s1 = ld8(vsrc1);
        *reinterpret_cast<bf16x8*>(&vbuf[0][0] + soff0) = s0;
        *reinterpret_cast<bf16x8*>(&vbuf[0][0] + soff1) = s1;
    }
    __syncthreads();

    f32x4 oaccA[4], oaccB[4];
    float mrowA = -1e30f, lrowA = 0.f, mrowB = -1e30f, lrowB = 0.f;
#pragma unroll
    for (int ct = 0; ct < 4; ++ct) { oaccA[ct] = fzero; oaccB[ct] = fzero; }

    for (int kt = 0; kt < 16; ++kt) {
        int cur = kt & 1;
        // ---- issue next-tile V loads early
        bf16x8 sv0, sv1;
        if (kt < 15) {
            sv0 = ld8(vsrc0 + (kt + 1) * 64);
            sv1 = ld8(vsrc1 + (kt + 1) * 64);
        }

        // S^T = K Q^T for both tiles (K fragments shared)
        f32x4 sA[4], sB[4];
#pragma unroll
        for (int ct = 0; ct < 4; ++ct) { sA[ct] = fzero; sB[ct] = fzero; }
        const bf16* kp = Ktb + (long)(kt * 64 + l15) * CC + h * DKK + quad * 8;
#pragma unroll
        for (int ct = 0; ct < 4; ++ct) {
            bf16x8 ka0 = ld8(kp + ct * 16 * CC);
            bf16x8 ka1 = ld8(kp + ct * 16 * CC + 32);
            sA[ct] = __builtin_amdgcn_mfma_f32_16x16x32_bf16(ka0, aq0A, sA[ct], 0, 0, 0);
            sA[ct] = __builtin_amdgcn_mfma_f32_16x16x32_bf16(ka1, aq1A, sA[ct], 0, 0, 0);
            sB[ct] = __builtin_amdgcn_mfma_f32_16x16x32_bf16(ka0, aq0B, sB[ct], 0, 0, 0);
            sB[ct] = __builtin_amdgcn_mfma_f32_16x16x32_bf16(ka1, aq1B, sB[ct], 0, 0, 0);
        }

        // online softmax: two independent scalar chains (ILP)
        float pvA[4][4], pvB[4][4];
#pragma unroll
        for (int ct = 0; ct < 4; ++ct)
#pragma unroll
            for (int r = 0; r < 4; ++r) {
                pvA[ct][r] = sA[ct][r] * 0.125f;
                pvB[ct][r] = sB[ct][r] * 0.125f;
            }
        float tA0 = fmaxf(fmaxf(pvA[0][0], pvA[0][1]), fmaxf(pvA[0][2], pvA[0][3]));
        float tA1 = fmaxf(fmaxf(pvA[1][0], pvA[1][1]), fmaxf(pvA[1][2], pvA[1][3]));
        float tA2 = fmaxf(fmaxf(pvA[2][0], pvA[2][1]), fmaxf(pvA[2][2], pvA[2][3]));
        float tA3 = fmaxf(fmaxf(pvA[3][0], pvA[3][1]), fmaxf(pvA[3][2], pvA[3][3]));
        float tB0 = fmaxf(fmaxf(pvB[0][0], pvB[0][1]), fmaxf(pvB[0][2], pvB[0][3]));
        float tB1 = fmaxf(fmaxf(pvB[1][0], pvB[1][1]), fmaxf(pvB[1][2], pvB[1][3]));
        float tB2 = fmaxf(fmaxf(pvB[2][0], pvB[2][1]), fmaxf(pvB[2][2], pvB[2][3]));
        float tB3 = fmaxf(fmaxf(pvB[3][0], pvB[3][1]), fmaxf(pvB[3][2], pvB[3][3]));
        float tmaxA = fmaxf(fmaxf(tA0, tA1), fmaxf(tA2, tA3));
        float tmaxB = fmaxf(fmaxf(tB0, tB1), fmaxf(tB2, tB3));
        tmaxA = fmaxf(tmaxA, __shfl_xor(tmaxA, 16));
        tmaxB = fmaxf(tmaxB, __shfl_xor(tmaxB, 16));
        tmaxA = fmaxf(tmaxA, __shfl_xor(tmaxA, 32));
        tmaxB = fmaxf(tmaxB, __shfl_xor(tmaxB, 32));
        float mnA = fmaxf(mrowA, tmaxA), mnB = fmaxf(mrowB, tmaxB);
        float alphaA = __expf(mrowA - mnA), alphaB = __expf(mrowB - mnB);
        mrowA = mnA; mrowB = mnB;
        float lsA = 0.f, lsB = 0.f;
#pragma unroll
        for (int ct = 0; ct < 4; ++ct)
#pragma unroll
            for (int r = 0; r < 4; ++r) {
                pvA[ct][r] = __expf(pvA[ct][r] - mnA);
                pvB[ct][r] = __expf(pvB[ct][r] - mnB);
                lsA += pvA[ct][r];
                lsB += pvB[ct][r];
            }
        lrowA = lrowA * alphaA + lsA;
        lrowB = lrowB * alphaB + lsB;
#pragma unroll
        for (int ct = 0; ct < 4; ++ct)
#pragma unroll
            for (int r = 0; r < 4; ++r) {
                oaccA[ct][r] *= alphaA;
                oaccB[ct][r] *= alphaB;
            }

        // P^T stripes: row = query (A: l15, B: 16+l15), col = key; ONE fence
        bf16* pl = &ptile[w][0];
#pragma unroll
        for (int ct = 0; ct < 4; ++ct)
#pragma unroll
            for (int r = 0; r < 4; ++r) {
                pl[l15 * 72 + ct * 16 + quad * 4 + r] = (bf16)pvA[ct][r];
                pl[(16 + l15) * 72 + ct * 16 + quad * 4 + r] = (bf16)pvB[ct][r];
            }
        asm volatile("s_waitcnt lgkmcnt(0)" ::: "memory");
        __builtin_amdgcn_sched_barrier(0);

        // O^T += V^T P^T  (V fragments shared between tiles)
        const bf16* vb = &vbuf[cur][0];
#pragma unroll
        for (int ks = 0; ks < 2; ++ks) {
            bf16x8 bpA = ld8(pl + l15 * 72 + ks * 32 + quad * 8);
            bf16x8 bpB = ld8(pl + (16 + l15) * 72 + ks * 32 + quad * 8);
#pragma unroll
            for (int ct = 0; ct < 4; ++ct) {
                int d = ct * 16 + l15;
                bf16x8 av = ld8(vb + d * 64 + (((ks * 4 + quad) ^ (d & 7)) * 8));
                oaccA[ct] = __builtin_amdgcn_mfma_f32_16x16x32_bf16(av, bpA, oaccA[ct], 0, 0, 0);
                oaccB[ct] = __builtin_amdgcn_mfma_f32_16x16x32_bf16(av, bpB, oaccB[ct], 0, 0, 0);
            }
        }

        // ---- write staged V for tile kt+1 into the other buffer
        if (kt < 15) {
            bf16* wb = &vbuf[cur ^ 1][0];
            *reinterpret_cast<bf16x8*>(wb + soff0) = sv0;
            *reinterpret_cast<bf16x8*>(wb + soff1) = sv1;
        }
        __syncthreads();
    }

    // final denominators
    lrowA += __shfl_xor(lrowA, 16);
    lrowB += __shfl_xor(lrowB, 16);
    lrowA += __shfl_xor(lrowA, 32);
    lrowB += __shfl_xor(lrowB, 32);
    float invA = 1.f / lrowA, invB = 1.f / lrowB;

    // O^T -> transpose via ptile stripes -> coalesced stores
    bf16* pl = &ptile[w][0];
#pragma unroll
    for (int ct = 0; ct < 4; ++ct)
#pragma unroll
        for (int r = 0; r < 4; ++r) {
            pl[l15 * 72 + ct * 16 + quad * 4 + r] = (bf16)(oaccA[ct][r] * invA);
            pl[(16 + l15) * 72 + ct * 16 + quad * 4 + r] = (bf16)(oaccB[ct][r] * invB);
        }
    asm volatile("s_waitcnt lgkmcnt(0)" ::: "memory");
    __builtin_amdgcn_sched_barrier(0);
    {
        bf16x8 o0 = ld8(pl + l15 * 72 + quad * 16);
        bf16x8 o1 = ld8(pl + l15 * 72 + quad * 16 + 8);
        bf16* dst = Otb + (long)(m0 + l15) * CC + h * DKK + quad * 16;
        *reinterpret_cast<bf16x8*>(dst) = o0;
        *reinterpret_cast<bf16x8*>(dst + 8) = o1;
        bf16x8 p0 = ld8(pl + (16 + l15) * 72 + quad * 16);
        bf16x8 p1 = ld8(pl + (16 + l15) * 72 + quad * 16 + 8);
        bf16* dstB = Otb + (long)(m0 + 16 + l15) * CC + h * DKK + quad * 16;
        *reinterpret_cast<bf16x8*>(dstB) = p0;
        *reinterpret_cast<bf16x8*>(dstB + 8) = p1;
    }
}

// ---------------------------------------------------------------------------
// proj: p[b,o,n] = Wproj . ot[b,n,:]^T, fp32 out; LDS-staged double-buffered
// GEMM (A = Wpb tile, B = ot tile). BN raw stats fused via shfl + atomics.
// ---------------------------------------------------------------------------
__global__ __launch_bounds__(256) void gemm_ntf(const bf16* __restrict__ A,
                                                const bf16* __restrict__ Bt,
                                                float* __restrict__ C,
                                                float* __restrict__ stats) {
    __shared__ __align__(16) bf16 sa[2][64][40];   // Wpb tile [ch][k]
    __shared__ __align__(16) bf16 sb[2][64][40];   // ot tile [px][k]
    const f32x4 fzero = {0.f, 0.f, 0.f, 0.f};
    int b = blockIdx.z;
    const bf16* Btb = Bt + (size_t)b * NN * CC;
    float* Cb = C + (size_t)b * CC * NN;
    int w = threadIdx.x >> 6, lane = threadIdx.x & 63;
    int quad = lane >> 4, l15 = lane & 15;
    long m0 = (long)blockIdx.x * 64 + w * 16;
    long n0 = (long)blockIdx.y * 64;

    // staging: 256 threads cover 64 rows x 32 k (1 ld8 each per matrix)
    int srow = threadIdx.x >> 2, sseg = threadIdx.x & 3;
    const bf16* apS = A + ((long)blockIdx.x * 64 + srow) * CC + sseg * 8;
    const bf16* bpS = Btb + (n0 + srow) * CC + sseg * 8;

    {
        bf16x8 a0 = ld8(apS);
        bf16x8 b0 = ld8(bpS);
        *reinterpret_cast<bf16x8*>(&sa[0][srow][sseg * 8]) = a0;
        *reinterpret_cast<bf16x8*>(&sb[0][srow][sseg * 8]) = b0;
    }
    __syncthreads();

    f32x4 acc[4];
#pragma unroll
    for (int ct = 0; ct < 4; ++ct) acc[ct] = fzero;

    for (int s = 0; s < 16; ++s) {
        int cur = s & 1;
        bf16x8 svA, svB;
        if (s < 15) {
            int k1 = (s + 1) * 32;
            svA = ld8(apS + k1);
            svB = ld8(bpS + k1);
        }
        bf16x8 a = ld8(&sa[cur][w * 16 + l15][quad * 8]);
#pragma unroll
        for (int ct = 0; ct < 4; ++ct) {
            bf16x8 bv = ld8(&sb[cur][ct * 16 + l15][quad * 8]);
            acc[ct] = __builtin_amdgcn_mfma_f32_16x16x32_bf16(a, bv, acc[ct], 0, 0, 0);
        }
        if (s < 15) {
            *reinterpret_cast<bf16x8*>(&sa[cur ^ 1][srow][sseg * 8]) = svA;
            *reinterpret_cast<bf16x8*>(&sb[cur ^ 1][srow][sseg * 8]) = svB;
        }
        __syncthreads();
    }

    float ps[4], pss[4];
#pragma unroll
    for (int r = 0; r < 4; ++r) { ps[r] = 0.f; pss[r] = 0.f; }
#pragma unroll
    for (int ct = 0; ct < 4; ++ct)
#pragma unroll
        for (int r = 0; r < 4; ++r) {
            float v = acc[ct][r];
            Cb[(m0 + quad * 4 + r) * NN + n0 + ct * 16 + l15] = v;
            ps[r] += v; pss[r] += v * v;
        }
    // reduce over l15 (16 lanes share channel m0+quad*4+r)
#pragma unroll
    for (int off = 1; off < 16; off <<= 1)
#pragma unroll
        for (int r = 0; r < 4; ++r) {
            ps[r] += __shfl_xor(ps[r], off);
            pss[r] += __shfl_xor(pss[r], off);
        }
    if (l15 == 0) {
#pragma unroll
        for (int r = 0; r < 4; ++r) {
            int c = (int)(m0 + quad * 4 + r);
            atomicAdd(&stats[c * 2], ps[r]);
            atomicAdd(&stats[c * 2 + 1], pss[r]);
        }
    }
}

// ---------------------------------------------------------------------------
// y = x + bn(p); LayerNorm over C per pixel; BN scale/shift derived from raw
// stats in a small LDS preamble. fp32 in-place on d_out.
// ---------------------------------------------------------------------------
__global__ __launch_bounds__(256) void final_kernel(const float* __restrict__ x,
                                                    const float* __restrict__ p,
                                                    const float* __restrict__ stats,
                                                    const float* __restrict__ bng,
                                                    const float* __restrict__ bnb,
                                                    const float* __restrict__ lg,
                                                    const float* __restrict__ lb,
                                                    float* __restrict__ out) {
    __shared__ float scs[512], shs[512];
    for (int c = threadIdx.x; c < 512; c += 256) {
        float sum = stats[c * 2], ssq = stats[c * 2 + 1];
        float mean = sum * (1.f / 16384.f);
        float var = ssq * (1.f / 16384.f) - mean * mean;
        float rstd = rsqrtf(var + 1e-5f);
        float sc = bng[c] * rstd;
        scs[c] = sc;
        shs[c] = bnb[c] - mean * sc;
    }
    __syncthreads();
    int blk = blockIdx.x;
    int b = blk >> 6;
    int pix0 = (blk & 63) * 64;
    int sub = threadIdx.x >> 6, px = threadIdx.x & 63;
    float s = 0.f, ss = 0.f;
    for (int i = 0; i < 128; ++i) {
        int c = i * 4 + sub;
        long idx = ((long)(b * CC + c)) * NN + pix0 + px;
        float y = x[idx] + p[idx] * scs[c] + shs[c];
        s += y; ss += y * y;
    }
    __shared__ float rs[4][64], rss[4][64];
    rs[sub][px] = s; rss[sub][px] = ss;
    __syncthreads();
    float sum = rs[0][px] + rs[1][px] + rs[2][px] + rs[3][px];
    float sq  = rss[0][px] + rss[1][px] + rss[2][px] + rss[3][px];
    float mu = sum * (1.f / 512.f);
    float var = sq * (1.f / 512.f) - mu * mu;
    float rstd = rsqrtf(var + 1e-5f);
    for (int i = 0; i < 128; ++i) {
        int c = i * 4 + sub;
        long idx = ((long)(b * CC + c)) * NN + pix0 + px;
        float y = x[idx] + p[idx] * scs[c] + shs[c];
        out[idx] = (y - mu) * rstd * lg[c] + lb[c];
    }
}

// ---------------------------------------------------------------------------
extern "C" void kernel_launch(void* const* d_in, const int* in_sizes, int n_in,
                              void* d_out, int out_size, void* d_ws, size_t ws_size,
                              hipStream_t stream) {
    (void)in_sizes; (void)n_in; (void)out_size;
    const float* x     = (const float*)d_in[0];
    const float* Wq    = (const float*)d_in[1];
    const float* Wk    = (const float*)d_in[2];
    const float* Wv    = (const float*)d_in[3];
    const float* bias  = (const float*)d_in[4];
    const float* Wproj = (const float*)d_in[5];
    const float* bng   = (const float*)d_in[6];
    const float* bnb   = (const float*)d_in[7];
    const float* lng   = (const float*)d_in[8];
    const float* lnb   = (const float*)d_in[9];
    float* out = (float*)d_out;   // fp32 output (verified R9)

    char* ws = (char*)d_ws;
    size_t off = 0;
    auto alloc = [&](size_t bytes) {
        char* pp = ws + off;
        off += (bytes + 255) & ~(size_t)255;
        return pp;
    };
    bf16* Wqb = (bf16*)alloc((size_t)CC * CC * 2);          // 0.52 MB
    bf16* Wpb = (bf16*)alloc((size_t)CC * CC * 2);          // 0.52 MB
    float* stats = (float*)alloc(512 * 2 * sizeof(float));

    // Layout A (fully batched) needs ~47 MB; layout B (per-batch) ~11.6 MB.
    size_t needA = off + ((size_t)CC * 2048 * 2 * 2)        // Wkf+Wvf 4.2 MB
                 + ((size_t)BB * NN * CC * 2)               // xt_all 16.8
                 + ((size_t)BB * NRR * CC * 2 * 2)          // kt+vt   8.4
                 + ((size_t)BB * NN * CC * 2) + 4096;       // ot_all 16.8

    if (ws_size >= needA) {
        // ---- layout A: one launch per stage, full batch in grid.z ----
        bf16* Wkf = (bf16*)alloc((size_t)CC * 2048 * 2);
        bf16* Wvf = (bf16*)alloc((size_t)CC * 2048 * 2);
        bf16* xt  = (bf16*)alloc((size_t)BB * NN * CC * 2);
        bf16* kt  = (bf16*)alloc((size_t)BB * NRR * CC * 2);
        bf16* vt  = (bf16*)alloc((size_t)BB * NRR * CC * 2);   // holds V^T [c][m]
        bf16* ot  = (bf16*)alloc((size_t)BB * NN * CC * 2);

        wcvt_kernel<<<1024, 256, 0, stream>>>(Wq, Wproj, Wqb, Wpb, stats);
        wperm_kernel<<<4096, 256, 0, stream>>>(Wk, Wv, Wkf, Wvf);
        transpose_kernel<<<dim3(64, 8, BB), 256, 0, stream>>>(x, xt);
        gemm_kv<<<dim3(16, 8, BB), 256, 0, stream>>>(xt, Wkf, Wvf, kt, vt);
        attn_kernel<<<dim3(32, NHH, BB), 256, 0, stream>>>(xt, Wqb, kt, vt, bias, ot);
        gemm_ntf<<<dim3(8, 64, BB), 256, 0, stream>>>(Wpb, ot, out, stats);
    } else {
        // ---- layout B: per-batch loop, Wkf/Wvf overlay out slice 3 ----
        bf16* Wkf = (bf16*)(out + (size_t)3 * CC * NN);
        bf16* Wvf = Wkf + (size_t)CC * 2048;
        bf16* xt = (bf16*)alloc((size_t)NN * CC * 2);
        bf16* kt = (bf16*)alloc((size_t)NRR * CC * 2);
        bf16* vt = (bf16*)alloc((size_t)NRR * CC * 2);         // V^T [c][m]
        bf16* ot = (bf16*)alloc((size_t)NN * CC * 2);

        wcvt_kernel<<<1024, 256, 0, stream>>>(Wq, Wproj, Wqb, Wpb, stats);
        wperm_kernel<<<4096, 256, 0, stream>>>(Wk, Wv, Wkf, Wvf);
        for (int b = 0; b < BB; ++b) {
            const float* xb = x + (size_t)b * CC * NN;
            float* pb = out + (size_t)b * CC * NN;
            transpose_kernel<<<dim3(64, 8, 1), 256, 0, stream>>>(xb, xt);
            gemm_kv<<<dim3(16, 8, 1), 256, 0, stream>>>(xt, Wkf, Wvf, kt, vt);
            attn_kernel<<<dim3(32, NHH, 1), 256, 0, stream>>>(xt, Wqb, kt, vt, bias, ot);
            gemm_ntf<<<dim3(8, 64, 1), 256, 0, stream>>>(Wpb, ot, pb, stats);
        }
    }

    final_kernel<<<256, 256, 0, stream>>>(x, out, stats, bng, bnb, lng, lnb, out);
}

// Round 8
// 367.048 us; speedup vs baseline: 1.8558x; 1.0063x over previous
//
#include <hip/hip_runtime.h>
#include <hip/hip_bf16.h>
#include <cmath>

typedef __bf16 bf16;
typedef __bf16 bf16x4 __attribute__((ext_vector_type(4)));
typedef __bf16 bf16x8 __attribute__((ext_vector_type(8)));
typedef float f32x4 __attribute__((ext_vector_type(4)));

#define BB 4
#define CC 512
#define NN 4096      // 64*64 spatial
#define NRR 1024     // 32*32 spatial (stride-2)
#define NHH 8
#define DKK 64

static __device__ __forceinline__ bf16x8 ld8(const bf16* p) {
    return *reinterpret_cast<const bf16x8*>(p);
}

// ---------------------------------------------------------------------------
// weight convert / permute (fp32 -> bf16); also zeroes the BN stats buffer
// ---------------------------------------------------------------------------
__global__ __launch_bounds__(256) void wcvt_kernel(const float* __restrict__ Wq,
                                                   const float* __restrict__ Wp,
                                                   bf16* __restrict__ Wqb,
                                                   bf16* __restrict__ Wpb,
                                                   float* __restrict__ stats) {
    int e = blockIdx.x * 256 + threadIdx.x;   // 262144
    if (e < 1024) stats[e] = 0.f;
    Wqb[e] = (bf16)Wq[e];
    Wpb[e] = (bf16)Wp[e];
}

__global__ __launch_bounds__(256) void wperm_kernel(const float* __restrict__ Wk,
                                                    const float* __restrict__ Wv,
                                                    bf16* __restrict__ Wkf,
                                                    bf16* __restrict__ Wvf) {
    int e = blockIdx.x * 256 + threadIdx.x;   // 512*2048
    int o = e >> 11, q = (e >> 9) & 3, ci = e & 511;
    int src = o * 2048 + ci * 4 + q;
    Wkf[e] = (bf16)Wk[src];
    Wvf[e] = (bf16)Wv[src];
}

// ---------------------------------------------------------------------------
// x (b,C,N) fp32 -> xt (b,N,C) bf16; blockIdx.z = batch
// ---------------------------------------------------------------------------
__global__ __launch_bounds__(256) void transpose_kernel(const float* __restrict__ x,
                                                        bf16* __restrict__ xt) {
    __shared__ bf16 tile[64][65];
    int b = blockIdx.z;
    const float* xb = x + (size_t)b * CC * NN;
    bf16* xtb = xt + (size_t)b * NN * CC;
    int n0 = blockIdx.x * 64, c0 = blockIdx.y * 64;
    int tr = threadIdx.x >> 6, tc = threadIdx.x & 63;
#pragma unroll
    for (int i = 0; i < 64; i += 4)
        tile[tc][i + tr] = (bf16)xb[(long)(c0 + i + tr) * NN + n0 + tc];
    __syncthreads();
#pragma unroll
    for (int i = 0; i < 64; i += 4)
        xtb[(long)(n0 + i + tr) * CC + c0 + tc] = tile[i + tr][tc];
}

// ---------------------------------------------------------------------------
// Merged K+V GEMM with LDS-staged weights; im2col A-gather prefetched.
// ---------------------------------------------------------------------------
__global__ __launch_bounds__(256) void gemm_kv(const bf16* __restrict__ xt,
                                               const bf16* __restrict__ Wkf,
                                               const bf16* __restrict__ Wvf,
                                               bf16* __restrict__ kt,
                                               bf16* __restrict__ vt) {
    __shared__ __align__(16) bf16 smem[2][2][64][40];   // [dbuf][K/V][ch][k]
    const f32x4 fzero = {0.f, 0.f, 0.f, 0.f};
    int b = blockIdx.z;
    const bf16* xtb = xt + (size_t)b * NN * CC;
    int w = threadIdx.x >> 6, lane = threadIdx.x & 63;
    int quad = lane >> 4, l15 = lane & 15;
    int m0 = blockIdx.x * 64 + w * 16;
    int n0 = blockIdx.y * 64;

    int m = m0 + l15;
    int i2 = m >> 5, j2 = m & 31;
    int nrow[4];
#pragma unroll
    for (int q = 0; q < 4; ++q)
        nrow[q] = (2 * i2 + (q >> 1)) * 64 + 2 * j2 + (q & 1);

    int srow = threadIdx.x >> 2, sseg = threadIdx.x & 3;
    const bf16* wkp = Wkf + (long)(n0 + srow) * 2048 + sseg * 8;
    const bf16* wvp = Wvf + (long)(n0 + srow) * 2048 + sseg * 8;

    {
        bf16x8 k0v = ld8(wkp);
        bf16x8 v0v = ld8(wvp);
        *reinterpret_cast<bf16x8*>(&smem[0][0][srow][sseg * 8]) = k0v;
        *reinterpret_cast<bf16x8*>(&smem[0][1][srow][sseg * 8]) = v0v;
    }
    bf16x8 areg = ld8(xtb + (long)nrow[0] * CC + quad * 8);
    __syncthreads();

    f32x4 accK[4], accV[4];
#pragma unroll
    for (int ct = 0; ct < 4; ++ct) { accK[ct] = fzero; accV[ct] = fzero; }

    for (int s = 0; s < 64; ++s) {
        int cur = s & 1;
        bf16x8 svK, svV, aNext;
        if (s < 63) {
            int k1 = (s + 1) * 32;
            svK = ld8(wkp + k1);
            svV = ld8(wvp + k1);
            int q1 = k1 >> 9, ci1 = k1 & 511;
            aNext = ld8(xtb + (long)nrow[q1] * CC + ci1 + quad * 8);
        }
#pragma unroll
        for (int ct = 0; ct < 4; ++ct) {
            bf16x8 bk = ld8(&smem[cur][0][ct * 16 + l15][quad * 8]);
            bf16x8 bv = ld8(&smem[cur][1][ct * 16 + l15][quad * 8]);
            accK[ct] = __builtin_amdgcn_mfma_f32_16x16x32_bf16(areg, bk, accK[ct], 0, 0, 0);
            accV[ct] = __builtin_amdgcn_mfma_f32_16x16x32_bf16(areg, bv, accV[ct], 0, 0, 0);
        }
        if (s < 63) {
            areg = aNext;
            *reinterpret_cast<bf16x8*>(&smem[cur ^ 1][0][srow][sseg * 8]) = svK;
            *reinterpret_cast<bf16x8*>(&smem[cur ^ 1][1][srow][sseg * 8]) = svV;
        }
        __syncthreads();
    }

    bf16* Ck = kt + (size_t)b * NRR * CC;
#pragma unroll
    for (int ct = 0; ct < 4; ++ct)
#pragma unroll
        for (int r = 0; r < 4; ++r)
            Ck[(long)(m0 + quad * 4 + r) * CC + n0 + ct * 16 + l15] = (bf16)accK[ct][r];

    bf16* tt = (bf16*)smem;   // viewed as [64][72]
#pragma unroll
    for (int ct = 0; ct < 4; ++ct)
#pragma unroll
        for (int r = 0; r < 4; ++r)
            tt[(ct * 16 + l15) * 72 + w * 16 + quad * 4 + r] = (bf16)accV[ct][r];
    __syncthreads();
    {
        int row = threadIdx.x >> 2, seg = threadIdx.x & 3;
        bf16x8 v0 = ld8(tt + row * 72 + seg * 16);
        bf16x8 v1 = ld8(tt + row * 72 + seg * 16 + 8);
        bf16* dst = vt + (size_t)b * CC * NRR + (long)(n0 + row) * NRR
                  + (long)blockIdx.x * 64 + seg * 16;
        *reinterpret_cast<bf16x8*>(dst) = v0;
        *reinterpret_cast<bf16x8*>(dst + 8) = v1;
    }
}

// ---------------------------------------------------------------------------
// flash attention, swapped-operand QK^T, two query tiles per wave (32 q).
// This round: exp2-domain softmax + defer-rescale (T13), vectorized P
// writes (b64), vbuf padded to stride 72 (bank-rotating rows, same XOR on
// write+read sides).
// ---------------------------------------------------------------------------
#define VST 72   // vbuf row stride (bf16 elements)
__global__ __launch_bounds__(256) void attn_kernel(const bf16* __restrict__ xt,
                                                   const bf16* __restrict__ Wqb,
                                                   const bf16* __restrict__ Kt,
                                                   const bf16* __restrict__ Vt,
                                                   const float* __restrict__ bias,
                                                   bf16* __restrict__ Ot) {
    __shared__ __align__(16) bf16 vbuf[2][64 * VST];    // [d][m] padded+XOR
    __shared__ __align__(16) bf16 ptile[4][32 * 72];    // per-wave 2 stripes
    const f32x4 fzero = {0.f, 0.f, 0.f, 0.f};
    const float SCALE2 = 0.125f * 1.44269504089f;       // into log2 domain
    (void)bias;                                         // softmax-invariant
    int b = blockIdx.z, h = blockIdx.y;
    const bf16* xtb = xt + (size_t)b * NN * CC;
    const bf16* Ktb = Kt + (size_t)b * NRR * CC;
    const bf16* Vtb = Vt + (size_t)b * CC * NRR;        // [c][m] layout
    bf16* Otb = Ot + (size_t)b * NN * CC;
    int w = threadIdx.x >> 6, lane = threadIdx.x & 63;
    int quad = lane >> 4, l15 = lane & 15;
    int m0 = blockIdx.x * 128 + w * 32;                 // tile A: m0, tile B: m0+16

    // staging geometry: thread covers (d0, chunk) and (d0+32, chunk)
    int sd0 = threadIdx.x >> 3, schunk = threadIdx.x & 7;
    const bf16* vsrc0 = Vtb + (long)(h * DKK + sd0) * NRR + schunk * 8;
    const bf16* vsrc1 = vsrc0 + (long)32 * NRR;
    int soff0 = sd0 * VST + ((schunk ^ (sd0 & 7)) * 8);
    int soff1 = (sd0 + 32) * VST + ((schunk ^ (sd0 & 7)) * 8);

    // fused Q-GEMM for both tiles
    f32x4 qaccA[4], qaccB[4];
#pragma unroll
    for (int ct = 0; ct < 4; ++ct) { qaccA[ct] = fzero; qaccB[ct] = fzero; }
    {
        const bf16* axpA = xtb + (long)(m0 + l15) * CC + quad * 8;
        const bf16* axpB = axpA + 16 * CC;
        const bf16* bwp = Wqb + (long)(h * DKK + l15) * CC + quad * 8;
#pragma unroll 2
        for (int k0 = 0; k0 < 512; k0 += 32) {
            bf16x8 aA = ld8(axpA + k0);
            bf16x8 aB = ld8(axpB + k0);
#pragma unroll
            for (int ct = 0; ct < 4; ++ct) {
                bf16x8 bv = ld8(bwp + k0 + ct * 16 * CC);
                qaccA[ct] = __builtin_amdgcn_mfma_f32_16x16x32_bf16(aA, bv, qaccA[ct], 0, 0, 0);
                qaccB[ct] = __builtin_amdgcn_mfma_f32_16x16x32_bf16(aB, bv, qaccB[ct], 0, 0, 0);
            }
        }
    }
    bf16* ql = &ptile[w][0];
#pragma unroll
    for (int ct = 0; ct < 4; ++ct)
#pragma unroll
        for (int r = 0; r < 4; ++r) {
            ql[(quad * 4 + r) * 72 + ct * 16 + l15] = (bf16)qaccA[ct][r];
            ql[(16 + quad * 4 + r) * 72 + ct * 16 + l15] = (bf16)qaccB[ct][r];
        }
    asm volatile("s_waitcnt lgkmcnt(0)" ::: "memory");
    __builtin_amdgcn_sched_barrier(0);
    bf16x8 aq0A = ld8(ql + l15 * 72 + quad * 8);
    bf16x8 aq1A = ld8(ql + l15 * 72 + 32 + quad * 8);
    bf16x8 aq0B = ld8(ql + (16 + l15) * 72 + quad * 8);
    bf16x8 aq1B = ld8(ql + (16 + l15) * 72 + 32 + quad * 8);

    // prologue: stage V tile 0
    {
        bf16x8 s0 = ld8(vsrc0);
        bf16x8 s1 = ld8(vsrc1);
        *reinterpret_cast<bf16x8*>(&vbuf[0][0] + soff0) = s0;
        *reinterpret_cast<bf16x8*>(&vbuf[0][0] + soff1) = s1;
    }
    __syncthreads();

    f32x4 oaccA[4], oaccB[4];
    float mrowA = -1e30f, lrowA = 0.f, mrowB = -1e30f, lrowB = 0.f;
#pragma unroll
    for (int ct = 0; ct < 4; ++ct) { oaccA[ct] = fzero; oaccB[ct] = fzero; }

    for (int kt = 0; kt < 16; ++kt) {
        int cur = kt & 1;
        bf16x8 sv0, sv1;
        if (kt < 15) {
            sv0 = ld8(vsrc0 + (kt + 1) * 64);
            sv1 = ld8(vsrc1 + (kt + 1) * 64);
        }

        // S^T = K Q^T for both tiles (K fragments shared)
        f32x4 sA[4], sB[4];
#pragma unroll
        for (int ct = 0; ct < 4; ++ct) { sA[ct] = fzero; sB[ct] = fzero; }
        const bf16* kp = Ktb + (long)(kt * 64 + l15) * CC + h * DKK + quad * 8;
#pragma unroll
        for (int ct = 0; ct < 4; ++ct) {
            bf16x8 ka0 = ld8(kp + ct * 16 * CC);
            bf16x8 ka1 = ld8(kp + ct * 16 * CC + 32);
            sA[ct] = __builtin_amdgcn_mfma_f32_16x16x32_bf16(ka0, aq0A, sA[ct], 0, 0, 0);
            sA[ct] = __builtin_amdgcn_mfma_f32_16x16x32_bf16(ka1, aq1A, sA[ct], 0, 0, 0);
            sB[ct] = __builtin_amdgcn_mfma_f32_16x16x32_bf16(ka0, aq0B, sB[ct], 0, 0, 0);
            sB[ct] = __builtin_amdgcn_mfma_f32_16x16x32_bf16(ka1, aq1B, sB[ct], 0, 0, 0);
        }

        // max tree on RAW s, scale once after reduce (log2 domain)
        float tA0 = fmaxf(fmaxf(sA[0][0], sA[0][1]), fmaxf(sA[0][2], sA[0][3]));
        float tA1 = fmaxf(fmaxf(sA[1][0], sA[1][1]), fmaxf(sA[1][2], sA[1][3]));
        float tA2 = fmaxf(fmaxf(sA[2][0], sA[2][1]), fmaxf(sA[2][2], sA[2][3]));
        float tA3 = fmaxf(fmaxf(sA[3][0], sA[3][1]), fmaxf(sA[3][2], sA[3][3]));
        float tB0 = fmaxf(fmaxf(sB[0][0], sB[0][1]), fmaxf(sB[0][2], sB[0][3]));
        float tB1 = fmaxf(fmaxf(sB[1][0], sB[1][1]), fmaxf(sB[1][2], sB[1][3]));
        float tB2 = fmaxf(fmaxf(sB[2][0], sB[2][1]), fmaxf(sB[2][2], sB[2][3]));
        float tB3 = fmaxf(fmaxf(sB[3][0], sB[3][1]), fmaxf(sB[3][2], sB[3][3]));
        float tmaxA = fmaxf(fmaxf(tA0, tA1), fmaxf(tA2, tA3));
        float tmaxB = fmaxf(fmaxf(tB0, tB1), fmaxf(tB2, tB3));
        tmaxA = fmaxf(tmaxA, __shfl_xor(tmaxA, 16));
        tmaxB = fmaxf(tmaxB, __shfl_xor(tmaxB, 16));
        tmaxA = fmaxf(tmaxA, __shfl_xor(tmaxA, 32));
        tmaxB = fmaxf(tmaxB, __shfl_xor(tmaxB, 32));
        tmaxA *= SCALE2;
        tmaxB *= SCALE2;

        // defer-rescale (T13): skip O-rescale when max didn't grow much
        if (!__all(tmaxA - mrowA <= 10.f)) {
            float mnA = fmaxf(mrowA, tmaxA);
            float alphaA = __builtin_amdgcn_exp2f(mrowA - mnA);
            mrowA = mnA;
            lrowA *= alphaA;
#pragma unroll
            for (int ct = 0; ct < 4; ++ct)
#pragma unroll
                for (int r = 0; r < 4; ++r) oaccA[ct][r] *= alphaA;
        }
        if (!__all(tmaxB - mrowB <= 10.f)) {
            float mnB = fmaxf(mrowB, tmaxB);
            float alphaB = __builtin_amdgcn_exp2f(mrowB - mnB);
            mrowB = mnB;
            lrowB *= alphaB;
#pragma unroll
            for (int ct = 0; ct < 4; ++ct)
#pragma unroll
                for (int r = 0; r < 4; ++r) oaccB[ct][r] *= alphaB;
        }

        // P = exp2(s*SCALE2 - m); pack 4 at a time; vectorized b64 writes
        bf16* pl = &ptile[w][0];
        float lsA = 0.f, lsB = 0.f;
#pragma unroll
        for (int ct = 0; ct < 4; ++ct) {
            bf16x4 pkA, pkB;
#pragma unroll
            for (int r = 0; r < 4; ++r) {
                float eA = __builtin_amdgcn_exp2f(fmaf(sA[ct][r], SCALE2, -mrowA));
                float eB = __builtin_amdgcn_exp2f(fmaf(sB[ct][r], SCALE2, -mrowB));
                lsA += eA; lsB += eB;
                pkA[r] = (bf16)eA; pkB[r] = (bf16)eB;
            }
            *reinterpret_cast<bf16x4*>(pl + l15 * 72 + ct * 16 + quad * 4) = pkA;
            *reinterpret_cast<bf16x4*>(pl + (16 + l15) * 72 + ct * 16 + quad * 4) = pkB;
        }
        lrowA += lsA;
        lrowB += lsB;
        asm volatile("s_waitcnt lgkmcnt(0)" ::: "memory");
        __builtin_amdgcn_sched_barrier(0);

        // O^T += V^T P^T  (V fragments shared between tiles)
        const bf16* vb = &vbuf[cur][0];
#pragma unroll
        for (int ks = 0; ks < 2; ++ks) {
            bf16x8 bpA = ld8(pl + l15 * 72 + ks * 32 + quad * 8);
            bf16x8 bpB = ld8(pl + (16 + l15) * 72 + ks * 32 + quad * 8);
#pragma unroll
            for (int ct = 0; ct < 4; ++ct) {
                int d = ct * 16 + l15;
                bf16x8 av = ld8(vb + d * VST + (((ks * 4 + quad) ^ (d & 7)) * 8));
                oaccA[ct] = __builtin_amdgcn_mfma_f32_16x16x32_bf16(av, bpA, oaccA[ct], 0, 0, 0);
                oaccB[ct] = __builtin_amdgcn_mfma_f32_16x16x32_bf16(av, bpB, oaccB[ct], 0, 0, 0);
            }
        }

        if (kt < 15) {
            bf16* wb = &vbuf[cur ^ 1][0];
            *reinterpret_cast<bf16x8*>(wb + soff0) = sv0;
            *reinterpret_cast<bf16x8*>(wb + soff1) = sv1;
        }
        __syncthreads();
    }

    // final denominators
    lrowA += __shfl_xor(lrowA, 16);
    lrowB += __shfl_xor(lrowB, 16);
    lrowA += __shfl_xor(lrowA, 32);
    lrowB += __shfl_xor(lrowB, 32);
    float invA = 1.f / lrowA, invB = 1.f / lrowB;

    // O^T -> transpose via ptile stripes -> coalesced stores
    bf16* pl = &ptile[w][0];
#pragma unroll
    for (int ct = 0; ct < 4; ++ct) {
        bf16x4 okA, okB;
#pragma unroll
        for (int r = 0; r < 4; ++r) {
            okA[r] = (bf16)(oaccA[ct][r] * invA);
            okB[r] = (bf16)(oaccB[ct][r] * invB);
        }
        *reinterpret_cast<bf16x4*>(pl + l15 * 72 + ct * 16 + quad * 4) = okA;
        *reinterpret_cast<bf16x4*>(pl + (16 + l15) * 72 + ct * 16 + quad * 4) = okB;
    }
    asm volatile("s_waitcnt lgkmcnt(0)" ::: "memory");
    __builtin_amdgcn_sched_barrier(0);
    {
        bf16x8 o0 = ld8(pl + l15 * 72 + quad * 16);
        bf16x8 o1 = ld8(pl + l15 * 72 + quad * 16 + 8);
        bf16* dst = Otb + (long)(m0 + l15) * CC + h * DKK + quad * 16;
        *reinterpret_cast<bf16x8*>(dst) = o0;
        *reinterpret_cast<bf16x8*>(dst + 8) = o1;
        bf16x8 p0 = ld8(pl + (16 + l15) * 72 + quad * 16);
        bf16x8 p1 = ld8(pl + (16 + l15) * 72 + quad * 16 + 8);
        bf16* dstB = Otb + (long)(m0 + 16 + l15) * CC + h * DKK + quad * 16;
        *reinterpret_cast<bf16x8*>(dstB) = p0;
        *reinterpret_cast<bf16x8*>(dstB + 8) = p1;
    }
}

// ---------------------------------------------------------------------------
// proj: p[b,o,n] = Wproj . ot[b,n,:]^T, fp32 out; LDS-staged double-buffered
// GEMM. BN raw stats fused via shfl + atomics.
// ---------------------------------------------------------------------------
__global__ __launch_bounds__(256) void gemm_ntf(const bf16* __restrict__ A,
                                                const bf16* __restrict__ Bt,
                                                float* __restrict__ C,
                                                float* __restrict__ stats) {
    __shared__ __align__(16) bf16 sa[2][64][40];   // Wpb tile [ch][k]
    __shared__ __align__(16) bf16 sb[2][64][40];   // ot tile [px][k]
    const f32x4 fzero = {0.f, 0.f, 0.f, 0.f};
    int b = blockIdx.z;
    const bf16* Btb = Bt + (size_t)b * NN * CC;
    float* Cb = C + (size_t)b * CC * NN;
    int w = threadIdx.x >> 6, lane = threadIdx.x & 63;
    int quad = lane >> 4, l15 = lane & 15;
    long m0 = (long)blockIdx.x * 64 + w * 16;
    long n0 = (long)blockIdx.y * 64;

    int srow = threadIdx.x >> 2, sseg = threadIdx.x & 3;
    const bf16* apS = A + ((long)blockIdx.x * 64 + srow) * CC + sseg * 8;
    const bf16* bpS = Btb + (n0 + srow) * CC + sseg * 8;

    {
        bf16x8 a0 = ld8(apS);
        bf16x8 b0 = ld8(bpS);
        *reinterpret_cast<bf16x8*>(&sa[0][srow][sseg * 8]) = a0;
        *reinterpret_cast<bf16x8*>(&sb[0][srow][sseg * 8]) = b0;
    }
    __syncthreads();

    f32x4 acc[4];
#pragma unroll
    for (int ct = 0; ct < 4; ++ct) acc[ct] = fzero;

    for (int s = 0; s < 16; ++s) {
        int cur = s & 1;
        bf16x8 svA, svB;
        if (s < 15) {
            int k1 = (s + 1) * 32;
            svA = ld8(apS + k1);
            svB = ld8(bpS + k1);
        }
        bf16x8 a = ld8(&sa[cur][w * 16 + l15][quad * 8]);
#pragma unroll
        for (int ct = 0; ct < 4; ++ct) {
            bf16x8 bv = ld8(&sb[cur][ct * 16 + l15][quad * 8]);
            acc[ct] = __builtin_amdgcn_mfma_f32_16x16x32_bf16(a, bv, acc[ct], 0, 0, 0);
        }
        if (s < 15) {
            *reinterpret_cast<bf16x8*>(&sa[cur ^ 1][srow][sseg * 8]) = svA;
            *reinterpret_cast<bf16x8*>(&sb[cur ^ 1][srow][sseg * 8]) = svB;
        }
        __syncthreads();
    }

    float ps[4], pss[4];
#pragma unroll
    for (int r = 0; r < 4; ++r) { ps[r] = 0.f; pss[r] = 0.f; }
#pragma unroll
    for (int ct = 0; ct < 4; ++ct)
#pragma unroll
        for (int r = 0; r < 4; ++r) {
            float v = acc[ct][r];
            Cb[(m0 + quad * 4 + r) * NN + n0 + ct * 16 + l15] = v;
            ps[r] += v; pss[r] += v * v;
        }
#pragma unroll
    for (int off = 1; off < 16; off <<= 1)
#pragma unroll
        for (int r = 0; r < 4; ++r) {
            ps[r] += __shfl_xor(ps[r], off);
            pss[r] += __shfl_xor(pss[r], off);
        }
    if (l15 == 0) {
#pragma unroll
        for (int r = 0; r < 4; ++r) {
            int c = (int)(m0 + quad * 4 + r);
            atomicAdd(&stats[c * 2], ps[r]);
            atomicAdd(&stats[c * 2 + 1], pss[r]);
        }
    }
}

// ---------------------------------------------------------------------------
// y = x + bn(p); LayerNorm over C per pixel; BN scale/shift derived from raw
// stats in a small LDS preamble. fp32 in-place on d_out.
// ---------------------------------------------------------------------------
__global__ __launch_bounds__(256) void final_kernel(const float* __restrict__ x,
                                                    const float* __restrict__ p,
                                                    const float* __restrict__ stats,
                                                    const float* __restrict__ bng,
                                                    const float* __restrict__ bnb,
                                                    const float* __restrict__ lg,
                                                    const float* __restrict__ lb,
                                                    float* __restrict__ out) {
    __shared__ float scs[512], shs[512];
    for (int c = threadIdx.x; c < 512; c += 256) {
        float sum = stats[c * 2], ssq = stats[c * 2 + 1];
        float mean = sum * (1.f / 16384.f);
        float var = ssq * (1.f / 16384.f) - mean * mean;
        float rstd = rsqrtf(var + 1e-5f);
        float sc = bng[c] * rstd;
        scs[c] = sc;
        shs[c] = bnb[c] - mean * sc;
    }
    __syncthreads();
    int blk = blockIdx.x;
    int b = blk >> 6;
    int pix0 = (blk & 63) * 64;
    int sub = threadIdx.x >> 6, px = threadIdx.x & 63;
    float s = 0.f, ss = 0.f;
    for (int i = 0; i < 128; ++i) {
        int c = i * 4 + sub;
        long idx = ((long)(b * CC + c)) * NN + pix0 + px;
        float y = x[idx] + p[idx] * scs[c] + shs[c];
        s += y; ss += y * y;
    }
    __shared__ float rs[4][64], rss[4][64];
    rs[sub][px] = s; rss[sub][px] = ss;
    __syncthreads();
    float sum = rs[0][px] + rs[1][px] + rs[2][px] + rs[3][px];
    float sq  = rss[0][px] + rss[1][px] + rss[2][px] + rss[3][px];
    float mu = sum * (1.f / 512.f);
    float var = sq * (1.f / 512.f) - mu * mu;
    float rstd = rsqrtf(var + 1e-5f);
    for (int i = 0; i < 128; ++i) {
        int c = i * 4 + sub;
        long idx = ((long)(b * CC + c)) * NN + pix0 + px;
        float y = x[idx] + p[idx] * scs[c] + shs[c];
        out[idx] = (y - mu) * rstd * lg[c] + lb[c];
    }
}

// ---------------------------------------------------------------------------
extern "C" void kernel_launch(void* const* d_in, const int* in_sizes, int n_in,
                              void* d_out, int out_size, void* d_ws, size_t ws_size,
                              hipStream_t stream) {
    (void)in_sizes; (void)n_in; (void)out_size;
    const float* x     = (const float*)d_in[0];
    const float* Wq    = (const float*)d_in[1];
    const float* Wk    = (const float*)d_in[2];
    const float* Wv    = (const float*)d_in[3];
    const float* bias  = (const float*)d_in[4];
    const float* Wproj = (const float*)d_in[5];
    const float* bng   = (const float*)d_in[6];
    const float* bnb   = (const float*)d_in[7];
    const float* lng   = (const float*)d_in[8];
    const float* lnb   = (const float*)d_in[9];
    float* out = (float*)d_out;   // fp32 output (verified R9)

    char* ws = (char*)d_ws;
    size_t off = 0;
    auto alloc = [&](size_t bytes) {
        char* pp = ws + off;
        off += (bytes + 255) & ~(size_t)255;
        return pp;
    };
    bf16* Wqb = (bf16*)alloc((size_t)CC * CC * 2);          // 0.52 MB
    bf16* Wpb = (bf16*)alloc((size_t)CC * CC * 2);          // 0.52 MB
    float* stats = (float*)alloc(512 * 2 * sizeof(float));

    size_t needA = off + ((size_t)CC * 2048 * 2 * 2)        // Wkf+Wvf 4.2 MB
                 + ((size_t)BB * NN * CC * 2)               // xt_all 16.8
                 + ((size_t)BB * NRR * CC * 2 * 2)          // kt+vt   8.4
                 + ((size_t)BB * NN * CC * 2) + 4096;       // ot_all 16.8

    if (ws_size >= needA) {
        bf16* Wkf = (bf16*)alloc((size_t)CC * 2048 * 2);
        bf16* Wvf = (bf16*)alloc((size_t)CC * 2048 * 2);
        bf16* xt  = (bf16*)alloc((size_t)BB * NN * CC * 2);
        bf16* kt  = (bf16*)alloc((size_t)BB * NRR * CC * 2);
        bf16* vt  = (bf16*)alloc((size_t)BB * NRR * CC * 2);   // holds V^T [c][m]
        bf16* ot  = (bf16*)alloc((size_t)BB * NN * CC * 2);

        wcvt_kernel<<<1024, 256, 0, stream>>>(Wq, Wproj, Wqb, Wpb, stats);
        wperm_kernel<<<4096, 256, 0, stream>>>(Wk, Wv, Wkf, Wvf);
        transpose_kernel<<<dim3(64, 8, BB), 256, 0, stream>>>(x, xt);
        gemm_kv<<<dim3(16, 8, BB), 256, 0, stream>>>(xt, Wkf, Wvf, kt, vt);
        attn_kernel<<<dim3(32, NHH, BB), 256, 0, stream>>>(xt, Wqb, kt, vt, bias, ot);
        gemm_ntf<<<dim3(8, 64, BB), 256, 0, stream>>>(Wpb, ot, out, stats);
    } else {
        bf16* Wkf = (bf16*)(out + (size_t)3 * CC * NN);
        bf16* Wvf = Wkf + (size_t)CC * 2048;
        bf16* xt = (bf16*)alloc((size_t)NN * CC * 2);
        bf16* kt = (bf16*)alloc((size_t)NRR * CC * 2);
        bf16* vt = (bf16*)alloc((size_t)NRR * CC * 2);         // V^T [c][m]
        bf16* ot = (bf16*)alloc((size_t)NN * CC * 2);

        wcvt_kernel<<<1024, 256, 0, stream>>>(Wq, Wproj, Wqb, Wpb, stats);
        wperm_kernel<<<4096, 256, 0, stream>>>(Wk, Wv, Wkf, Wvf);
        for (int b = 0; b < BB; ++b) {
            const float* xb = x + (size_t)b * CC * NN;
            float* pb = out + (size_t)b * CC * NN;
            transpose_kernel<<<dim3(64, 8, 1), 256, 0, stream>>>(xb, xt);
            gemm_kv<<<dim3(16, 8, 1), 256, 0, stream>>>(xt, Wkf, Wvf, kt, vt);
            attn_kernel<<<dim3(32, NHH, 1), 256, 0, stream>>>(xt, Wqb, kt, vt, bias, ot);
            gemm_ntf<<<dim3(8, 64, 1), 256, 0, stream>>>(Wpb, ot, pb, stats);
        }
    }

    final_kernel<<<256, 256, 0, stream>>>(x, out, stats, bng, bnb, lng, lnb, out);
}

// Round 9
// 347.890 us; speedup vs baseline: 1.9580x; 1.0551x over previous
//
#include <hip/hip_runtime.h>
#include <hip/hip_bf16.h>
#include <cmath>

typedef __bf16 bf16;
typedef __bf16 bf16x4 __attribute__((ext_vector_type(4)));
typedef __bf16 bf16x8 __attribute__((ext_vector_type(8)));
typedef float f32x4 __attribute__((ext_vector_type(4)));

#define BB 4
#define CC 512
#define NN 4096      // 64*64 spatial
#define NRR 1024     // 32*32 spatial (stride-2)
#define NHH 8
#define DKK 64

static __device__ __forceinline__ bf16x8 ld8(const bf16* p) {
    return *reinterpret_cast<const bf16x8*>(p);
}

// ---------------------------------------------------------------------------
// weight convert / permute (fp32 -> bf16); also zeroes the BN stats buffer
// ---------------------------------------------------------------------------
__global__ __launch_bounds__(256) void wcvt_kernel(const float* __restrict__ Wq,
                                                   const float* __restrict__ Wp,
                                                   bf16* __restrict__ Wqb,
                                                   bf16* __restrict__ Wpb,
                                                   float* __restrict__ stats) {
    int e = blockIdx.x * 256 + threadIdx.x;   // 262144
    if (e < 1024) stats[e] = 0.f;
    Wqb[e] = (bf16)Wq[e];
    Wpb[e] = (bf16)Wp[e];
}

__global__ __launch_bounds__(256) void wperm_kernel(const float* __restrict__ Wk,
                                                    const float* __restrict__ Wv,
                                                    bf16* __restrict__ Wkf,
                                                    bf16* __restrict__ Wvf) {
    int e = blockIdx.x * 256 + threadIdx.x;   // 512*2048
    int o = e >> 11, q = (e >> 9) & 3, ci = e & 511;
    int src = o * 2048 + ci * 4 + q;
    Wkf[e] = (bf16)Wk[src];
    Wvf[e] = (bf16)Wv[src];
}

// ---------------------------------------------------------------------------
// x (b,C,N) fp32 -> xt (b,N,C) bf16; blockIdx.z = batch
// ---------------------------------------------------------------------------
__global__ __launch_bounds__(256) void transpose_kernel(const float* __restrict__ x,
                                                        bf16* __restrict__ xt) {
    __shared__ bf16 tile[64][65];
    int b = blockIdx.z;
    const float* xb = x + (size_t)b * CC * NN;
    bf16* xtb = xt + (size_t)b * NN * CC;
    int n0 = blockIdx.x * 64, c0 = blockIdx.y * 64;
    int tr = threadIdx.x >> 6, tc = threadIdx.x & 63;
#pragma unroll
    for (int i = 0; i < 64; i += 4)
        tile[tc][i + tr] = (bf16)xb[(long)(c0 + i + tr) * NN + n0 + tc];
    __syncthreads();
#pragma unroll
    for (int i = 0; i < 64; i += 4)
        xtb[(long)(n0 + i + tr) * CC + c0 + tc] = tile[i + tr][tc];
}

// ---------------------------------------------------------------------------
// Merged K+V GEMM, BK=64: 16 MFMA per barrier (was 8). LDS-staged weights
// double-buffered, pad-72 rows (bank = 4*(l15+quad)+kk/2 mod 32 -> 8/bank
// floor). im2col A fragments register-prefetched.
// ---------------------------------------------------------------------------
__global__ __launch_bounds__(256) void gemm_kv(const bf16* __restrict__ xt,
                                               const bf16* __restrict__ Wkf,
                                               const bf16* __restrict__ Wvf,
                                               bf16* __restrict__ kt,
                                               bf16* __restrict__ vt) {
    __shared__ __align__(16) bf16 smem[2][2][64][72];   // [dbuf][K/V][ch][k]
    const f32x4 fzero = {0.f, 0.f, 0.f, 0.f};
    int b = blockIdx.z;
    const bf16* xtb = xt + (size_t)b * NN * CC;
    int w = threadIdx.x >> 6, lane = threadIdx.x & 63;
    int quad = lane >> 4, l15 = lane & 15;
    int m0 = blockIdx.x * 64 + w * 16;
    int n0 = blockIdx.y * 64;

    int m = m0 + l15;
    int i2 = m >> 5, j2 = m & 31;
    int nrow[4];
#pragma unroll
    for (int q = 0; q < 4; ++q)
        nrow[q] = (2 * i2 + (q >> 1)) * 64 + 2 * j2 + (q & 1);

    int srow = threadIdx.x >> 2, sseg = threadIdx.x & 3;
    const bf16* wkp = Wkf + (long)(n0 + srow) * 2048 + sseg * 8;
    const bf16* wvp = Wvf + (long)(n0 + srow) * 2048 + sseg * 8;

    {
        *reinterpret_cast<bf16x8*>(&smem[0][0][srow][sseg * 8]) = ld8(wkp);
        *reinterpret_cast<bf16x8*>(&smem[0][0][srow][32 + sseg * 8]) = ld8(wkp + 32);
        *reinterpret_cast<bf16x8*>(&smem[0][1][srow][sseg * 8]) = ld8(wvp);
        *reinterpret_cast<bf16x8*>(&smem[0][1][srow][32 + sseg * 8]) = ld8(wvp + 32);
    }
    bf16x8 areg0 = ld8(xtb + (long)nrow[0] * CC + quad * 8);
    bf16x8 areg1 = ld8(xtb + (long)nrow[0] * CC + 32 + quad * 8);
    __syncthreads();

    f32x4 accK[4], accV[4];
#pragma unroll
    for (int ct = 0; ct < 4; ++ct) { accK[ct] = fzero; accV[ct] = fzero; }

    for (int s = 0; s < 32; ++s) {
        int cur = s & 1;
        bf16x8 svK0, svK1, svV0, svV1, aN0, aN1;
        if (s < 31) {
            int k1 = (s + 1) * 64;
            svK0 = ld8(wkp + k1);
            svK1 = ld8(wkp + k1 + 32);
            svV0 = ld8(wvp + k1);
            svV1 = ld8(wvp + k1 + 32);
            int q1 = k1 >> 9, ci1 = k1 & 511;
            aN0 = ld8(xtb + (long)nrow[q1] * CC + ci1 + quad * 8);
            aN1 = ld8(xtb + (long)nrow[q1] * CC + ci1 + 32 + quad * 8);
        }
#pragma unroll
        for (int ct = 0; ct < 4; ++ct) {
            bf16x8 bk0 = ld8(&smem[cur][0][ct * 16 + l15][quad * 8]);
            bf16x8 bv0 = ld8(&smem[cur][1][ct * 16 + l15][quad * 8]);
            accK[ct] = __builtin_amdgcn_mfma_f32_16x16x32_bf16(areg0, bk0, accK[ct], 0, 0, 0);
            accV[ct] = __builtin_amdgcn_mfma_f32_16x16x32_bf16(areg0, bv0, accV[ct], 0, 0, 0);
            bf16x8 bk1 = ld8(&smem[cur][0][ct * 16 + l15][32 + quad * 8]);
            bf16x8 bv1 = ld8(&smem[cur][1][ct * 16 + l15][32 + quad * 8]);
            accK[ct] = __builtin_amdgcn_mfma_f32_16x16x32_bf16(areg1, bk1, accK[ct], 0, 0, 0);
            accV[ct] = __builtin_amdgcn_mfma_f32_16x16x32_bf16(areg1, bv1, accV[ct], 0, 0, 0);
        }
        if (s < 31) {
            areg0 = aN0; areg1 = aN1;
            *reinterpret_cast<bf16x8*>(&smem[cur ^ 1][0][srow][sseg * 8]) = svK0;
            *reinterpret_cast<bf16x8*>(&smem[cur ^ 1][0][srow][32 + sseg * 8]) = svK1;
            *reinterpret_cast<bf16x8*>(&smem[cur ^ 1][1][srow][sseg * 8]) = svV0;
            *reinterpret_cast<bf16x8*>(&smem[cur ^ 1][1][srow][32 + sseg * 8]) = svV1;
        }
        __syncthreads();
    }

    bf16* Ck = kt + (size_t)b * NRR * CC;
#pragma unroll
    for (int ct = 0; ct < 4; ++ct)
#pragma unroll
        for (int r = 0; r < 4; ++r)
            Ck[(long)(m0 + quad * 4 + r) * CC + n0 + ct * 16 + l15] = (bf16)accK[ct][r];

    bf16* tt = (bf16*)smem;   // viewed as [64][72]
#pragma unroll
    for (int ct = 0; ct < 4; ++ct)
#pragma unroll
        for (int r = 0; r < 4; ++r)
            tt[(ct * 16 + l15) * 72 + w * 16 + quad * 4 + r] = (bf16)accV[ct][r];
    __syncthreads();
    {
        int row = threadIdx.x >> 2, seg = threadIdx.x & 3;
        bf16x8 v0 = ld8(tt + row * 72 + seg * 16);
        bf16x8 v1 = ld8(tt + row * 72 + seg * 16 + 8);
        bf16* dst = vt + (size_t)b * CC * NRR + (long)(n0 + row) * NRR
                  + (long)blockIdx.x * 64 + seg * 16;
        *reinterpret_cast<bf16x8*>(dst) = v0;
        *reinterpret_cast<bf16x8*>(dst + 8) = v1;
    }
}

// ---------------------------------------------------------------------------
// flash attention, swapped-operand QK^T, two query tiles per wave (32 q).
// VST reverted to 64 (stride-64 XOR is at the b128 bank floor; 72 aliased).
// K fragments register-prefetched one tile ahead (issued after the P-fence,
// hidden under PV + barrier).
// ---------------------------------------------------------------------------
#define VST 64   // vbuf row stride (bf16 elements)
__global__ __launch_bounds__(256) void attn_kernel(const bf16* __restrict__ xt,
                                                   const bf16* __restrict__ Wqb,
                                                   const bf16* __restrict__ Kt,
                                                   const bf16* __restrict__ Vt,
                                                   const float* __restrict__ bias,
                                                   bf16* __restrict__ Ot) {
    __shared__ __align__(16) bf16 vbuf[2][64 * VST];    // [d][m] XOR-swizzled
    __shared__ __align__(16) bf16 ptile[4][32 * 72];    // per-wave 2 stripes
    const f32x4 fzero = {0.f, 0.f, 0.f, 0.f};
    const float SCALE2 = 0.125f * 1.44269504089f;       // into log2 domain
    (void)bias;                                         // softmax-invariant
    int b = blockIdx.z, h = blockIdx.y;
    const bf16* xtb = xt + (size_t)b * NN * CC;
    const bf16* Ktb = Kt + (size_t)b * NRR * CC;
    const bf16* Vtb = Vt + (size_t)b * CC * NRR;        // [c][m] layout
    bf16* Otb = Ot + (size_t)b * NN * CC;
    int w = threadIdx.x >> 6, lane = threadIdx.x & 63;
    int quad = lane >> 4, l15 = lane & 15;
    int m0 = blockIdx.x * 128 + w * 32;                 // tile A: m0, tile B: m0+16

    // staging geometry: thread covers (d0, chunk) and (d0+32, chunk)
    int sd0 = threadIdx.x >> 3, schunk = threadIdx.x & 7;
    const bf16* vsrc0 = Vtb + (long)(h * DKK + sd0) * NRR + schunk * 8;
    const bf16* vsrc1 = vsrc0 + (long)32 * NRR;
    int soff0 = sd0 * VST + ((schunk ^ (sd0 & 7)) * 8);
    int soff1 = (sd0 + 32) * VST + ((schunk ^ (sd0 & 7)) * 8);

    // fused Q-GEMM for both tiles
    f32x4 qaccA[4], qaccB[4];
#pragma unroll
    for (int ct = 0; ct < 4; ++ct) { qaccA[ct] = fzero; qaccB[ct] = fzero; }
    {
        const bf16* axpA = xtb + (long)(m0 + l15) * CC + quad * 8;
        const bf16* axpB = axpA + 16 * CC;
        const bf16* bwp = Wqb + (long)(h * DKK + l15) * CC + quad * 8;
#pragma unroll 2
        for (int k0 = 0; k0 < 512; k0 += 32) {
            bf16x8 aA = ld8(axpA + k0);
            bf16x8 aB = ld8(axpB + k0);
#pragma unroll
            for (int ct = 0; ct < 4; ++ct) {
                bf16x8 bv = ld8(bwp + k0 + ct * 16 * CC);
                qaccA[ct] = __builtin_amdgcn_mfma_f32_16x16x32_bf16(aA, bv, qaccA[ct], 0, 0, 0);
                qaccB[ct] = __builtin_amdgcn_mfma_f32_16x16x32_bf16(aB, bv, qaccB[ct], 0, 0, 0);
            }
        }
    }
    bf16* ql = &ptile[w][0];
#pragma unroll
    for (int ct = 0; ct < 4; ++ct)
#pragma unroll
        for (int r = 0; r < 4; ++r) {
            ql[(quad * 4 + r) * 72 + ct * 16 + l15] = (bf16)qaccA[ct][r];
            ql[(16 + quad * 4 + r) * 72 + ct * 16 + l15] = (bf16)qaccB[ct][r];
        }
    asm volatile("s_waitcnt lgkmcnt(0)" ::: "memory");
    __builtin_amdgcn_sched_barrier(0);
    bf16x8 aq0A = ld8(ql + l15 * 72 + quad * 8);
    bf16x8 aq1A = ld8(ql + l15 * 72 + 32 + quad * 8);
    bf16x8 aq0B = ld8(ql + (16 + l15) * 72 + quad * 8);
    bf16x8 aq1B = ld8(ql + (16 + l15) * 72 + 32 + quad * 8);

    // prologue: stage V tile 0; preload K fragments for tile 0
    {
        bf16x8 s0 = ld8(vsrc0);
        bf16x8 s1 = ld8(vsrc1);
        *reinterpret_cast<bf16x8*>(&vbuf[0][0] + soff0) = s0;
        *reinterpret_cast<bf16x8*>(&vbuf[0][0] + soff1) = s1;
    }
    const bf16* kbase = Ktb + (long)l15 * CC + h * DKK + quad * 8;
    bf16x8 kf0[4], kf1[4];
#pragma unroll
    for (int ct = 0; ct < 4; ++ct) {
        kf0[ct] = ld8(kbase + (long)ct * 16 * CC);
        kf1[ct] = ld8(kbase + (long)ct * 16 * CC + 32);
    }
    __syncthreads();

    f32x4 oaccA[4], oaccB[4];
    float mrowA = -1e30f, lrowA = 0.f, mrowB = -1e30f, lrowB = 0.f;
#pragma unroll
    for (int ct = 0; ct < 4; ++ct) { oaccA[ct] = fzero; oaccB[ct] = fzero; }

    for (int kt = 0; kt < 16; ++kt) {
        int cur = kt & 1;
        bf16x8 sv0, sv1;
        if (kt < 15) {
            sv0 = ld8(vsrc0 + (kt + 1) * 64);
            sv1 = ld8(vsrc1 + (kt + 1) * 64);
        }

        // S^T = K Q^T for both tiles (K fragments already in registers)
        f32x4 sA[4], sB[4];
#pragma unroll
        for (int ct = 0; ct < 4; ++ct) { sA[ct] = fzero; sB[ct] = fzero; }
#pragma unroll
        for (int ct = 0; ct < 4; ++ct) {
            sA[ct] = __builtin_amdgcn_mfma_f32_16x16x32_bf16(kf0[ct], aq0A, sA[ct], 0, 0, 0);
            sA[ct] = __builtin_amdgcn_mfma_f32_16x16x32_bf16(kf1[ct], aq1A, sA[ct], 0, 0, 0);
            sB[ct] = __builtin_amdgcn_mfma_f32_16x16x32_bf16(kf0[ct], aq0B, sB[ct], 0, 0, 0);
            sB[ct] = __builtin_amdgcn_mfma_f32_16x16x32_bf16(kf1[ct], aq1B, sB[ct], 0, 0, 0);
        }

        // max tree on RAW s, scale once after reduce (log2 domain)
        float tA0 = fmaxf(fmaxf(sA[0][0], sA[0][1]), fmaxf(sA[0][2], sA[0][3]));
        float tA1 = fmaxf(fmaxf(sA[1][0], sA[1][1]), fmaxf(sA[1][2], sA[1][3]));
        float tA2 = fmaxf(fmaxf(sA[2][0], sA[2][1]), fmaxf(sA[2][2], sA[2][3]));
        float tA3 = fmaxf(fmaxf(sA[3][0], sA[3][1]), fmaxf(sA[3][2], sA[3][3]));
        float tB0 = fmaxf(fmaxf(sB[0][0], sB[0][1]), fmaxf(sB[0][2], sB[0][3]));
        float tB1 = fmaxf(fmaxf(sB[1][0], sB[1][1]), fmaxf(sB[1][2], sB[1][3]));
        float tB2 = fmaxf(fmaxf(sB[2][0], sB[2][1]), fmaxf(sB[2][2], sB[2][3]));
        float tB3 = fmaxf(fmaxf(sB[3][0], sB[3][1]), fmaxf(sB[3][2], sB[3][3]));
        float tmaxA = fmaxf(fmaxf(tA0, tA1), fmaxf(tA2, tA3));
        float tmaxB = fmaxf(fmaxf(tB0, tB1), fmaxf(tB2, tB3));
        tmaxA = fmaxf(tmaxA, __shfl_xor(tmaxA, 16));
        tmaxB = fmaxf(tmaxB, __shfl_xor(tmaxB, 16));
        tmaxA = fmaxf(tmaxA, __shfl_xor(tmaxA, 32));
        tmaxB = fmaxf(tmaxB, __shfl_xor(tmaxB, 32));
        tmaxA *= SCALE2;
        tmaxB *= SCALE2;

        // defer-rescale (T13)
        if (!__all(tmaxA - mrowA <= 10.f)) {
            float mnA = fmaxf(mrowA, tmaxA);
            float alphaA = __builtin_amdgcn_exp2f(mrowA - mnA);
            mrowA = mnA;
            lrowA *= alphaA;
#pragma unroll
            for (int ct = 0; ct < 4; ++ct)
#pragma unroll
                for (int r = 0; r < 4; ++r) oaccA[ct][r] *= alphaA;
        }
        if (!__all(tmaxB - mrowB <= 10.f)) {
            float mnB = fmaxf(mrowB, tmaxB);
            float alphaB = __builtin_amdgcn_exp2f(mrowB - mnB);
            mrowB = mnB;
            lrowB *= alphaB;
#pragma unroll
            for (int ct = 0; ct < 4; ++ct)
#pragma unroll
                for (int r = 0; r < 4; ++r) oaccB[ct][r] *= alphaB;
        }

        // P = exp2(s*SCALE2 - m); packed b64 writes
        bf16* pl = &ptile[w][0];
        float lsA = 0.f, lsB = 0.f;
#pragma unroll
        for (int ct = 0; ct < 4; ++ct) {
            bf16x4 pkA, pkB;
#pragma unroll
            for (int r = 0; r < 4; ++r) {
                float eA = __builtin_amdgcn_exp2f(fmaf(sA[ct][r], SCALE2, -mrowA));
                float eB = __builtin_amdgcn_exp2f(fmaf(sB[ct][r], SCALE2, -mrowB));
                lsA += eA; lsB += eB;
                pkA[r] = (bf16)eA; pkB[r] = (bf16)eB;
            }
            *reinterpret_cast<bf16x4*>(pl + l15 * 72 + ct * 16 + quad * 4) = pkA;
            *reinterpret_cast<bf16x4*>(pl + (16 + l15) * 72 + ct * 16 + quad * 4) = pkB;
        }
        lrowA += lsA;
        lrowB += lsB;
        asm volatile("s_waitcnt lgkmcnt(0)" ::: "memory");
        __builtin_amdgcn_sched_barrier(0);

        // ---- issue next-tile K loads here (hidden under PV + barrier)
        bf16x8 nf0[4], nf1[4];
        if (kt < 15) {
            const bf16* kn = kbase + (long)(kt + 1) * 64 * CC;
#pragma unroll
            for (int ct = 0; ct < 4; ++ct) {
                nf0[ct] = ld8(kn + (long)ct * 16 * CC);
                nf1[ct] = ld8(kn + (long)ct * 16 * CC + 32);
            }
        }

        // O^T += V^T P^T  (V fragments shared between tiles)
        const bf16* vb = &vbuf[cur][0];
#pragma unroll
        for (int ks = 0; ks < 2; ++ks) {
            bf16x8 bpA = ld8(pl + l15 * 72 + ks * 32 + quad * 8);
            bf16x8 bpB = ld8(pl + (16 + l15) * 72 + ks * 32 + quad * 8);
#pragma unroll
            for (int ct = 0; ct < 4; ++ct) {
                int d = ct * 16 + l15;
                bf16x8 av = ld8(vb + d * VST + (((ks * 4 + quad) ^ (d & 7)) * 8));
                oaccA[ct] = __builtin_amdgcn_mfma_f32_16x16x32_bf16(av, bpA, oaccA[ct], 0, 0, 0);
                oaccB[ct] = __builtin_amdgcn_mfma_f32_16x16x32_bf16(av, bpB, oaccB[ct], 0, 0, 0);
            }
        }

        if (kt < 15) {
            bf16* wb = &vbuf[cur ^ 1][0];
            *reinterpret_cast<bf16x8*>(wb + soff0) = sv0;
            *reinterpret_cast<bf16x8*>(wb + soff1) = sv1;
#pragma unroll
            for (int ct = 0; ct < 4; ++ct) { kf0[ct] = nf0[ct]; kf1[ct] = nf1[ct]; }
        }
        __syncthreads();
    }

    // final denominators
    lrowA += __shfl_xor(lrowA, 16);
    lrowB += __shfl_xor(lrowB, 16);
    lrowA += __shfl_xor(lrowA, 32);
    lrowB += __shfl_xor(lrowB, 32);
    float invA = 1.f / lrowA, invB = 1.f / lrowB;

    // O^T -> transpose via ptile stripes -> coalesced stores
    bf16* pl = &ptile[w][0];
#pragma unroll
    for (int ct = 0; ct < 4; ++ct) {
        bf16x4 okA, okB;
#pragma unroll
        for (int r = 0; r < 4; ++r) {
            okA[r] = (bf16)(oaccA[ct][r] * invA);
            okB[r] = (bf16)(oaccB[ct][r] * invB);
        }
        *reinterpret_cast<bf16x4*>(pl + l15 * 72 + ct * 16 + quad * 4) = okA;
        *reinterpret_cast<bf16x4*>(pl + (16 + l15) * 72 + ct * 16 + quad * 4) = okB;
    }
    asm volatile("s_waitcnt lgkmcnt(0)" ::: "memory");
    __builtin_amdgcn_sched_barrier(0);
    {
        bf16x8 o0 = ld8(pl + l15 * 72 + quad * 16);
        bf16x8 o1 = ld8(pl + l15 * 72 + quad * 16 + 8);
        bf16* dst = Otb + (long)(m0 + l15) * CC + h * DKK + quad * 16;
        *reinterpret_cast<bf16x8*>(dst) = o0;
        *reinterpret_cast<bf16x8*>(dst + 8) = o1;
        bf16x8 p0 = ld8(pl + (16 + l15) * 72 + quad * 16);
        bf16x8 p1 = ld8(pl + (16 + l15) * 72 + quad * 16 + 8);
        bf16* dstB = Otb + (long)(m0 + 16 + l15) * CC + h * DKK + quad * 16;
        *reinterpret_cast<bf16x8*>(dstB) = p0;
        *reinterpret_cast<bf16x8*>(dstB + 8) = p1;
    }
}

// ---------------------------------------------------------------------------
// proj: p[b,o,n] = Wproj . ot[b,n,:]^T, fp32 out; LDS-staged double-buffered
// GEMM, BK=64 (8 MFMA per barrier). BN raw stats fused via shfl + atomics.
// ---------------------------------------------------------------------------
__global__ __launch_bounds__(256) void gemm_ntf(const bf16* __restrict__ A,
                                                const bf16* __restrict__ Bt,
                                                float* __restrict__ C,
                                                float* __restrict__ stats) {
    __shared__ __align__(16) bf16 sa[2][64][72];   // Wpb tile [ch][k]
    __shared__ __align__(16) bf16 sb[2][64][72];   // ot tile [px][k]
    const f32x4 fzero = {0.f, 0.f, 0.f, 0.f};
    int b = blockIdx.z;
    const bf16* Btb = Bt + (size_t)b * NN * CC;
    float* Cb = C + (size_t)b * CC * NN;
    int w = threadIdx.x >> 6, lane = threadIdx.x & 63;
    int quad = lane >> 4, l15 = lane & 15;
    long m0 = (long)blockIdx.x * 64 + w * 16;
    long n0 = (long)blockIdx.y * 64;

    int srow = threadIdx.x >> 2, sseg = threadIdx.x & 3;
    const bf16* apS = A + ((long)blockIdx.x * 64 + srow) * CC + sseg * 8;
    const bf16* bpS = Btb + (n0 + srow) * CC + sseg * 8;

    {
        *reinterpret_cast<bf16x8*>(&sa[0][srow][sseg * 8]) = ld8(apS);
        *reinterpret_cast<bf16x8*>(&sa[0][srow][32 + sseg * 8]) = ld8(apS + 32);
        *reinterpret_cast<bf16x8*>(&sb[0][srow][sseg * 8]) = ld8(bpS);
        *reinterpret_cast<bf16x8*>(&sb[0][srow][32 + sseg * 8]) = ld8(bpS + 32);
    }
    __syncthreads();

    f32x4 acc[4];
#pragma unroll
    for (int ct = 0; ct < 4; ++ct) acc[ct] = fzero;

    for (int s = 0; s < 8; ++s) {
        int cur = s & 1;
        bf16x8 svA0, svA1, svB0, svB1;
        if (s < 7) {
            int k1 = (s + 1) * 64;
            svA0 = ld8(apS + k1);
            svA1 = ld8(apS + k1 + 32);
            svB0 = ld8(bpS + k1);
            svB1 = ld8(bpS + k1 + 32);
        }
        bf16x8 a0 = ld8(&sa[cur][w * 16 + l15][quad * 8]);
        bf16x8 a1 = ld8(&sa[cur][w * 16 + l15][32 + quad * 8]);
#pragma unroll
        for (int ct = 0; ct < 4; ++ct) {
            bf16x8 b0 = ld8(&sb[cur][ct * 16 + l15][quad * 8]);
            acc[ct] = __builtin_amdgcn_mfma_f32_16x16x32_bf16(a0, b0, acc[ct], 0, 0, 0);
            bf16x8 b1 = ld8(&sb[cur][ct * 16 + l15][32 + quad * 8]);
            acc[ct] = __builtin_amdgcn_mfma_f32_16x16x32_bf16(a1, b1, acc[ct], 0, 0, 0);
        }
        if (s < 7) {
            *reinterpret_cast<bf16x8*>(&sa[cur ^ 1][srow][sseg * 8]) = svA0;
            *reinterpret_cast<bf16x8*>(&sa[cur ^ 1][srow][32 + sseg * 8]) = svA1;
            *reinterpret_cast<bf16x8*>(&sb[cur ^ 1][srow][sseg * 8]) = svB0;
            *reinterpret_cast<bf16x8*>(&sb[cur ^ 1][srow][32 + sseg * 8]) = svB1;
        }
        __syncthreads();
    }

    float ps[4], pss[4];
#pragma unroll
    for (int r = 0; r < 4; ++r) { ps[r] = 0.f; pss[r] = 0.f; }
#pragma unroll
    for (int ct = 0; ct < 4; ++ct)
#pragma unroll
        for (int r = 0; r < 4; ++r) {
            float v = acc[ct][r];
            Cb[(m0 + quad * 4 + r) * NN + n0 + ct * 16 + l15] = v;
            ps[r] += v; pss[r] += v * v;
        }
#pragma unroll
    for (int off = 1; off < 16; off <<= 1)
#pragma unroll
        for (int r = 0; r < 4; ++r) {
            ps[r] += __shfl_xor(ps[r], off);
            pss[r] += __shfl_xor(pss[r], off);
        }
    if (l15 == 0) {
#pragma unroll
        for (int r = 0; r < 4; ++r) {
            int c = (int)(m0 + quad * 4 + r);
            atomicAdd(&stats[c * 2], ps[r]);
            atomicAdd(&stats[c * 2 + 1], pss[r]);
        }
    }
}

// ---------------------------------------------------------------------------
// y = x + bn(p); LayerNorm over C per pixel; BN scale/shift derived from raw
// stats in a small LDS preamble. fp32 in-place on d_out.
// ---------------------------------------------------------------------------
__global__ __launch_bounds__(256) void final_kernel(const float* __restrict__ x,
                                                    const float* __restrict__ p,
                                                    const float* __restrict__ stats,
                                                    const float* __restrict__ bng,
                                                    const float* __restrict__ bnb,
                                                    const float* __restrict__ lg,
                                                    const float* __restrict__ lb,
                                                    float* __restrict__ out) {
    __shared__ float scs[512], shs[512];
    for (int c = threadIdx.x; c < 512; c += 256) {
        float sum = stats[c * 2], ssq = stats[c * 2 + 1];
        float mean = sum * (1.f / 16384.f);
        float var = ssq * (1.f / 16384.f) - mean * mean;
        float rstd = rsqrtf(var + 1e-5f);
        float sc = bng[c] * rstd;
        scs[c] = sc;
        shs[c] = bnb[c] - mean * sc;
    }
    __syncthreads();
    int blk = blockIdx.x;
    int b = blk >> 6;
    int pix0 = (blk & 63) * 64;
    int sub = threadIdx.x >> 6, px = threadIdx.x & 63;
    float s = 0.f, ss = 0.f;
    for (int i = 0; i < 128; ++i) {
        int c = i * 4 + sub;
        long idx = ((long)(b * CC + c)) * NN + pix0 + px;
        float y = x[idx] + p[idx] * scs[c] + shs[c];
        s += y; ss += y * y;
    }
    __shared__ float rs[4][64], rss[4][64];
    rs[sub][px] = s; rss[sub][px] = ss;
    __syncthreads();
    float sum = rs[0][px] + rs[1][px] + rs[2][px] + rs[3][px];
    float sq  = rss[0][px] + rss[1][px] + rss[2][px] + rss[3][px];
    float mu = sum * (1.f / 512.f);
    float var = sq * (1.f / 512.f) - mu * mu;
    float rstd = rsqrtf(var + 1e-5f);
    for (int i = 0; i < 128; ++i) {
        int c = i * 4 + sub;
        long idx = ((long)(b * CC + c)) * NN + pix0 + px;
        float y = x[idx] + p[idx] * scs[c] + shs[c];
        out[idx] = (y - mu) * rstd * lg[c] + lb[c];
    }
}

// ---------------------------------------------------------------------------
extern "C" void kernel_launch(void* const* d_in, const int* in_sizes, int n_in,
                              void* d_out, int out_size, void* d_ws, size_t ws_size,
                              hipStream_t stream) {
    (void)in_sizes; (void)n_in; (void)out_size;
    const float* x     = (const float*)d_in[0];
    const float* Wq    = (const float*)d_in[1];
    const float* Wk    = (const float*)d_in[2];
    const float* Wv    = (const float*)d_in[3];
    const float* bias  = (const float*)d_in[4];
    const float* Wproj = (const float*)d_in[5];
    const float* bng   = (const float*)d_in[6];
    const float* bnb   = (const float*)d_in[7];
    const float* lng   = (const float*)d_in[8];
    const float* lnb   = (const float*)d_in[9];
    float* out = (float*)d_out;   // fp32 output (verified R9)

    char* ws = (char*)d_ws;
    size_t off = 0;
    auto alloc = [&](size_t bytes) {
        char* pp = ws + off;
        off += (bytes + 255) & ~(size_t)255;
        return pp;
    };
    bf16* Wqb = (bf16*)alloc((size_t)CC * CC * 2);          // 0.52 MB
    bf16* Wpb = (bf16*)alloc((size_t)CC * CC * 2);          // 0.52 MB
    float* stats = (float*)alloc(512 * 2 * sizeof(float));

    size_t needA = off + ((size_t)CC * 2048 * 2 * 2)        // Wkf+Wvf 4.2 MB
                 + ((size_t)BB * NN * CC * 2)               // xt_all 16.8
                 + ((size_t)BB * NRR * CC * 2 * 2)          // kt+vt   8.4
                 + ((size_t)BB * NN * CC * 2) + 4096;       // ot_all 16.8

    if (ws_size >= needA) {
        bf16* Wkf = (bf16*)alloc((size_t)CC * 2048 * 2);
        bf16* Wvf = (bf16*)alloc((size_t)CC * 2048 * 2);
        bf16* xt  = (bf16*)alloc((size_t)BB * NN * CC * 2);
        bf16* kt  = (bf16*)alloc((size_t)BB * NRR * CC * 2);
        bf16* vt  = (bf16*)alloc((size_t)BB * NRR * CC * 2);   // holds V^T [c][m]
        bf16* ot  = (bf16*)alloc((size_t)BB * NN * CC * 2);

        wcvt_kernel<<<1024, 256, 0, stream>>>(Wq, Wproj, Wqb, Wpb, stats);
        wperm_kernel<<<4096, 256, 0, stream>>>(Wk, Wv, Wkf, Wvf);
        transpose_kernel<<<dim3(64, 8, BB), 256, 0, stream>>>(x, xt);
        gemm_kv<<<dim3(16, 8, BB), 256, 0, stream>>>(xt, Wkf, Wvf, kt, vt);
        attn_kernel<<<dim3(32, NHH, BB), 256, 0, stream>>>(xt, Wqb, kt, vt, bias, ot);
        gemm_ntf<<<dim3(8, 64, BB), 256, 0, stream>>>(Wpb, ot, out, stats);
    } else {
        bf16* Wkf = (bf16*)(out + (size_t)3 * CC * NN);
        bf16* Wvf = Wkf + (size_t)CC * 2048;
        bf16* xt = (bf16*)alloc((size_t)NN * CC * 2);
        bf16* kt = (bf16*)alloc((size_t)NRR * CC * 2);
        bf16* vt = (bf16*)alloc((size_t)NRR * CC * 2);         // V^T [c][m]
        bf16* ot = (bf16*)alloc((size_t)NN * CC * 2);

        wcvt_kernel<<<1024, 256, 0, stream>>>(Wq, Wproj, Wqb, Wpb, stats);
        wperm_kernel<<<4096, 256, 0, stream>>>(Wk, Wv, Wkf, Wvf);
        for (int b = 0; b < BB; ++b) {
            const float* xb = x + (size_t)b * CC * NN;
            float* pb = out + (size_t)b * CC * NN;
            transpose_kernel<<<dim3(64, 8, 1), 256, 0, stream>>>(xb, xt);
            gemm_kv<<<dim3(16, 8, 1), 256, 0, stream>>>(xt, Wkf, Wvf, kt, vt);
            attn_kernel<<<dim3(32, NHH, 1), 256, 0, stream>>>(xt, Wqb, kt, vt, bias, ot);
            gemm_ntf<<<dim3(8, 64, 1), 256, 0, stream>>>(Wpb, ot, pb, stats);
        }
    }

    final_kernel<<<256, 256, 0, stream>>>(x, out, stats, bng, bnb, lng, lnb, out);
}

// Round 10
// 344.996 us; speedup vs baseline: 1.9744x; 1.0084x over previous
//
#include <hip/hip_runtime.h>
#include <hip/hip_bf16.h>
#include <cmath>

typedef __bf16 bf16;
typedef __bf16 bf16x4 __attribute__((ext_vector_type(4)));
typedef __bf16 bf16x8 __attribute__((ext_vector_type(8)));
typedef float f32x4 __attribute__((ext_vector_type(4)));

#define BB 4
#define CC 512
#define NN 4096      // 64*64 spatial
#define NRR 1024     // 32*32 spatial (stride-2)
#define NHH 8
#define DKK 64

static __device__ __forceinline__ bf16x8 ld8(const bf16* p) {
    return *reinterpret_cast<const bf16x8*>(p);
}

// ptile swizzled index: element (row, col) of a 32x64 stripe.
// chunk-XOR keeps b64 writes at the 4/bank floor and ld8 reads 2-way.
static __device__ __forceinline__ int swz(int row, int col) {
    return row * 64 + ((((col >> 3) ^ (row & 7)) << 3) | (col & 7));
}

// ---------------------------------------------------------------------------
// weight convert / permute (fp32 -> bf16); also zeroes the BN stats buffer.
// Wq is pre-scaled by 0.125*log2(e) so QK^T lands directly in exp2 domain.
// ---------------------------------------------------------------------------
__global__ __launch_bounds__(256) void wcvt_kernel(const float* __restrict__ Wq,
                                                   const float* __restrict__ Wp,
                                                   bf16* __restrict__ Wqb,
                                                   bf16* __restrict__ Wpb,
                                                   float* __restrict__ stats) {
    int e = blockIdx.x * 256 + threadIdx.x;   // 262144
    if (e < 1024) stats[e] = 0.f;
    Wqb[e] = (bf16)(Wq[e] * 0.18033688011f);  // 0.125 * log2(e)
    Wpb[e] = (bf16)Wp[e];
}

__global__ __launch_bounds__(256) void wperm_kernel(const float* __restrict__ Wk,
                                                    const float* __restrict__ Wv,
                                                    bf16* __restrict__ Wkf,
                                                    bf16* __restrict__ Wvf) {
    int e = blockIdx.x * 256 + threadIdx.x;   // 512*2048
    int o = e >> 11, q = (e >> 9) & 3, ci = e & 511;
    int src = o * 2048 + ci * 4 + q;
    Wkf[e] = (bf16)Wk[src];
    Wvf[e] = (bf16)Wv[src];
}

// ---------------------------------------------------------------------------
// x (b,C,N) fp32 -> xt (b,N,C) bf16; blockIdx.z = batch
// ---------------------------------------------------------------------------
__global__ __launch_bounds__(256) void transpose_kernel(const float* __restrict__ x,
                                                        bf16* __restrict__ xt) {
    __shared__ bf16 tile[64][65];
    int b = blockIdx.z;
    const float* xb = x + (size_t)b * CC * NN;
    bf16* xtb = xt + (size_t)b * NN * CC;
    int n0 = blockIdx.x * 64, c0 = blockIdx.y * 64;
    int tr = threadIdx.x >> 6, tc = threadIdx.x & 63;
#pragma unroll
    for (int i = 0; i < 64; i += 4)
        tile[tc][i + tr] = (bf16)xb[(long)(c0 + i + tr) * NN + n0 + tc];
    __syncthreads();
#pragma unroll
    for (int i = 0; i < 64; i += 4)
        xtb[(long)(n0 + i + tr) * CC + c0 + tc] = tile[i + tr][tc];
}

// ---------------------------------------------------------------------------
// Merged K+V GEMM, BK=64: 16 MFMA per barrier. LDS-staged weights
// double-buffered, pad-72 rows. im2col A fragments register-prefetched.
// ---------------------------------------------------------------------------
__global__ __launch_bounds__(256) void gemm_kv(const bf16* __restrict__ xt,
                                               const bf16* __restrict__ Wkf,
                                               const bf16* __restrict__ Wvf,
                                               bf16* __restrict__ kt,
                                               bf16* __restrict__ vt) {
    __shared__ __align__(16) bf16 smem[2][2][64][72];   // [dbuf][K/V][ch][k]
    const f32x4 fzero = {0.f, 0.f, 0.f, 0.f};
    int b = blockIdx.z;
    const bf16* xtb = xt + (size_t)b * NN * CC;
    int w = threadIdx.x >> 6, lane = threadIdx.x & 63;
    int quad = lane >> 4, l15 = lane & 15;
    int m0 = blockIdx.x * 64 + w * 16;
    int n0 = blockIdx.y * 64;

    int m = m0 + l15;
    int i2 = m >> 5, j2 = m & 31;
    int nrow[4];
#pragma unroll
    for (int q = 0; q < 4; ++q)
        nrow[q] = (2 * i2 + (q >> 1)) * 64 + 2 * j2 + (q & 1);

    int srow = threadIdx.x >> 2, sseg = threadIdx.x & 3;
    const bf16* wkp = Wkf + (long)(n0 + srow) * 2048 + sseg * 8;
    const bf16* wvp = Wvf + (long)(n0 + srow) * 2048 + sseg * 8;

    {
        *reinterpret_cast<bf16x8*>(&smem[0][0][srow][sseg * 8]) = ld8(wkp);
        *reinterpret_cast<bf16x8*>(&smem[0][0][srow][32 + sseg * 8]) = ld8(wkp + 32);
        *reinterpret_cast<bf16x8*>(&smem[0][1][srow][sseg * 8]) = ld8(wvp);
        *reinterpret_cast<bf16x8*>(&smem[0][1][srow][32 + sseg * 8]) = ld8(wvp + 32);
    }
    bf16x8 areg0 = ld8(xtb + (long)nrow[0] * CC + quad * 8);
    bf16x8 areg1 = ld8(xtb + (long)nrow[0] * CC + 32 + quad * 8);
    __syncthreads();

    f32x4 accK[4], accV[4];
#pragma unroll
    for (int ct = 0; ct < 4; ++ct) { accK[ct] = fzero; accV[ct] = fzero; }

    for (int s = 0; s < 32; ++s) {
        int cur = s & 1;
        bf16x8 svK0, svK1, svV0, svV1, aN0, aN1;
        if (s < 31) {
            int k1 = (s + 1) * 64;
            svK0 = ld8(wkp + k1);
            svK1 = ld8(wkp + k1 + 32);
            svV0 = ld8(wvp + k1);
            svV1 = ld8(wvp + k1 + 32);
            int q1 = k1 >> 9, ci1 = k1 & 511;
            aN0 = ld8(xtb + (long)nrow[q1] * CC + ci1 + quad * 8);
            aN1 = ld8(xtb + (long)nrow[q1] * CC + ci1 + 32 + quad * 8);
        }
#pragma unroll
        for (int ct = 0; ct < 4; ++ct) {
            bf16x8 bk0 = ld8(&smem[cur][0][ct * 16 + l15][quad * 8]);
            bf16x8 bv0 = ld8(&smem[cur][1][ct * 16 + l15][quad * 8]);
            accK[ct] = __builtin_amdgcn_mfma_f32_16x16x32_bf16(areg0, bk0, accK[ct], 0, 0, 0);
            accV[ct] = __builtin_amdgcn_mfma_f32_16x16x32_bf16(areg0, bv0, accV[ct], 0, 0, 0);
            bf16x8 bk1 = ld8(&smem[cur][0][ct * 16 + l15][32 + quad * 8]);
            bf16x8 bv1 = ld8(&smem[cur][1][ct * 16 + l15][32 + quad * 8]);
            accK[ct] = __builtin_amdgcn_mfma_f32_16x16x32_bf16(areg1, bk1, accK[ct], 0, 0, 0);
            accV[ct] = __builtin_amdgcn_mfma_f32_16x16x32_bf16(areg1, bv1, accV[ct], 0, 0, 0);
        }
        if (s < 31) {
            areg0 = aN0; areg1 = aN1;
            *reinterpret_cast<bf16x8*>(&smem[cur ^ 1][0][srow][sseg * 8]) = svK0;
            *reinterpret_cast<bf16x8*>(&smem[cur ^ 1][0][srow][32 + sseg * 8]) = svK1;
            *reinterpret_cast<bf16x8*>(&smem[cur ^ 1][1][srow][sseg * 8]) = svV0;
            *reinterpret_cast<bf16x8*>(&smem[cur ^ 1][1][srow][32 + sseg * 8]) = svV1;
        }
        __syncthreads();
    }

    bf16* Ck = kt + (size_t)b * NRR * CC;
#pragma unroll
    for (int ct = 0; ct < 4; ++ct)
#pragma unroll
        for (int r = 0; r < 4; ++r)
            Ck[(long)(m0 + quad * 4 + r) * CC + n0 + ct * 16 + l15] = (bf16)accK[ct][r];

    bf16* tt = (bf16*)smem;   // viewed as [64][72]
#pragma unroll
    for (int ct = 0; ct < 4; ++ct)
#pragma unroll
        for (int r = 0; r < 4; ++r)
            tt[(ct * 16 + l15) * 72 + w * 16 + quad * 4 + r] = (bf16)accV[ct][r];
    __syncthreads();
    {
        int row = threadIdx.x >> 2, seg = threadIdx.x & 3;
        bf16x8 v0 = ld8(tt + row * 72 + seg * 16);
        bf16x8 v1 = ld8(tt + row * 72 + seg * 16 + 8);
        bf16* dst = vt + (size_t)b * CC * NRR + (long)(n0 + row) * NRR
                  + (long)blockIdx.x * 64 + seg * 16;
        *reinterpret_cast<bf16x8*>(dst) = v0;
        *reinterpret_cast<bf16x8*>(dst + 8) = v1;
    }
}

// ---------------------------------------------------------------------------
// flash attention, swapped-operand QK^T, two query tiles per wave (32 q).
// ptile: XOR-swizzled stride-64 stripes -> LDS 32 KB total -> 5 blocks/CU.
// Q pre-scaled into exp2 domain (wcvt). K register-prefetched one tile ahead.
// ---------------------------------------------------------------------------
#define VST 64   // vbuf row stride (bf16 elements)
__global__ __launch_bounds__(256) void attn_kernel(const bf16* __restrict__ xt,
                                                   const bf16* __restrict__ Wqb,
                                                   const bf16* __restrict__ Kt,
                                                   const bf16* __restrict__ Vt,
                                                   const float* __restrict__ bias,
                                                   bf16* __restrict__ Ot) {
    __shared__ __align__(16) bf16 vbuf[2][64 * VST];    // [d][m] XOR-swizzled
    __shared__ __align__(16) bf16 ptile[4][32 * 64];    // per-wave swz stripes
    const f32x4 fzero = {0.f, 0.f, 0.f, 0.f};
    (void)bias;                                         // softmax-invariant
    int b = blockIdx.z, h = blockIdx.y;
    const bf16* xtb = xt + (size_t)b * NN * CC;
    const bf16* Ktb = Kt + (size_t)b * NRR * CC;
    const bf16* Vtb = Vt + (size_t)b * CC * NRR;        // [c][m] layout
    bf16* Otb = Ot + (size_t)b * NN * CC;
    int w = threadIdx.x >> 6, lane = threadIdx.x & 63;
    int quad = lane >> 4, l15 = lane & 15;
    int m0 = blockIdx.x * 128 + w * 32;                 // tile A: m0, tile B: m0+16

    // staging geometry: thread covers (d0, chunk) and (d0+32, chunk)
    int sd0 = threadIdx.x >> 3, schunk = threadIdx.x & 7;
    const bf16* vsrc0 = Vtb + (long)(h * DKK + sd0) * NRR + schunk * 8;
    const bf16* vsrc1 = vsrc0 + (long)32 * NRR;
    int soff0 = sd0 * VST + ((schunk ^ (sd0 & 7)) * 8);
    int soff1 = (sd0 + 32) * VST + ((schunk ^ (sd0 & 7)) * 8);

    // fused Q-GEMM for both tiles (Wq pre-scaled: output in exp2 domain)
    f32x4 qaccA[4], qaccB[4];
#pragma unroll
    for (int ct = 0; ct < 4; ++ct) { qaccA[ct] = fzero; qaccB[ct] = fzero; }
    {
        const bf16* axpA = xtb + (long)(m0 + l15) * CC + quad * 8;
        const bf16* axpB = axpA + 16 * CC;
        const bf16* bwp = Wqb + (long)(h * DKK + l15) * CC + quad * 8;
#pragma unroll 2
        for (int k0 = 0; k0 < 512; k0 += 32) {
            bf16x8 aA = ld8(axpA + k0);
            bf16x8 aB = ld8(axpB + k0);
#pragma unroll
            for (int ct = 0; ct < 4; ++ct) {
                bf16x8 bv = ld8(bwp + k0 + ct * 16 * CC);
                qaccA[ct] = __builtin_amdgcn_mfma_f32_16x16x32_bf16(aA, bv, qaccA[ct], 0, 0, 0);
                qaccB[ct] = __builtin_amdgcn_mfma_f32_16x16x32_bf16(aB, bv, qaccB[ct], 0, 0, 0);
            }
        }
    }
    bf16* ql = &ptile[w][0];
#pragma unroll
    for (int ct = 0; ct < 4; ++ct)
#pragma unroll
        for (int r = 0; r < 4; ++r) {
            ql[swz(quad * 4 + r, ct * 16 + l15)] = (bf16)qaccA[ct][r];
            ql[swz(16 + quad * 4 + r, ct * 16 + l15)] = (bf16)qaccB[ct][r];
        }
    asm volatile("s_waitcnt lgkmcnt(0)" ::: "memory");
    __builtin_amdgcn_sched_barrier(0);
    bf16x8 aq0A = ld8(ql + swz(l15, quad * 8));
    bf16x8 aq1A = ld8(ql + swz(l15, 32 + quad * 8));
    bf16x8 aq0B = ld8(ql + swz(16 + l15, quad * 8));
    bf16x8 aq1B = ld8(ql + swz(16 + l15, 32 + quad * 8));

    // prologue: stage V tile 0; preload K fragments for tile 0
    {
        bf16x8 s0 = ld8(vsrc0);
        bf16x8 s1 = ld8(vsrc1);
        *reinterpret_cast<bf16x8*>(&vbuf[0][0] + soff0) = s0;
        *reinterpret_cast<bf16x8*>(&vbuf[0][0] + soff1) = s1;
    }
    const bf16* kbase = Ktb + (long)l15 * CC + h * DKK + quad * 8;
    bf16x8 kf0[4], kf1[4];
#pragma unroll
    for (int ct = 0; ct < 4; ++ct) {
        kf0[ct] = ld8(kbase + (long)ct * 16 * CC);
        kf1[ct] = ld8(kbase + (long)ct * 16 * CC + 32);
    }
    __syncthreads();

    f32x4 oaccA[4], oaccB[4];
    float mrowA = -1e30f, lrowA = 0.f, mrowB = -1e30f, lrowB = 0.f;
#pragma unroll
    for (int ct = 0; ct < 4; ++ct) { oaccA[ct] = fzero; oaccB[ct] = fzero; }

    for (int kt = 0; kt < 16; ++kt) {
        int cur = kt & 1;
        bf16x8 sv0, sv1;
        if (kt < 15) {
            sv0 = ld8(vsrc0 + (kt + 1) * 64);
            sv1 = ld8(vsrc1 + (kt + 1) * 64);
        }

        // S^T = K Q^T for both tiles (K fragments already in registers)
        f32x4 sA[4], sB[4];
#pragma unroll
        for (int ct = 0; ct < 4; ++ct) { sA[ct] = fzero; sB[ct] = fzero; }
#pragma unroll
        for (int ct = 0; ct < 4; ++ct) {
            sA[ct] = __builtin_amdgcn_mfma_f32_16x16x32_bf16(kf0[ct], aq0A, sA[ct], 0, 0, 0);
            sA[ct] = __builtin_amdgcn_mfma_f32_16x16x32_bf16(kf1[ct], aq1A, sA[ct], 0, 0, 0);
            sB[ct] = __builtin_amdgcn_mfma_f32_16x16x32_bf16(kf0[ct], aq0B, sB[ct], 0, 0, 0);
            sB[ct] = __builtin_amdgcn_mfma_f32_16x16x32_bf16(kf1[ct], aq1B, sB[ct], 0, 0, 0);
        }

        // max tree (s already in log2 domain)
        float tA0 = fmaxf(fmaxf(sA[0][0], sA[0][1]), fmaxf(sA[0][2], sA[0][3]));
        float tA1 = fmaxf(fmaxf(sA[1][0], sA[1][1]), fmaxf(sA[1][2], sA[1][3]));
        float tA2 = fmaxf(fmaxf(sA[2][0], sA[2][1]), fmaxf(sA[2][2], sA[2][3]));
        float tA3 = fmaxf(fmaxf(sA[3][0], sA[3][1]), fmaxf(sA[3][2], sA[3][3]));
        float tB0 = fmaxf(fmaxf(sB[0][0], sB[0][1]), fmaxf(sB[0][2], sB[0][3]));
        float tB1 = fmaxf(fmaxf(sB[1][0], sB[1][1]), fmaxf(sB[1][2], sB[1][3]));
        float tB2 = fmaxf(fmaxf(sB[2][0], sB[2][1]), fmaxf(sB[2][2], sB[2][3]));
        float tB3 = fmaxf(fmaxf(sB[3][0], sB[3][1]), fmaxf(sB[3][2], sB[3][3]));
        float tmaxA = fmaxf(fmaxf(tA0, tA1), fmaxf(tA2, tA3));
        float tmaxB = fmaxf(fmaxf(tB0, tB1), fmaxf(tB2, tB3));
        tmaxA = fmaxf(tmaxA, __shfl_xor(tmaxA, 16));
        tmaxB = fmaxf(tmaxB, __shfl_xor(tmaxB, 16));
        tmaxA = fmaxf(tmaxA, __shfl_xor(tmaxA, 32));
        tmaxB = fmaxf(tmaxB, __shfl_xor(tmaxB, 32));

        // defer-rescale (T13)
        if (!__all(tmaxA - mrowA <= 10.f)) {
            float mnA = fmaxf(mrowA, tmaxA);
            float alphaA = __builtin_amdgcn_exp2f(mrowA - mnA);
            mrowA = mnA;
            lrowA *= alphaA;
#pragma unroll
            for (int ct = 0; ct < 4; ++ct)
#pragma unroll
                for (int r = 0; r < 4; ++r) oaccA[ct][r] *= alphaA;
        }
        if (!__all(tmaxB - mrowB <= 10.f)) {
            float mnB = fmaxf(mrowB, tmaxB);
            float alphaB = __builtin_amdgcn_exp2f(mrowB - mnB);
            mrowB = mnB;
            lrowB *= alphaB;
#pragma unroll
            for (int ct = 0; ct < 4; ++ct)
#pragma unroll
                for (int r = 0; r < 4; ++r) oaccB[ct][r] *= alphaB;
        }

        // P = exp2(s - m); packed b64 swizzled writes
        bf16* pl = &ptile[w][0];
        float lsA = 0.f, lsB = 0.f;
#pragma unroll
        for (int ct = 0; ct < 4; ++ct) {
            bf16x4 pkA, pkB;
#pragma unroll
            for (int r = 0; r < 4; ++r) {
                float eA = __builtin_amdgcn_exp2f(sA[ct][r] - mrowA);
                float eB = __builtin_amdgcn_exp2f(sB[ct][r] - mrowB);
                lsA += eA; lsB += eB;
                pkA[r] = (bf16)eA; pkB[r] = (bf16)eB;
            }
            *reinterpret_cast<bf16x4*>(pl + swz(l15, ct * 16 + quad * 4)) = pkA;
            *reinterpret_cast<bf16x4*>(pl + swz(16 + l15, ct * 16 + quad * 4)) = pkB;
        }
        lrowA += lsA;
        lrowB += lsB;
        asm volatile("s_waitcnt lgkmcnt(0)" ::: "memory");
        __builtin_amdgcn_sched_barrier(0);

        // ---- issue next-tile K loads here (hidden under PV + barrier)
        bf16x8 nf0[4], nf1[4];
        if (kt < 15) {
            const bf16* kn = kbase + (long)(kt + 1) * 64 * CC;
#pragma unroll
            for (int ct = 0; ct < 4; ++ct) {
                nf0[ct] = ld8(kn + (long)ct * 16 * CC);
                nf1[ct] = ld8(kn + (long)ct * 16 * CC + 32);
            }
        }

        // O^T += V^T P^T  (V fragments shared between tiles)
        const bf16* vb = &vbuf[cur][0];
#pragma unroll
        for (int ks = 0; ks < 2; ++ks) {
            bf16x8 bpA = ld8(pl + swz(l15, ks * 32 + quad * 8));
            bf16x8 bpB = ld8(pl + swz(16 + l15, ks * 32 + quad * 8));
#pragma unroll
            for (int ct = 0; ct < 4; ++ct) {
                int d = ct * 16 + l15;
                bf16x8 av = ld8(vb + d * VST + (((ks * 4 + quad) ^ (d & 7)) * 8));
                oaccA[ct] = __builtin_amdgcn_mfma_f32_16x16x32_bf16(av, bpA, oaccA[ct], 0, 0, 0);
                oaccB[ct] = __builtin_amdgcn_mfma_f32_16x16x32_bf16(av, bpB, oaccB[ct], 0, 0, 0);
            }
        }

        if (kt < 15) {
            bf16* wb = &vbuf[cur ^ 1][0];
            *reinterpret_cast<bf16x8*>(wb + soff0) = sv0;
            *reinterpret_cast<bf16x8*>(wb + soff1) = sv1;
#pragma unroll
            for (int ct = 0; ct < 4; ++ct) { kf0[ct] = nf0[ct]; kf1[ct] = nf1[ct]; }
        }
        __syncthreads();
    }

    // final denominators
    lrowA += __shfl_xor(lrowA, 16);
    lrowB += __shfl_xor(lrowB, 16);
    lrowA += __shfl_xor(lrowA, 32);
    lrowB += __shfl_xor(lrowB, 32);
    float invA = 1.f / lrowA, invB = 1.f / lrowB;

    // O^T -> transpose via swizzled stripes -> coalesced stores
    bf16* pl = &ptile[w][0];
#pragma unroll
    for (int ct = 0; ct < 4; ++ct) {
        bf16x4 okA, okB;
#pragma unroll
        for (int r = 0; r < 4; ++r) {
            okA[r] = (bf16)(oaccA[ct][r] * invA);
            okB[r] = (bf16)(oaccB[ct][r] * invB);
        }
        *reinterpret_cast<bf16x4*>(pl + swz(l15, ct * 16 + quad * 4)) = okA;
        *reinterpret_cast<bf16x4*>(pl + swz(16 + l15, ct * 16 + quad * 4)) = okB;
    }
    asm volatile("s_waitcnt lgkmcnt(0)" ::: "memory");
    __builtin_amdgcn_sched_barrier(0);
    {
        bf16x8 o0 = ld8(pl + swz(l15, quad * 16));
        bf16x8 o1 = ld8(pl + swz(l15, quad * 16 + 8));
        bf16* dst = Otb + (long)(m0 + l15) * CC + h * DKK + quad * 16;
        *reinterpret_cast<bf16x8*>(dst) = o0;
        *reinterpret_cast<bf16x8*>(dst + 8) = o1;
        bf16x8 p0 = ld8(pl + swz(16 + l15, quad * 16));
        bf16x8 p1 = ld8(pl + swz(16 + l15, quad * 16 + 8));
        bf16* dstB = Otb + (long)(m0 + 16 + l15) * CC + h * DKK + quad * 16;
        *reinterpret_cast<bf16x8*>(dstB) = p0;
        *reinterpret_cast<bf16x8*>(dstB + 8) = p1;
    }
}

// ---------------------------------------------------------------------------
// proj: p[b,o,n] = Wproj . ot[b,n,:]^T, fp32 out; LDS-staged double-buffered
// GEMM, BK=64. BN raw stats fused via shfl + atomics.
// ---------------------------------------------------------------------------
__global__ __launch_bounds__(256) void gemm_ntf(const bf16* __restrict__ A,
                                                const bf16* __restrict__ Bt,
                                                float* __restrict__ C,
                                                float* __restrict__ stats) {
    __shared__ __align__(16) bf16 sa[2][64][72];   // Wpb tile [ch][k]
    __shared__ __align__(16) bf16 sb[2][64][72];   // ot tile [px][k]
    const f32x4 fzero = {0.f, 0.f, 0.f, 0.f};
    int b = blockIdx.z;
    const bf16* Btb = Bt + (size_t)b * NN * CC;
    float* Cb = C + (size_t)b * CC * NN;
    int w = threadIdx.x >> 6, lane = threadIdx.x & 63;
    int quad = lane >> 4, l15 = lane & 15;
    long m0 = (long)blockIdx.x * 64 + w * 16;
    long n0 = (long)blockIdx.y * 64;

    int srow = threadIdx.x >> 2, sseg = threadIdx.x & 3;
    const bf16* apS = A + ((long)blockIdx.x * 64 + srow) * CC + sseg * 8;
    const bf16* bpS = Btb + (n0 + srow) * CC + sseg * 8;

    {
        *reinterpret_cast<bf16x8*>(&sa[0][srow][sseg * 8]) = ld8(apS);
        *reinterpret_cast<bf16x8*>(&sa[0][srow][32 + sseg * 8]) = ld8(apS + 32);
        *reinterpret_cast<bf16x8*>(&sb[0][srow][sseg * 8]) = ld8(bpS);
        *reinterpret_cast<bf16x8*>(&sb[0][srow][32 + sseg * 8]) = ld8(bpS + 32);
    }
    __syncthreads();

    f32x4 acc[4];
#pragma unroll
    for (int ct = 0; ct < 4; ++ct) acc[ct] = fzero;

    for (int s = 0; s < 8; ++s) {
        int cur = s & 1;
        bf16x8 svA0, svA1, svB0, svB1;
        if (s < 7) {
            int k1 = (s + 1) * 64;
            svA0 = ld8(apS + k1);
            svA1 = ld8(apS + k1 + 32);
            svB0 = ld8(bpS + k1);
            svB1 = ld8(bpS + k1 + 32);
        }
        bf16x8 a0 = ld8(&sa[cur][w * 16 + l15][quad * 8]);
        bf16x8 a1 = ld8(&sa[cur][w * 16 + l15][32 + quad * 8]);
#pragma unroll
        for (int ct = 0; ct < 4; ++ct) {
            bf16x8 b0 = ld8(&sb[cur][ct * 16 + l15][quad * 8]);
            acc[ct] = __builtin_amdgcn_mfma_f32_16x16x32_bf16(a0, b0, acc[ct], 0, 0, 0);
            bf16x8 b1 = ld8(&sb[cur][ct * 16 + l15][32 + quad * 8]);
            acc[ct] = __builtin_amdgcn_mfma_f32_16x16x32_bf16(a1, b1, acc[ct], 0, 0, 0);
        }
        if (s < 7) {
            *reinterpret_cast<bf16x8*>(&sa[cur ^ 1][srow][sseg * 8]) = svA0;
            *reinterpret_cast<bf16x8*>(&sa[cur ^ 1][srow][32 + sseg * 8]) = svA1;
            *reinterpret_cast<bf16x8*>(&sb[cur ^ 1][srow][sseg * 8]) = svB0;
            *reinterpret_cast<bf16x8*>(&sb[cur ^ 1][srow][32 + sseg * 8]) = svB1;
        }
        __syncthreads();
    }

    float ps[4], pss[4];
#pragma unroll
    for (int r = 0; r < 4; ++r) { ps[r] = 0.f; pss[r] = 0.f; }
#pragma unroll
    for (int ct = 0; ct < 4; ++ct)
#pragma unroll
        for (int r = 0; r < 4; ++r) {
            float v = acc[ct][r];
            Cb[(m0 + quad * 4 + r) * NN + n0 + ct * 16 + l15] = v;
            ps[r] += v; pss[r] += v * v;
        }
#pragma unroll
    for (int off = 1; off < 16; off <<= 1)
#pragma unroll
        for (int r = 0; r < 4; ++r) {
            ps[r] += __shfl_xor(ps[r], off);
            pss[r] += __shfl_xor(pss[r], off);
        }
    if (l15 == 0) {
#pragma unroll
        for (int r = 0; r < 4; ++r) {
            int c = (int)(m0 + quad * 4 + r);
            atomicAdd(&stats[c * 2], ps[r]);
            atomicAdd(&stats[c * 2 + 1], pss[r]);
        }
    }
}

// ---------------------------------------------------------------------------
// y = x + bn(p); LayerNorm over C per pixel; BN scale/shift derived from raw
// stats in a small LDS preamble. fp32 in-place on d_out.
// ---------------------------------------------------------------------------
__global__ __launch_bounds__(256) void final_kernel(const float* __restrict__ x,
                                                    const float* __restrict__ p,
                                                    const float* __restrict__ stats,
                                                    const float* __restrict__ bng,
                                                    const float* __restrict__ bnb,
                                                    const float* __restrict__ lg,
                                                    const float* __restrict__ lb,
                                                    float* __restrict__ out) {
    __shared__ float scs[512], shs[512];
    for (int c = threadIdx.x; c < 512; c += 256) {
        float sum = stats[c * 2], ssq = stats[c * 2 + 1];
        float mean = sum * (1.f / 16384.f);
        float var = ssq * (1.f / 16384.f) - mean * mean;
        float rstd = rsqrtf(var + 1e-5f);
        float sc = bng[c] * rstd;
        scs[c] = sc;
        shs[c] = bnb[c] - mean * sc;
    }
    __syncthreads();
    int blk = blockIdx.x;
    int b = blk >> 6;
    int pix0 = (blk & 63) * 64;
    int sub = threadIdx.x >> 6, px = threadIdx.x & 63;
    float s = 0.f, ss = 0.f;
    for (int i = 0; i < 128; ++i) {
        int c = i * 4 + sub;
        long idx = ((long)(b * CC + c)) * NN + pix0 + px;
        float y = x[idx] + p[idx] * scs[c] + shs[c];
        s += y; ss += y * y;
    }
    __shared__ float rs[4][64], rss[4][64];
    rs[sub][px] = s; rss[sub][px] = ss;
    __syncthreads();
    float sum = rs[0][px] + rs[1][px] + rs[2][px] + rs[3][px];
    float sq  = rss[0][px] + rss[1][px] + rss[2][px] + rss[3][px];
    float mu = sum * (1.f / 512.f);
    float var = sq * (1.f / 512.f) - mu * mu;
    float rstd = rsqrtf(var + 1e-5f);
    for (int i = 0; i < 128; ++i) {
        int c = i * 4 + sub;
        long idx = ((long)(b * CC + c)) * NN + pix0 + px;
        float y = x[idx] + p[idx] * scs[c] + shs[c];
        out[idx] = (y - mu) * rstd * lg[c] + lb[c];
    }
}

// ---------------------------------------------------------------------------
extern "C" void kernel_launch(void* const* d_in, const int* in_sizes, int n_in,
                              void* d_out, int out_size, void* d_ws, size_t ws_size,
                              hipStream_t stream) {
    (void)in_sizes; (void)n_in; (void)out_size;
    const float* x     = (const float*)d_in[0];
    const float* Wq    = (const float*)d_in[1];
    const float* Wk    = (const float*)d_in[2];
    const float* Wv    = (const float*)d_in[3];
    const float* bias  = (const float*)d_in[4];
    const float* Wproj = (const float*)d_in[5];
    const float* bng   = (const float*)d_in[6];
    const float* bnb   = (const float*)d_in[7];
    const float* lng   = (const float*)d_in[8];
    const float* lnb   = (const float*)d_in[9];
    float* out = (float*)d_out;   // fp32 output (verified R9)

    char* ws = (char*)d_ws;
    size_t off = 0;
    auto alloc = [&](size_t bytes) {
        char* pp = ws + off;
        off += (bytes + 255) & ~(size_t)255;
        return pp;
    };
    bf16* Wqb = (bf16*)alloc((size_t)CC * CC * 2);          // 0.52 MB
    bf16* Wpb = (bf16*)alloc((size_t)CC * CC * 2);          // 0.52 MB
    float* stats = (float*)alloc(512 * 2 * sizeof(float));

    size_t needA = off + ((size_t)CC * 2048 * 2 * 2)        // Wkf+Wvf 4.2 MB
                 + ((size_t)BB * NN * CC * 2)               // xt_all 16.8
                 + ((size_t)BB * NRR * CC * 2 * 2)          // kt+vt   8.4
                 + ((size_t)BB * NN * CC * 2) + 4096;       // ot_all 16.8

    if (ws_size >= needA) {
        bf16* Wkf = (bf16*)alloc((size_t)CC * 2048 * 2);
        bf16* Wvf = (bf16*)alloc((size_t)CC * 2048 * 2);
        bf16* xt  = (bf16*)alloc((size_t)BB * NN * CC * 2);
        bf16* kt  = (bf16*)alloc((size_t)BB * NRR * CC * 2);
        bf16* vt  = (bf16*)alloc((size_t)BB * NRR * CC * 2);   // holds V^T [c][m]
        bf16* ot  = (bf16*)alloc((size_t)BB * NN * CC * 2);

        wcvt_kernel<<<1024, 256, 0, stream>>>(Wq, Wproj, Wqb, Wpb, stats);
        wperm_kernel<<<4096, 256, 0, stream>>>(Wk, Wv, Wkf, Wvf);
        transpose_kernel<<<dim3(64, 8, BB), 256, 0, stream>>>(x, xt);
        gemm_kv<<<dim3(16, 8, BB), 256, 0, stream>>>(xt, Wkf, Wvf, kt, vt);
        attn_kernel<<<dim3(32, NHH, BB), 256, 0, stream>>>(xt, Wqb, kt, vt, bias, ot);
        gemm_ntf<<<dim3(8, 64, BB), 256, 0, stream>>>(Wpb, ot, out, stats);
    } else {
        bf16* Wkf = (bf16*)(out + (size_t)3 * CC * NN);
        bf16* Wvf = Wkf + (size_t)CC * 2048;
        bf16* xt = (bf16*)alloc((size_t)NN * CC * 2);
        bf16* kt = (bf16*)alloc((size_t)NRR * CC * 2);
        bf16* vt = (bf16*)alloc((size_t)NRR * CC * 2);         // V^T [c][m]
        bf16* ot = (bf16*)alloc((size_t)NN * CC * 2);

        wcvt_kernel<<<1024, 256, 0, stream>>>(Wq, Wproj, Wqb, Wpb, stats);
        wperm_kernel<<<4096, 256, 0, stream>>>(Wk, Wv, Wkf, Wvf);
        for (int b = 0; b < BB; ++b) {
            const float* xb = x + (size_t)b * CC * NN;
            float* pb = out + (size_t)b * CC * NN;
            transpose_kernel<<<dim3(64, 8, 1), 256, 0, stream>>>(xb, xt);
            gemm_kv<<<dim3(16, 8, 1), 256, 0, stream>>>(xt, Wkf, Wvf, kt, vt);
            attn_kernel<<<dim3(32, NHH, 1), 256, 0, stream>>>(xt, Wqb, kt, vt, bias, ot);
            gemm_ntf<<<dim3(8, 64, 1), 256, 0, stream>>>(Wpb, ot, pb, stats);
        }
    }

    final_kernel<<<256, 256, 0, stream>>>(x, out, stats, bng, bnb, lng, lnb, out);
}